// Round 1
// baseline (413.460 us; speedup 1.0000x reference)
//
#include <hip/hip_runtime.h>
#include <hip/hip_bf16.h>
#include <stdint.h>

#define D 128

// ---------------- GEMM: OUT[r,:] = IN[r,:] @ W (+bias). 16 rows/block. ----------------
__global__ __launch_bounds__(256) void gemm128_k(const float* __restrict__ IN,
                                                 const float* __restrict__ W,
                                                 const float* __restrict__ bias,
                                                 float* __restrict__ OUT, int nrows) {
    __shared__ float xs[16][132];   // pad 132 (mult of 4): 16B-aligned float4 reads
    int row0 = blockIdx.x * 16;
    int tid  = threadIdx.x;
    // stage 16 rows (2048 floats = 512 float4) with 256 threads
    const float4* in4 = (const float4*)(IN + (size_t)row0 * D);
#pragma unroll
    for (int it = 0; it < 2; ++it) {
        int idx = tid + it * 256;           // float4 index
        int r = idx >> 5;                   // 32 float4 per row
        int k = (idx & 31) * 4;
        float4 v = make_float4(0.f, 0.f, 0.f, 0.f);
        if (row0 + r < nrows) v = in4[idx];
        xs[r][k] = v.x; xs[r][k + 1] = v.y; xs[r][k + 2] = v.z; xs[r][k + 3] = v.w;
    }
    __syncthreads();
    int j = tid & 127;            // output col
    int g = (tid >> 7) * 8;       // row sub-block: 0 or 8
    float acc[8] = {0, 0, 0, 0, 0, 0, 0, 0};
    for (int k0 = 0; k0 < D; k0 += 4) {
        float w0 = W[(k0 + 0) * D + j];
        float w1 = W[(k0 + 1) * D + j];
        float w2 = W[(k0 + 2) * D + j];
        float w3 = W[(k0 + 3) * D + j];
#pragma unroll
        for (int r = 0; r < 8; ++r) {
            const float4 xv = *(const float4*)&xs[g + r][k0];  // broadcast b128
            acc[r] += xv.x * w0;
            acc[r] += xv.y * w1;
            acc[r] += xv.z * w2;
            acc[r] += xv.w * w3;
        }
    }
    float bv = bias ? bias[j] : 0.0f;
#pragma unroll
    for (int r = 0; r < 8; ++r) {
        int row = row0 + g + r;
        if (row < nrows) OUT[(size_t)row * D + j] = acc[r] + bv;
    }
}

// ---------------- per-node attention scores: ss[n]=h[n]·a_src, sd[n]=h[n]·a_dst ----------------
__global__ __launch_bounds__(256) void scores_k(const float* __restrict__ h,
                                                const float* __restrict__ a_src,
                                                const float* __restrict__ a_dst,
                                                float* __restrict__ ss, float* __restrict__ sd,
                                                int n) {
    int wave = (int)((blockIdx.x * 256 + threadIdx.x) >> 6);
    int lane = threadIdx.x & 63;
    if (wave >= n) return;
    float x0 = h[(size_t)wave * D + lane];
    float x1 = h[(size_t)wave * D + 64 + lane];
    float s = x0 * a_src[lane] + x1 * a_src[64 + lane];
    float d = x0 * a_dst[lane] + x1 * a_dst[64 + lane];
#pragma unroll
    for (int off = 32; off; off >>= 1) {
        s += __shfl_xor(s, off);
        d += __shfl_xor(d, off);
    }
    if (lane == 0) { ss[wave] = s; sd[wave] = d; }
}

// ---------------- CSR build ----------------
__global__ void degree_k(const int* __restrict__ src, const int* __restrict__ dst,
                         int* deg_s, int* deg_d, int ne) {
    int i = blockIdx.x * 256 + threadIdx.x;
    if (i >= ne) return;
    atomicAdd(&deg_s[src[i]], 1);
    atomicAdd(&deg_d[dst[i]], 1);
}

// one block per array; 1024-thread Hillis-Steele chunked scan
__global__ __launch_bounds__(1024) void scan_k(const int* __restrict__ deg_d,
                                               const int* __restrict__ deg_s,
                                               int* rp_d, int* cur_d, int* rp_s, int* cur_s,
                                               int n) {
    const int* deg = blockIdx.x ? deg_s : deg_d;
    int* rp  = blockIdx.x ? rp_s  : rp_d;
    int* cur = blockIdx.x ? cur_s : cur_d;
    __shared__ int buf[1024];
    int carry = 0;
    for (int base = 0; base < n; base += 1024) {
        int i = base + (int)threadIdx.x;
        int v = (i < n) ? deg[i] : 0;
        buf[threadIdx.x] = v;
        __syncthreads();
        for (int off = 1; off < 1024; off <<= 1) {
            int t = (threadIdx.x >= (unsigned)off) ? buf[threadIdx.x - off] : 0;
            __syncthreads();
            buf[threadIdx.x] += t;
            __syncthreads();
        }
        int incl = buf[threadIdx.x];
        if (i < n) { rp[i] = carry + incl - v; cur[i] = carry + incl - v; }
        int tot = buf[1023];
        __syncthreads();
        carry += tot;
    }
    if (threadIdx.x == 0) rp[n] = carry;
}

__global__ void fill_k(const int* __restrict__ src, const int* __restrict__ dst,
                       int* cur_d, int* cur_s, int* nbr_d, int* nbr_s, int ne) {
    int i = blockIdx.x * 256 + threadIdx.x;
    if (i >= ne) return;
    int s = src[i], d = dst[i];
    nbr_d[atomicAdd(&cur_d[d], 1)] = s;   // incoming-by-dst stores src id
    nbr_s[atomicAdd(&cur_s[s], 1)] = d;   // incoming-by-src (reversed conv) stores dst id
}

// ---------------- GAT gather: one wave per node; fused softmax-norm + bias + residual ----------------
__global__ __launch_bounds__(256) void gat_gather_k(const int* __restrict__ rowptr,
                                                    const int* __restrict__ nbrs,
                                                    const float* __restrict__ score_nb,
                                                    const float* __restrict__ score_self,
                                                    const float* __restrict__ h,
                                                    const float* __restrict__ bias,
                                                    const float* __restrict__ resid,
                                                    float* __restrict__ out, int n) {
    int wave = (int)((blockIdx.x * 256 + threadIdx.x) >> 6);
    int lane = threadIdx.x & 63;
    if (wave >= n) return;
    int node = wave;
    int beg = rowptr[node], end = rowptr[node + 1];
    float sself = score_self[node];
    float acc0 = 0.f, acc1 = 0.f, wsum = 0.f;
    for (int j = beg; j < end; ++j) {
        int nb = nbrs[j];
        float e = score_nb[nb] + sself;
        e = (e > 0.f) ? e : 0.2f * e;       // leaky_relu 0.2
        float w = __expf(e);                // max-shift skipped: alpha identical
        wsum += w;
        const float* hp = h + (size_t)nb * D;
        acc0 += w * hp[lane];
        acc1 += w * hp[64 + lane];
    }
    float inv = 1.0f / (wsum + 1e-16f);
    size_t o = (size_t)node * D + lane;
    out[o]      = acc0 * inv + bias[lane]      + resid[o];
    out[o + 64] = acc1 * inv + bias[lane + 64] + resid[o + 64];
}

// ---------------- host ----------------
extern "C" void kernel_launch(void* const* d_in, const int* in_sizes, int n_in,
                              void* d_out, int out_size, void* d_ws, size_t ws_size,
                              hipStream_t stream) {
    const float* Xw    = (const float*)d_in[0];
    const float* Xs    = (const float*)d_in[1];
    const int*   edge  = (const int*)d_in[2];
    const float* W_s2w = (const float*)d_in[3];
    const float* as1   = (const float*)d_in[4];
    const float* ad1   = (const float*)d_in[5];
    const float* b1    = (const float*)d_in[6];
    const float* W_w2s = (const float*)d_in[7];
    const float* as2   = (const float*)d_in[8];
    const float* ad2   = (const float*)d_in[9];
    const float* b2    = (const float*)d_in[10];
    const float* W_lin = (const float*)d_in[11];
    const float* b_lin = (const float*)d_in[12];
    float* out = (float*)d_out;

    const int N  = in_sizes[0] / D;       // 20000
    const int NE = in_sizes[2] / 2;       // 640000
    const int* e_src = edge;
    const int* e_dst = edge + NE;

    // workspace carve (256B aligned)
    char* p = (char*)d_ws;
    auto take = [&](size_t bytes) -> void* {
        p = (char*)(((uintptr_t)p + 255) & ~(uintptr_t)255);
        void* r = (void*)p;
        p += bytes;
        return r;
    };
    float* h1   = (float*)take((size_t)N * D * 4);
    float* h2   = (float*)take((size_t)N * D * 4);
    float* ss1  = (float*)take((size_t)N * 4);
    float* sd1  = (float*)take((size_t)N * 4);
    float* ss2  = (float*)take((size_t)N * 4);
    float* sd2  = (float*)take((size_t)N * 4);
    int*   deg  = (int*)take((size_t)2 * N * 4);   // deg_d | deg_s contiguous
    int*   deg_d = deg;
    int*   deg_s = deg + N;
    int*   rp_d = (int*)take((size_t)(N + 1) * 4);
    int*   rp_s = (int*)take((size_t)(N + 1) * 4);
    int*   cur_d = (int*)take((size_t)N * 4);
    int*   cur_s = (int*)take((size_t)N * 4);
    int*   nbr_d = (int*)take((size_t)NE * 4);
    int*   nbr_s = (int*)take((size_t)NE * 4);

    float* t1 = out;               // temp_word + Xw, staged in output buffer
    float* t2 = out + (size_t)N * D;

    hipMemsetAsync(deg, 0, (size_t)2 * N * 4, stream);

    int gemmGrid = (N + 15) / 16;
    // h1 = Xs @ W_s2w ; h2 = Xw @ W_w2s
    gemm128_k<<<gemmGrid, 256, 0, stream>>>(Xs, W_s2w, nullptr, h1, N);
    gemm128_k<<<gemmGrid, 256, 0, stream>>>(Xw, W_w2s, nullptr, h2, N);

    int nodeWaveGrid = (N + 3) / 4;     // 4 waves (nodes) per 256-thread block
    scores_k<<<nodeWaveGrid, 256, 0, stream>>>(h1, as1, ad1, ss1, sd1, N);
    scores_k<<<nodeWaveGrid, 256, 0, stream>>>(h2, as2, ad2, ss2, sd2, N);

    int edgeGrid = (NE + 255) / 256;
    degree_k<<<edgeGrid, 256, 0, stream>>>(e_src, e_dst, deg_s, deg_d, NE);
    scan_k<<<2, 1024, 0, stream>>>(deg_d, deg_s, rp_d, cur_d, rp_s, cur_s, N);
    fill_k<<<edgeGrid, 256, 0, stream>>>(e_src, e_dst, cur_d, cur_s, nbr_d, nbr_s, NE);

    // conv1 (sent2word): softmax over dst, neighbor=src, e = lrelu(ss1[src]+sd1[dst])
    gat_gather_k<<<nodeWaveGrid, 256, 0, stream>>>(rp_d, nbr_d, ss1, sd1, h1, b1, Xw, t1, N);
    // conv2 (word2sent, reversed edges): softmax over src, neighbor=dst, e = lrelu(ss2[dst]+sd2[src])
    gat_gather_k<<<nodeWaveGrid, 256, 0, stream>>>(rp_s, nbr_s, ss2, sd2, h2, b2, Xs, t2, N);

    // epilogue: out = t @ W_lin + b_lin   (in-place: each block stages its own rows first)
    gemm128_k<<<gemmGrid, 256, 0, stream>>>(t1, W_lin, b_lin, t1, N);
    gemm128_k<<<gemmGrid, 256, 0, stream>>>(t2, W_lin, b_lin, t2, N);
}

// Round 2
// 289.829 us; speedup vs baseline: 1.4266x; 1.4266x over previous
//
#include <hip/hip_runtime.h>
#include <hip/hip_bf16.h>
#include <stdint.h>

#define D 128
#define BKT_W 128            // nodes per bucket
#define NB_MAX 256           // supports N <= 32768

// ---------------- GEMM: OUT[r,:] = IN[r,:] @ W (+bias). 16 rows/block. ----------------
__global__ __launch_bounds__(256) void gemm128_k(const float* __restrict__ IN,
                                                 const float* __restrict__ W,
                                                 const float* __restrict__ bias,
                                                 float* __restrict__ OUT, int nrows) {
    __shared__ float xs[16][132];
    int row0 = blockIdx.x * 16;
    int tid  = threadIdx.x;
    const float4* in4 = (const float4*)(IN + (size_t)row0 * D);
#pragma unroll
    for (int it = 0; it < 2; ++it) {
        int idx = tid + it * 256;
        int r = idx >> 5;
        int k = (idx & 31) * 4;
        float4 v = make_float4(0.f, 0.f, 0.f, 0.f);
        if (row0 + r < nrows) v = in4[idx];
        xs[r][k] = v.x; xs[r][k + 1] = v.y; xs[r][k + 2] = v.z; xs[r][k + 3] = v.w;
    }
    __syncthreads();
    int j = tid & 127;
    int g = (tid >> 7) * 8;
    float acc[8] = {0, 0, 0, 0, 0, 0, 0, 0};
    for (int k0 = 0; k0 < D; k0 += 4) {
        float w0 = W[(k0 + 0) * D + j];
        float w1 = W[(k0 + 1) * D + j];
        float w2 = W[(k0 + 2) * D + j];
        float w3 = W[(k0 + 3) * D + j];
#pragma unroll
        for (int r = 0; r < 8; ++r) {
            const float4 xv = *(const float4*)&xs[g + r][k0];
            acc[r] += xv.x * w0;
            acc[r] += xv.y * w1;
            acc[r] += xv.z * w2;
            acc[r] += xv.w * w3;
        }
    }
    float bv = bias ? bias[j] : 0.0f;
#pragma unroll
    for (int r = 0; r < 8; ++r) {
        int row = row0 + g + r;
        if (row < nrows) OUT[(size_t)row * D + j] = acc[r] + bv;
    }
}

// ---------------- per-node attention scores ----------------
__global__ __launch_bounds__(256) void scores_k(const float* __restrict__ h,
                                                const float* __restrict__ a_src,
                                                const float* __restrict__ a_dst,
                                                float* __restrict__ ss, float* __restrict__ sd,
                                                int n) {
    int wave = (int)((blockIdx.x * 256 + threadIdx.x) >> 6);
    int lane = threadIdx.x & 63;
    if (wave >= n) return;
    float x0 = h[(size_t)wave * D + lane];
    float x1 = h[(size_t)wave * D + 64 + lane];
    float s = x0 * a_src[lane] + x1 * a_src[64 + lane];
    float d = x0 * a_dst[lane] + x1 * a_dst[64 + lane];
#pragma unroll
    for (int off = 32; off; off >>= 1) {
        s += __shfl_xor(s, off);
        d += __shfl_xor(d, off);
    }
    if (lane == 0) { ss[wave] = s; sd[wave] = d; }
}

// ---------------- CSR build: bucket histogram ----------------
__global__ __launch_bounds__(256) void hist_k(const int* __restrict__ src,
                                              const int* __restrict__ dst,
                                              int* __restrict__ bcnt_d, int* __restrict__ bcnt_s,
                                              int ne, int nb) {
    __shared__ int cnt[2][NB_MAX];
    int tid = threadIdx.x;
    for (int i = tid; i < 2 * NB_MAX; i += 256) ((int*)cnt)[i] = 0;
    __syncthreads();
    for (int i = blockIdx.x * 256 + tid; i < ne; i += gridDim.x * 256) {
        atomicAdd(&cnt[0][dst[i] >> 7], 1);
        atomicAdd(&cnt[1][src[i] >> 7], 1);
    }
    __syncthreads();
    for (int i = tid; i < nb; i += 256) {
        if (cnt[0][i]) atomicAdd(&bcnt_d[i], cnt[0][i]);
        if (cnt[1][i]) atomicAdd(&bcnt_s[i], cnt[1][i]);
    }
}

// ---------------- CSR build: bucket exclusive scan (1 block) ----------------
__global__ __launch_bounds__(256) void bscan_k(const int* __restrict__ bcnt_d,
                                               const int* __restrict__ bcnt_s,
                                               int* bbase_d, int* bbase_s,
                                               int* bcur_d, int* bcur_s,
                                               int* rp_d, int* rp_s,
                                               int nb, int n, int ne) {
    __shared__ int buf[256];
    int tid = threadIdx.x;
#pragma unroll
    for (int a = 0; a < 2; ++a) {
        const int* c = a ? bcnt_s : bcnt_d;
        int* bb = a ? bbase_s : bbase_d;
        int* bc = a ? bcur_s : bcur_d;
        int v = (tid < nb) ? c[tid] : 0;
        buf[tid] = v;
        __syncthreads();
        for (int off = 1; off < 256; off <<= 1) {
            int t = (tid >= off) ? buf[tid - off] : 0;
            __syncthreads();
            buf[tid] += t;
            __syncthreads();
        }
        int excl = buf[tid] - v;
        if (tid < nb) { bb[tid] = excl; bc[tid] = excl; }
        if (tid == nb - 1) bb[nb] = buf[tid];
        __syncthreads();
    }
    if (tid == 0) { rp_d[n] = ne; rp_s[n] = ne; }
}

// ---------------- CSR build: LDS-aggregated partition into bucket regions ----------------
// record = payload | (g_local << 17);  payload = neighbor id, g_local = group node within bucket
#define EPT 8
__global__ __launch_bounds__(256) void part_k(const int* __restrict__ src,
                                              const int* __restrict__ dst,
                                              int* __restrict__ bcur_d, int* __restrict__ bcur_s,
                                              uint32_t* __restrict__ rec_d, uint32_t* __restrict__ rec_s,
                                              int ne) {
    __shared__ int cnt[2][NB_MAX];
    __shared__ int base[2][NB_MAX];
    int tid = threadIdx.x;
    int blockStart = blockIdx.x * 256 * EPT;
    for (int i = tid; i < 2 * NB_MAX; i += 256) ((int*)cnt)[i] = 0;
    __syncthreads();
    int s[EPT], d[EPT], sl_d[EPT], sl_s[EPT];
#pragma unroll
    for (int e = 0; e < EPT; ++e) {
        int i = blockStart + e * 256 + tid;
        s[e] = -1;
        if (i < ne) {
            s[e] = src[i]; d[e] = dst[i];
            sl_d[e] = atomicAdd(&cnt[0][d[e] >> 7], 1);
            sl_s[e] = atomicAdd(&cnt[1][s[e] >> 7], 1);
        }
    }
    __syncthreads();
    for (int i = tid; i < NB_MAX; i += 256) {
        if (cnt[0][i]) base[0][i] = atomicAdd(&bcur_d[i], cnt[0][i]);
        if (cnt[1][i]) base[1][i] = atomicAdd(&bcur_s[i], cnt[1][i]);
    }
    __syncthreads();
#pragma unroll
    for (int e = 0; e < EPT; ++e) {
        if (s[e] >= 0) {
            rec_d[base[0][d[e] >> 7] + sl_d[e]] = (uint32_t)s[e] | ((uint32_t)(d[e] & 127) << 17);
            rec_s[base[1][s[e] >> 7] + sl_s[e]] = (uint32_t)d[e] | ((uint32_t)(s[e] & 127) << 17);
        }
    }
}

// ---------------- CSR build: per-bucket local fill (grid = (nb, 2)) ----------------
__global__ __launch_bounds__(256) void csrfill_k(const uint32_t* __restrict__ rec_d,
                                                 const uint32_t* __restrict__ rec_s,
                                                 const int* __restrict__ bbase_d,
                                                 const int* __restrict__ bbase_s,
                                                 int* __restrict__ rp_d, int* __restrict__ rp_s,
                                                 int* __restrict__ nbr_d, int* __restrict__ nbr_s,
                                                 int n) {
    const uint32_t* rec = blockIdx.y ? rec_s : rec_d;
    const int* bbase    = blockIdx.y ? bbase_s : bbase_d;
    int* rp             = blockIdx.y ? rp_s : rp_d;
    int* nbr            = blockIdx.y ? nbr_s : nbr_d;
    int b = blockIdx.x;
    int tid = threadIdx.x;
    int beg = bbase[b], end = bbase[b + 1];
    __shared__ int deg[BKT_W];
    __shared__ int sbuf[BKT_W];
    __shared__ int cur[BKT_W];
    if (tid < BKT_W) deg[tid] = 0;
    __syncthreads();
    for (int j = beg + tid; j < end; j += 256) atomicAdd(&deg[rec[j] >> 17], 1);
    __syncthreads();
    if (tid < BKT_W) sbuf[tid] = deg[tid];
    __syncthreads();
    for (int off = 1; off < BKT_W; off <<= 1) {
        int t = (tid < BKT_W && tid >= off) ? sbuf[tid - off] : 0;
        __syncthreads();
        if (tid < BKT_W) sbuf[tid] += t;
        __syncthreads();
    }
    if (tid < BKT_W) {
        int abs0 = beg + sbuf[tid] - deg[tid];   // exclusive
        cur[tid] = abs0;
        int node = b * BKT_W + tid;
        if (node < n) rp[node] = abs0;
    }
    __syncthreads();
    for (int j = beg + tid; j < end; j += 256) {
        uint32_t r = rec[j];
        nbr[atomicAdd(&cur[r >> 17], 1)] = (int)(r & 0x1FFFFu);
    }
}

// ---------------- GAT gather: one wave per node; fused norm + bias + residual ----------------
__global__ __launch_bounds__(256) void gat_gather_k(const int* __restrict__ rowptr,
                                                    const int* __restrict__ nbrs,
                                                    const float* __restrict__ score_nb,
                                                    const float* __restrict__ score_self,
                                                    const float* __restrict__ h,
                                                    const float* __restrict__ bias,
                                                    const float* __restrict__ resid,
                                                    float* __restrict__ out, int n) {
    int wave = (int)((blockIdx.x * 256 + threadIdx.x) >> 6);
    int lane = threadIdx.x & 63;
    if (wave >= n) return;
    int node = wave;
    int beg = rowptr[node], end = rowptr[node + 1];
    float sself = score_self[node];
    float acc0 = 0.f, acc1 = 0.f, wsum = 0.f;
    for (int j = beg; j < end; ++j) {
        int nb = nbrs[j];
        float e = score_nb[nb] + sself;
        e = (e > 0.f) ? e : 0.2f * e;
        float w = __expf(e);
        wsum += w;
        const float* hp = h + (size_t)nb * D;
        acc0 += w * hp[lane];
        acc1 += w * hp[64 + lane];
    }
    float inv = 1.0f / (wsum + 1e-16f);
    size_t o = (size_t)node * D + lane;
    out[o]      = acc0 * inv + bias[lane]      + resid[o];
    out[o + 64] = acc1 * inv + bias[lane + 64] + resid[o + 64];
}

// ---------------- host ----------------
extern "C" void kernel_launch(void* const* d_in, const int* in_sizes, int n_in,
                              void* d_out, int out_size, void* d_ws, size_t ws_size,
                              hipStream_t stream) {
    const float* Xw    = (const float*)d_in[0];
    const float* Xs    = (const float*)d_in[1];
    const int*   edge  = (const int*)d_in[2];
    const float* W_s2w = (const float*)d_in[3];
    const float* as1   = (const float*)d_in[4];
    const float* ad1   = (const float*)d_in[5];
    const float* b1    = (const float*)d_in[6];
    const float* W_w2s = (const float*)d_in[7];
    const float* as2   = (const float*)d_in[8];
    const float* ad2   = (const float*)d_in[9];
    const float* b2    = (const float*)d_in[10];
    const float* W_lin = (const float*)d_in[11];
    const float* b_lin = (const float*)d_in[12];
    float* out = (float*)d_out;

    const int N  = in_sizes[0] / D;       // 20000
    const int NE = in_sizes[2] / 2;       // 640000
    const int NB = (N + BKT_W - 1) / BKT_W;
    const int* e_src = edge;
    const int* e_dst = edge + NE;

    char* p = (char*)d_ws;
    auto take = [&](size_t bytes) -> void* {
        p = (char*)(((uintptr_t)p + 255) & ~(uintptr_t)255);
        void* r = (void*)p;
        p += bytes;
        return r;
    };
    float* h1   = (float*)take((size_t)N * D * 4);
    float* h2   = (float*)take((size_t)N * D * 4);
    float* ss1  = (float*)take((size_t)N * 4);
    float* sd1  = (float*)take((size_t)N * 4);
    float* ss2  = (float*)take((size_t)N * 4);
    float* sd2  = (float*)take((size_t)N * 4);
    int*   bcnt = (int*)take((size_t)2 * NB * 4);     // bcnt_d | bcnt_s
    int*   bcnt_d = bcnt;
    int*   bcnt_s = bcnt + NB;
    int*   bbase_d = (int*)take((size_t)(NB + 1) * 4);
    int*   bbase_s = (int*)take((size_t)(NB + 1) * 4);
    int*   bcur_d  = (int*)take((size_t)NB * 4);
    int*   bcur_s  = (int*)take((size_t)NB * 4);
    int*   rp_d = (int*)take((size_t)(N + 1) * 4);
    int*   rp_s = (int*)take((size_t)(N + 1) * 4);
    uint32_t* rec_d = (uint32_t*)take((size_t)NE * 4);
    uint32_t* rec_s = (uint32_t*)take((size_t)NE * 4);
    int*   nbr_d = (int*)take((size_t)NE * 4);
    int*   nbr_s = (int*)take((size_t)NE * 4);

    float* t1 = out;
    float* t2 = out + (size_t)N * D;

    hipMemsetAsync(bcnt, 0, (size_t)2 * NB * 4, stream);

    int gemmGrid = (N + 15) / 16;
    gemm128_k<<<gemmGrid, 256, 0, stream>>>(Xs, W_s2w, nullptr, h1, N);
    gemm128_k<<<gemmGrid, 256, 0, stream>>>(Xw, W_w2s, nullptr, h2, N);

    int nodeWaveGrid = (N + 3) / 4;
    scores_k<<<nodeWaveGrid, 256, 0, stream>>>(h1, as1, ad1, ss1, sd1, N);
    scores_k<<<nodeWaveGrid, 256, 0, stream>>>(h2, as2, ad2, ss2, sd2, N);

    // CSR build
    hist_k<<<512, 256, 0, stream>>>(e_src, e_dst, bcnt_d, bcnt_s, NE, NB);
    bscan_k<<<1, 256, 0, stream>>>(bcnt_d, bcnt_s, bbase_d, bbase_s, bcur_d, bcur_s,
                                   rp_d, rp_s, NB, N, NE);
    int partGrid = (NE + 256 * EPT - 1) / (256 * EPT);
    part_k<<<partGrid, 256, 0, stream>>>(e_src, e_dst, bcur_d, bcur_s, rec_d, rec_s, NE);
    dim3 fillGrid(NB, 2);
    csrfill_k<<<fillGrid, 256, 0, stream>>>(rec_d, rec_s, bbase_d, bbase_s,
                                            rp_d, rp_s, nbr_d, nbr_s, N);

    // conv1 (sent2word): group by dst, neighbor = src
    gat_gather_k<<<nodeWaveGrid, 256, 0, stream>>>(rp_d, nbr_d, ss1, sd1, h1, b1, Xw, t1, N);
    // conv2 (word2sent, reversed): group by src, neighbor = dst
    gat_gather_k<<<nodeWaveGrid, 256, 0, stream>>>(rp_s, nbr_s, ss2, sd2, h2, b2, Xs, t2, N);

    // epilogue: out = t @ W_lin + b_lin (in-place safe: block stages rows first)
    gemm128_k<<<gemmGrid, 256, 0, stream>>>(t1, W_lin, b_lin, t1, N);
    gemm128_k<<<gemmGrid, 256, 0, stream>>>(t2, W_lin, b_lin, t2, N);
}

// Round 3
// 247.571 us; speedup vs baseline: 1.6701x; 1.1707x over previous
//
#include <hip/hip_runtime.h>
#include <hip/hip_bf16.h>
#include <stdint.h>

#define D 128
#define BKT_W 128            // nodes per bucket
#define NB_MAX 256           // supports N <= 32768

// ---------------- GEMM: OUT[r,:] = IN[r,:] @ W (+bias). 16 rows/block. ----------------
// MODE 0: write f32 OUT (+bias). MODE 1: write bf16 split halves HB0/HB1 (no bias).
template <int MODE>
__global__ __launch_bounds__(256) void gemm128_k(const float* __restrict__ IN,
                                                 const float* __restrict__ W,
                                                 const float* __restrict__ bias,
                                                 float* __restrict__ OUT,
                                                 __hip_bfloat16* __restrict__ HB0,
                                                 __hip_bfloat16* __restrict__ HB1,
                                                 int nrows) {
    __shared__ float xs[16][132];
    int row0 = blockIdx.x * 16;
    int tid  = threadIdx.x;
    const float4* in4 = (const float4*)(IN + (size_t)row0 * D);
#pragma unroll
    for (int it = 0; it < 2; ++it) {
        int idx = tid + it * 256;
        int r = idx >> 5;
        int k = (idx & 31) * 4;
        float4 v = make_float4(0.f, 0.f, 0.f, 0.f);
        if (row0 + r < nrows) v = in4[idx];
        xs[r][k] = v.x; xs[r][k + 1] = v.y; xs[r][k + 2] = v.z; xs[r][k + 3] = v.w;
    }
    __syncthreads();
    int j = tid & 127;
    int g = (tid >> 7) * 8;
    float acc[8] = {0, 0, 0, 0, 0, 0, 0, 0};
    for (int k0 = 0; k0 < D; k0 += 4) {
        float w0 = W[(k0 + 0) * D + j];
        float w1 = W[(k0 + 1) * D + j];
        float w2 = W[(k0 + 2) * D + j];
        float w3 = W[(k0 + 3) * D + j];
#pragma unroll
        for (int r = 0; r < 8; ++r) {
            const float4 xv = *(const float4*)&xs[g + r][k0];
            acc[r] += xv.x * w0;
            acc[r] += xv.y * w1;
            acc[r] += xv.z * w2;
            acc[r] += xv.w * w3;
        }
    }
    if (MODE == 0) {
        float bv = bias ? bias[j] : 0.0f;
#pragma unroll
        for (int r = 0; r < 8; ++r) {
            int row = row0 + g + r;
            if (row < nrows) OUT[(size_t)row * D + j] = acc[r] + bv;
        }
    } else {
        __hip_bfloat16* hb = (j < 64) ? HB0 : HB1;
        int jj = j & 63;
#pragma unroll
        for (int r = 0; r < 8; ++r) {
            int row = row0 + g + r;
            if (row < nrows) hb[(size_t)row * 64 + jj] = __float2bfloat16(acc[r]);
        }
    }
}

// ---------------- per-node attention scores (reads bf16 halves) ----------------
__global__ __launch_bounds__(256) void scores_k(const __hip_bfloat16* __restrict__ hb0,
                                                const __hip_bfloat16* __restrict__ hb1,
                                                const float* __restrict__ a_src,
                                                const float* __restrict__ a_dst,
                                                float* __restrict__ ss, float* __restrict__ sd,
                                                int n) {
    int wave = (int)((blockIdx.x * 256 + threadIdx.x) >> 6);
    int lane = threadIdx.x & 63;
    if (wave >= n) return;
    float x0 = __bfloat162float(hb0[(size_t)wave * 64 + lane]);
    float x1 = __bfloat162float(hb1[(size_t)wave * 64 + lane]);
    float s = x0 * a_src[lane] + x1 * a_src[64 + lane];
    float d = x0 * a_dst[lane] + x1 * a_dst[64 + lane];
#pragma unroll
    for (int off = 32; off; off >>= 1) {
        s += __shfl_xor(s, off);
        d += __shfl_xor(d, off);
    }
    if (lane == 0) { ss[wave] = s; sd[wave] = d; }
}

// ---------------- CSR build: bucket histogram ----------------
__global__ __launch_bounds__(256) void hist_k(const int* __restrict__ src,
                                              const int* __restrict__ dst,
                                              int* __restrict__ bcnt_d, int* __restrict__ bcnt_s,
                                              int ne, int nb) {
    __shared__ int cnt[2][NB_MAX];
    int tid = threadIdx.x;
    for (int i = tid; i < 2 * NB_MAX; i += 256) ((int*)cnt)[i] = 0;
    __syncthreads();
    for (int i = blockIdx.x * 256 + tid; i < ne; i += gridDim.x * 256) {
        atomicAdd(&cnt[0][dst[i] >> 7], 1);
        atomicAdd(&cnt[1][src[i] >> 7], 1);
    }
    __syncthreads();
    for (int i = tid; i < nb; i += 256) {
        if (cnt[0][i]) atomicAdd(&bcnt_d[i], cnt[0][i]);
        if (cnt[1][i]) atomicAdd(&bcnt_s[i], cnt[1][i]);
    }
}

// ---------------- CSR build: bucket exclusive scan (1 block) ----------------
__global__ __launch_bounds__(256) void bscan_k(const int* __restrict__ bcnt_d,
                                               const int* __restrict__ bcnt_s,
                                               int* bbase_d, int* bbase_s,
                                               int* bcur_d, int* bcur_s,
                                               int* rp_d, int* rp_s,
                                               int nb, int n, int ne) {
    __shared__ int buf[256];
    int tid = threadIdx.x;
#pragma unroll
    for (int a = 0; a < 2; ++a) {
        const int* c = a ? bcnt_s : bcnt_d;
        int* bb = a ? bbase_s : bbase_d;
        int* bc = a ? bcur_s : bcur_d;
        int v = (tid < nb) ? c[tid] : 0;
        buf[tid] = v;
        __syncthreads();
        for (int off = 1; off < 256; off <<= 1) {
            int t = (tid >= off) ? buf[tid - off] : 0;
            __syncthreads();
            buf[tid] += t;
            __syncthreads();
        }
        int excl = buf[tid] - v;
        if (tid < nb) { bb[tid] = excl; bc[tid] = excl; }
        if (tid == nb - 1) bb[nb] = buf[tid];
        __syncthreads();
    }
    if (tid == 0) { rp_d[n] = ne; rp_s[n] = ne; }
}

// ---------------- CSR build: LDS-aggregated partition into bucket regions ----------------
#define EPT 8
__global__ __launch_bounds__(256) void part_k(const int* __restrict__ src,
                                              const int* __restrict__ dst,
                                              int* __restrict__ bcur_d, int* __restrict__ bcur_s,
                                              uint32_t* __restrict__ rec_d, uint32_t* __restrict__ rec_s,
                                              int ne) {
    __shared__ int cnt[2][NB_MAX];
    __shared__ int base[2][NB_MAX];
    int tid = threadIdx.x;
    int blockStart = blockIdx.x * 256 * EPT;
    for (int i = tid; i < 2 * NB_MAX; i += 256) ((int*)cnt)[i] = 0;
    __syncthreads();
    int s[EPT], d[EPT], sl_d[EPT], sl_s[EPT];
#pragma unroll
    for (int e = 0; e < EPT; ++e) {
        int i = blockStart + e * 256 + tid;
        s[e] = -1;
        if (i < ne) {
            s[e] = src[i]; d[e] = dst[i];
            sl_d[e] = atomicAdd(&cnt[0][d[e] >> 7], 1);
            sl_s[e] = atomicAdd(&cnt[1][s[e] >> 7], 1);
        }
    }
    __syncthreads();
    for (int i = tid; i < NB_MAX; i += 256) {
        if (cnt[0][i]) base[0][i] = atomicAdd(&bcur_d[i], cnt[0][i]);
        if (cnt[1][i]) base[1][i] = atomicAdd(&bcur_s[i], cnt[1][i]);
    }
    __syncthreads();
#pragma unroll
    for (int e = 0; e < EPT; ++e) {
        if (s[e] >= 0) {
            rec_d[base[0][d[e] >> 7] + sl_d[e]] = (uint32_t)s[e] | ((uint32_t)(d[e] & 127) << 17);
            rec_s[base[1][s[e] >> 7] + sl_s[e]] = (uint32_t)d[e] | ((uint32_t)(s[e] & 127) << 17);
        }
    }
}

// ---------------- CSR build: per-bucket local fill (grid = (nb, 2)) ----------------
__global__ __launch_bounds__(256) void csrfill_k(const uint32_t* __restrict__ rec_d,
                                                 const uint32_t* __restrict__ rec_s,
                                                 const int* __restrict__ bbase_d,
                                                 const int* __restrict__ bbase_s,
                                                 int* __restrict__ rp_d, int* __restrict__ rp_s,
                                                 int* __restrict__ nbr_d, int* __restrict__ nbr_s,
                                                 int n) {
    const uint32_t* rec = blockIdx.y ? rec_s : rec_d;
    const int* bbase    = blockIdx.y ? bbase_s : bbase_d;
    int* rp             = blockIdx.y ? rp_s : rp_d;
    int* nbr            = blockIdx.y ? nbr_s : nbr_d;
    int b = blockIdx.x;
    int tid = threadIdx.x;
    int beg = bbase[b], end = bbase[b + 1];
    __shared__ int deg[BKT_W];
    __shared__ int sbuf[BKT_W];
    __shared__ int cur[BKT_W];
    if (tid < BKT_W) deg[tid] = 0;
    __syncthreads();
    for (int j = beg + tid; j < end; j += 256) atomicAdd(&deg[rec[j] >> 17], 1);
    __syncthreads();
    if (tid < BKT_W) sbuf[tid] = deg[tid];
    __syncthreads();
    for (int off = 1; off < BKT_W; off <<= 1) {
        int t = (tid < BKT_W && tid >= off) ? sbuf[tid - off] : 0;
        __syncthreads();
        if (tid < BKT_W) sbuf[tid] += t;
        __syncthreads();
    }
    if (tid < BKT_W) {
        int abs0 = beg + sbuf[tid] - deg[tid];
        cur[tid] = abs0;
        int node = b * BKT_W + tid;
        if (node < n) rp[node] = abs0;
    }
    __syncthreads();
    for (int j = beg + tid; j < end; j += 256) {
        uint32_t r = rec[j];
        nbr[atomicAdd(&cur[r >> 17], 1)] = (int)(r & 0x1FFFFu);
    }
}

// ---------------- per-edge alpha: lane-parallel per node ----------------
__global__ __launch_bounds__(256) void alpha_k(const int* __restrict__ rowptr,
                                               const int* __restrict__ nbrs,
                                               const float* __restrict__ score_nb,
                                               const float* __restrict__ score_self,
                                               float* __restrict__ alpha, int n) {
    int wave = (int)((blockIdx.x * 256 + threadIdx.x) >> 6);
    int lane = threadIdx.x & 63;
    if (wave >= n) return;
    int beg = rowptr[wave], end = rowptr[wave + 1];
    float sself = score_self[wave];
    float wsum = 0.f;
    for (int j = beg + lane; j < end; j += 64) {
        int nb = nbrs[j];
        float e = score_nb[nb] + sself;
        e = (e > 0.f) ? e : 0.2f * e;
        float w = __expf(e);
        alpha[j] = w;
        wsum += w;
    }
#pragma unroll
    for (int off = 32; off; off >>= 1) wsum += __shfl_xor(wsum, off);
    float inv = 1.0f / (wsum + 1e-16f);
    for (int j = beg + lane; j < end; j += 64) alpha[j] *= inv;
}

// ---------------- GAT gather, one 64-col half per pass; 8-deep MLP unroll ----------------
__global__ __launch_bounds__(256) void gat_gather_half_k(const int* __restrict__ rowptr,
                                                         const int* __restrict__ nbrs,
                                                         const float* __restrict__ alpha,
                                                         const __hip_bfloat16* __restrict__ hbh,
                                                         const float* __restrict__ bias,
                                                         const float* __restrict__ resid,
                                                         float* __restrict__ out, int n, int half) {
    int wave = (int)((blockIdx.x * 256 + threadIdx.x) >> 6);
    int lane = threadIdx.x & 63;
    if (wave >= n) return;
    int beg = rowptr[wave], end = rowptr[wave + 1];
    float acc0 = 0.f, acc1 = 0.f, acc2 = 0.f, acc3 = 0.f;
    int j = beg;
    for (; j + 8 <= end; j += 8) {
        int   nb0 = nbrs[j],     nb1 = nbrs[j + 1], nb2 = nbrs[j + 2], nb3 = nbrs[j + 3];
        int   nb4 = nbrs[j + 4], nb5 = nbrs[j + 5], nb6 = nbrs[j + 6], nb7 = nbrs[j + 7];
        float a0 = alpha[j],     a1 = alpha[j + 1], a2 = alpha[j + 2], a3 = alpha[j + 3];
        float a4 = alpha[j + 4], a5 = alpha[j + 5], a6 = alpha[j + 6], a7 = alpha[j + 7];
        float h0 = __bfloat162float(hbh[(size_t)nb0 * 64 + lane]);
        float h1 = __bfloat162float(hbh[(size_t)nb1 * 64 + lane]);
        float h2 = __bfloat162float(hbh[(size_t)nb2 * 64 + lane]);
        float h3 = __bfloat162float(hbh[(size_t)nb3 * 64 + lane]);
        float h4 = __bfloat162float(hbh[(size_t)nb4 * 64 + lane]);
        float h5 = __bfloat162float(hbh[(size_t)nb5 * 64 + lane]);
        float h6 = __bfloat162float(hbh[(size_t)nb6 * 64 + lane]);
        float h7 = __bfloat162float(hbh[(size_t)nb7 * 64 + lane]);
        acc0 += a0 * h0; acc1 += a1 * h1; acc2 += a2 * h2; acc3 += a3 * h3;
        acc0 += a4 * h4; acc1 += a5 * h5; acc2 += a6 * h6; acc3 += a7 * h7;
    }
    for (; j < end; ++j)
        acc0 += alpha[j] * __bfloat162float(hbh[(size_t)nbrs[j] * 64 + lane]);
    float acc = (acc0 + acc1) + (acc2 + acc3);
    size_t o = (size_t)wave * D + (size_t)half * 64 + lane;
    out[o] = acc + bias[half * 64 + lane] + __builtin_nontemporal_load(&resid[o]);
}

// ---------------- host ----------------
extern "C" void kernel_launch(void* const* d_in, const int* in_sizes, int n_in,
                              void* d_out, int out_size, void* d_ws, size_t ws_size,
                              hipStream_t stream) {
    const float* Xw    = (const float*)d_in[0];
    const float* Xs    = (const float*)d_in[1];
    const int*   edge  = (const int*)d_in[2];
    const float* W_s2w = (const float*)d_in[3];
    const float* as1   = (const float*)d_in[4];
    const float* ad1   = (const float*)d_in[5];
    const float* b1    = (const float*)d_in[6];
    const float* W_w2s = (const float*)d_in[7];
    const float* as2   = (const float*)d_in[8];
    const float* ad2   = (const float*)d_in[9];
    const float* b2    = (const float*)d_in[10];
    const float* W_lin = (const float*)d_in[11];
    const float* b_lin = (const float*)d_in[12];
    float* out = (float*)d_out;

    const int N  = in_sizes[0] / D;       // 20000
    const int NE = in_sizes[2] / 2;       // 640000
    const int NB = (N + BKT_W - 1) / BKT_W;
    const int* e_src = edge;
    const int* e_dst = edge + NE;

    char* p = (char*)d_ws;
    auto take = [&](size_t bytes) -> void* {
        p = (char*)(((uintptr_t)p + 255) & ~(uintptr_t)255);
        void* r = (void*)p;
        p += bytes;
        return r;
    };
    __hip_bfloat16* hb1_0 = (__hip_bfloat16*)take((size_t)N * 64 * 2);
    __hip_bfloat16* hb1_1 = (__hip_bfloat16*)take((size_t)N * 64 * 2);
    __hip_bfloat16* hb2_0 = (__hip_bfloat16*)take((size_t)N * 64 * 2);
    __hip_bfloat16* hb2_1 = (__hip_bfloat16*)take((size_t)N * 64 * 2);
    float* ss1  = (float*)take((size_t)N * 4);
    float* sd1  = (float*)take((size_t)N * 4);
    float* ss2  = (float*)take((size_t)N * 4);
    float* sd2  = (float*)take((size_t)N * 4);
    float* alpha1 = (float*)take((size_t)NE * 4);
    float* alpha2 = (float*)take((size_t)NE * 4);
    int*   bcnt = (int*)take((size_t)2 * NB * 4);
    int*   bcnt_d = bcnt;
    int*   bcnt_s = bcnt + NB;
    int*   bbase_d = (int*)take((size_t)(NB + 1) * 4);
    int*   bbase_s = (int*)take((size_t)(NB + 1) * 4);
    int*   bcur_d  = (int*)take((size_t)NB * 4);
    int*   bcur_s  = (int*)take((size_t)NB * 4);
    int*   rp_d = (int*)take((size_t)(N + 1) * 4);
    int*   rp_s = (int*)take((size_t)(N + 1) * 4);
    uint32_t* rec_d = (uint32_t*)take((size_t)NE * 4);
    uint32_t* rec_s = (uint32_t*)take((size_t)NE * 4);
    int*   nbr_d = (int*)take((size_t)NE * 4);
    int*   nbr_s = (int*)take((size_t)NE * 4);

    float* t1 = out;
    float* t2 = out + (size_t)N * D;

    hipMemsetAsync(bcnt, 0, (size_t)2 * NB * 4, stream);

    int gemmGrid = (N + 15) / 16;
    // h (bf16 halves): h1 = Xs @ W_s2w ; h2 = Xw @ W_w2s
    gemm128_k<1><<<gemmGrid, 256, 0, stream>>>(Xs, W_s2w, nullptr, nullptr, hb1_0, hb1_1, N);
    gemm128_k<1><<<gemmGrid, 256, 0, stream>>>(Xw, W_w2s, nullptr, nullptr, hb2_0, hb2_1, N);

    int nodeWaveGrid = (N + 3) / 4;
    scores_k<<<nodeWaveGrid, 256, 0, stream>>>(hb1_0, hb1_1, as1, ad1, ss1, sd1, N);
    scores_k<<<nodeWaveGrid, 256, 0, stream>>>(hb2_0, hb2_1, as2, ad2, ss2, sd2, N);

    // CSR build
    hist_k<<<512, 256, 0, stream>>>(e_src, e_dst, bcnt_d, bcnt_s, NE, NB);
    bscan_k<<<1, 256, 0, stream>>>(bcnt_d, bcnt_s, bbase_d, bbase_s, bcur_d, bcur_s,
                                   rp_d, rp_s, NB, N, NE);
    int partGrid = (NE + 256 * EPT - 1) / (256 * EPT);
    part_k<<<partGrid, 256, 0, stream>>>(e_src, e_dst, bcur_d, bcur_s, rec_d, rec_s, NE);
    dim3 fillGrid(NB, 2);
    csrfill_k<<<fillGrid, 256, 0, stream>>>(rec_d, rec_s, bbase_d, bbase_s,
                                            rp_d, rp_s, nbr_d, nbr_s, N);

    // per-edge normalized attention weights
    alpha_k<<<nodeWaveGrid, 256, 0, stream>>>(rp_d, nbr_d, ss1, sd1, alpha1, N);
    alpha_k<<<nodeWaveGrid, 256, 0, stream>>>(rp_s, nbr_s, ss2, sd2, alpha2, N);

    // gathers: one 2.5 MB-footprint half at a time (L2-resident), sequential passes
    gat_gather_half_k<<<nodeWaveGrid, 256, 0, stream>>>(rp_d, nbr_d, alpha1, hb1_0, b1, Xw, t1, N, 0);
    gat_gather_half_k<<<nodeWaveGrid, 256, 0, stream>>>(rp_d, nbr_d, alpha1, hb1_1, b1, Xw, t1, N, 1);
    gat_gather_half_k<<<nodeWaveGrid, 256, 0, stream>>>(rp_s, nbr_s, alpha2, hb2_0, b2, Xs, t2, N, 0);
    gat_gather_half_k<<<nodeWaveGrid, 256, 0, stream>>>(rp_s, nbr_s, alpha2, hb2_1, b2, Xs, t2, N, 1);

    // epilogue: out = t @ W_lin + b_lin (in-place safe: block stages rows first)
    gemm128_k<0><<<gemmGrid, 256, 0, stream>>>(t1, W_lin, b_lin, t1, nullptr, nullptr, N);
    gemm128_k<0><<<gemmGrid, 256, 0, stream>>>(t2, W_lin, b_lin, t2, nullptr, nullptr, N);
}

// Round 4
// 193.269 us; speedup vs baseline: 2.1393x; 1.2810x over previous
//
#include <hip/hip_runtime.h>
#include <hip/hip_bf16.h>
#include <stdint.h>

#define D 128
#define BKT_W 128            // nodes per bucket
#define NB_MAX 256           // supports N <= 32768

// ---------------- GEMM: OUT[r,:] = IN[r,:] @ W (+bias). 16 rows/block. ----------------
// MODE 0: write f32 OUT (+bias), in-place safe (stages rows first).
// MODE 1: write bf16 full rows HB + fused per-row scores ss = h.a_src, sd = h.a_dst.
template <int MODE>
__global__ __launch_bounds__(256) void gemm128_k(const float* __restrict__ IN,
                                                 const float* __restrict__ W,
                                                 const float* __restrict__ bias,
                                                 float* __restrict__ OUT,
                                                 __hip_bfloat16* __restrict__ HB,
                                                 const float* __restrict__ a_src,
                                                 const float* __restrict__ a_dst,
                                                 float* __restrict__ ssO,
                                                 float* __restrict__ sdO,
                                                 int nrows) {
    __shared__ float xs[16][132];
    __shared__ float ps[2][2][8][2];   // [rowgrp][colhalf][r][src/dst]
    int row0 = blockIdx.x * 16;
    int tid  = threadIdx.x;
    const float4* in4 = (const float4*)(IN + (size_t)row0 * D);
#pragma unroll
    for (int it = 0; it < 2; ++it) {
        int idx = tid + it * 256;
        int r = idx >> 5;
        int k = (idx & 31) * 4;
        float4 v = make_float4(0.f, 0.f, 0.f, 0.f);
        if (row0 + r < nrows) v = in4[idx];
        xs[r][k] = v.x; xs[r][k + 1] = v.y; xs[r][k + 2] = v.z; xs[r][k + 3] = v.w;
    }
    __syncthreads();
    int j = tid & 127;
    int g = (tid >> 7) * 8;
    float acc[8] = {0, 0, 0, 0, 0, 0, 0, 0};
    for (int k0 = 0; k0 < D; k0 += 4) {
        float w0 = W[(k0 + 0) * D + j];
        float w1 = W[(k0 + 1) * D + j];
        float w2 = W[(k0 + 2) * D + j];
        float w3 = W[(k0 + 3) * D + j];
#pragma unroll
        for (int r = 0; r < 8; ++r) {
            const float4 xv = *(const float4*)&xs[g + r][k0];
            acc[r] += xv.x * w0;
            acc[r] += xv.y * w1;
            acc[r] += xv.z * w2;
            acc[r] += xv.w * w3;
        }
    }
    if (MODE == 0) {
        float bv = bias ? bias[j] : 0.0f;
#pragma unroll
        for (int r = 0; r < 8; ++r) {
            int row = row0 + g + r;
            if (row < nrows) OUT[(size_t)row * D + j] = acc[r] + bv;
        }
    } else {
#pragma unroll
        for (int r = 0; r < 8; ++r) {
            int row = row0 + g + r;
            if (row < nrows) HB[(size_t)row * D + j] = __float2bfloat16(acc[r]);
        }
        // fused scores: per row, reduce acc*a over the 128 cols (2 waves)
        float asj = a_src[j], adj = a_dst[j];
        float vs[8], vd[8];
#pragma unroll
        for (int r = 0; r < 8; ++r) { vs[r] = acc[r] * asj; vd[r] = acc[r] * adj; }
#pragma unroll
        for (int off = 1; off < 64; off <<= 1) {
#pragma unroll
            for (int r = 0; r < 8; ++r) {
                vs[r] += __shfl_xor(vs[r], off);
                vd[r] += __shfl_xor(vd[r], off);
            }
        }
        if ((tid & 63) == 0) {
            int rg = tid >> 7, ch = (tid >> 6) & 1;
#pragma unroll
            for (int r = 0; r < 8; ++r) { ps[rg][ch][r][0] = vs[r]; ps[rg][ch][r][1] = vd[r]; }
        }
        __syncthreads();
        if (tid < 16) {
            int rg = tid >> 3, r = tid & 7;
            int row = row0 + rg * 8 + r;
            if (row < nrows) {
                ssO[row] = ps[rg][0][r][0] + ps[rg][1][r][0];
                sdO[row] = ps[rg][0][r][1] + ps[rg][1][r][1];
            }
        }
    }
}

// ---------------- combined in-place epilogue GEMM: buf[dir] = buf[dir] @ W + b ----------------
__global__ __launch_bounds__(256) void gemm_ep_k(float* __restrict__ buf,
                                                 const float* __restrict__ W,
                                                 const float* __restrict__ bias,
                                                 int nrows) {
    float* t = buf + (size_t)blockIdx.y * nrows * D;
    __shared__ float xs[16][132];
    int row0 = blockIdx.x * 16;
    int tid  = threadIdx.x;
    const float4* in4 = (const float4*)(t + (size_t)row0 * D);
#pragma unroll
    for (int it = 0; it < 2; ++it) {
        int idx = tid + it * 256;
        int r = idx >> 5;
        int k = (idx & 31) * 4;
        float4 v = make_float4(0.f, 0.f, 0.f, 0.f);
        if (row0 + r < nrows) v = in4[idx];
        xs[r][k] = v.x; xs[r][k + 1] = v.y; xs[r][k + 2] = v.z; xs[r][k + 3] = v.w;
    }
    __syncthreads();
    int j = tid & 127;
    int g = (tid >> 7) * 8;
    float acc[8] = {0, 0, 0, 0, 0, 0, 0, 0};
    for (int k0 = 0; k0 < D; k0 += 4) {
        float w0 = W[(k0 + 0) * D + j];
        float w1 = W[(k0 + 1) * D + j];
        float w2 = W[(k0 + 2) * D + j];
        float w3 = W[(k0 + 3) * D + j];
#pragma unroll
        for (int r = 0; r < 8; ++r) {
            const float4 xv = *(const float4*)&xs[g + r][k0];
            acc[r] += xv.x * w0;
            acc[r] += xv.y * w1;
            acc[r] += xv.z * w2;
            acc[r] += xv.w * w3;
        }
    }
    float bv = bias[j];
#pragma unroll
    for (int r = 0; r < 8; ++r) {
        int row = row0 + g + r;
        if (row < nrows) t[(size_t)row * D + j] = acc[r] + bv;
    }
}

// ---------------- CSR build: bucket histogram ----------------
__global__ __launch_bounds__(256) void hist_k(const int* __restrict__ src,
                                              const int* __restrict__ dst,
                                              int* __restrict__ bcnt_d, int* __restrict__ bcnt_s,
                                              int ne, int nb) {
    __shared__ int cnt[2][NB_MAX];
    int tid = threadIdx.x;
    for (int i = tid; i < 2 * NB_MAX; i += 256) ((int*)cnt)[i] = 0;
    __syncthreads();
    for (int i = blockIdx.x * 256 + tid; i < ne; i += gridDim.x * 256) {
        atomicAdd(&cnt[0][dst[i] >> 7], 1);
        atomicAdd(&cnt[1][src[i] >> 7], 1);
    }
    __syncthreads();
    for (int i = tid; i < nb; i += 256) {
        if (cnt[0][i]) atomicAdd(&bcnt_d[i], cnt[0][i]);
        if (cnt[1][i]) atomicAdd(&bcnt_s[i], cnt[1][i]);
    }
}

// ---------------- CSR build: bucket exclusive scan (1 block) ----------------
__global__ __launch_bounds__(256) void bscan_k(const int* __restrict__ bcnt_d,
                                               const int* __restrict__ bcnt_s,
                                               int* bbase_d, int* bbase_s,
                                               int* bcur_d, int* bcur_s,
                                               int* rp_d, int* rp_s,
                                               int nb, int n, int ne) {
    __shared__ int buf[256];
    int tid = threadIdx.x;
#pragma unroll
    for (int a = 0; a < 2; ++a) {
        const int* c = a ? bcnt_s : bcnt_d;
        int* bb = a ? bbase_s : bbase_d;
        int* bc = a ? bcur_s : bcur_d;
        int v = (tid < nb) ? c[tid] : 0;
        buf[tid] = v;
        __syncthreads();
        for (int off = 1; off < 256; off <<= 1) {
            int t = (tid >= off) ? buf[tid - off] : 0;
            __syncthreads();
            buf[tid] += t;
            __syncthreads();
        }
        int excl = buf[tid] - v;
        if (tid < nb) { bb[tid] = excl; bc[tid] = excl; }
        if (tid == nb - 1) bb[nb] = buf[tid];
        __syncthreads();
    }
    if (tid == 0) { rp_d[n] = ne; rp_s[n] = ne; }
}

// ---------------- CSR build: LDS-aggregated partition into bucket regions ----------------
#define EPT 8
__global__ __launch_bounds__(256) void part_k(const int* __restrict__ src,
                                              const int* __restrict__ dst,
                                              int* __restrict__ bcur_d, int* __restrict__ bcur_s,
                                              uint32_t* __restrict__ rec_d, uint32_t* __restrict__ rec_s,
                                              int ne) {
    __shared__ int cnt[2][NB_MAX];
    __shared__ int base[2][NB_MAX];
    int tid = threadIdx.x;
    int blockStart = blockIdx.x * 256 * EPT;
    for (int i = tid; i < 2 * NB_MAX; i += 256) ((int*)cnt)[i] = 0;
    __syncthreads();
    int s[EPT], d[EPT], sl_d[EPT], sl_s[EPT];
#pragma unroll
    for (int e = 0; e < EPT; ++e) {
        int i = blockStart + e * 256 + tid;
        s[e] = -1;
        if (i < ne) {
            s[e] = src[i]; d[e] = dst[i];
            sl_d[e] = atomicAdd(&cnt[0][d[e] >> 7], 1);
            sl_s[e] = atomicAdd(&cnt[1][s[e] >> 7], 1);
        }
    }
    __syncthreads();
    for (int i = tid; i < NB_MAX; i += 256) {
        if (cnt[0][i]) base[0][i] = atomicAdd(&bcur_d[i], cnt[0][i]);
        if (cnt[1][i]) base[1][i] = atomicAdd(&bcur_s[i], cnt[1][i]);
    }
    __syncthreads();
#pragma unroll
    for (int e = 0; e < EPT; ++e) {
        if (s[e] >= 0) {
            rec_d[base[0][d[e] >> 7] + sl_d[e]] = (uint32_t)s[e] | ((uint32_t)(d[e] & 127) << 17);
            rec_s[base[1][s[e] >> 7] + sl_s[e]] = (uint32_t)d[e] | ((uint32_t)(s[e] & 127) << 17);
        }
    }
}

// ---------------- CSR build: per-bucket local fill (grid = (nb, 2)) ----------------
__global__ __launch_bounds__(256) void csrfill_k(const uint32_t* __restrict__ rec_d,
                                                 const uint32_t* __restrict__ rec_s,
                                                 const int* __restrict__ bbase_d,
                                                 const int* __restrict__ bbase_s,
                                                 int* __restrict__ rp_d, int* __restrict__ rp_s,
                                                 int* __restrict__ nbr_d, int* __restrict__ nbr_s,
                                                 int n) {
    const uint32_t* rec = blockIdx.y ? rec_s : rec_d;
    const int* bbase    = blockIdx.y ? bbase_s : bbase_d;
    int* rp             = blockIdx.y ? rp_s : rp_d;
    int* nbr            = blockIdx.y ? nbr_s : nbr_d;
    int b = blockIdx.x;
    int tid = threadIdx.x;
    int beg = bbase[b], end = bbase[b + 1];
    __shared__ int deg[BKT_W];
    __shared__ int sbuf[BKT_W];
    __shared__ int cur[BKT_W];
    if (tid < BKT_W) deg[tid] = 0;
    __syncthreads();
    for (int j = beg + tid; j < end; j += 256) atomicAdd(&deg[rec[j] >> 17], 1);
    __syncthreads();
    if (tid < BKT_W) sbuf[tid] = deg[tid];
    __syncthreads();
    for (int off = 1; off < BKT_W; off <<= 1) {
        int t = (tid < BKT_W && tid >= off) ? sbuf[tid - off] : 0;
        __syncthreads();
        if (tid < BKT_W) sbuf[tid] += t;
        __syncthreads();
    }
    if (tid < BKT_W) {
        int abs0 = beg + sbuf[tid] - deg[tid];
        cur[tid] = abs0;
        int node = b * BKT_W + tid;
        if (node < n) rp[node] = abs0;
    }
    __syncthreads();
    for (int j = beg + tid; j < end; j += 256) {
        uint32_t r = rec[j];
        nbr[atomicAdd(&cur[r >> 17], 1)] = (int)(r & 0x1FFFFu);
    }
}

// ---------------- GAT gather: wave/node, 2 cols/lane (bf16x2), fused alpha+norm+bias+resid ----------------
__global__ __launch_bounds__(256) void gat_gather_k(const int* __restrict__ rowptr,
                                                    const int* __restrict__ nbrs,
                                                    const float* __restrict__ score_nb,
                                                    const float* __restrict__ score_self,
                                                    const __hip_bfloat16* __restrict__ hb,
                                                    const float* __restrict__ bias,
                                                    const float* __restrict__ resid,
                                                    float* __restrict__ out, int n) {
    int wave = (int)((blockIdx.x * 256 + threadIdx.x) >> 6);
    int lane = threadIdx.x & 63;
    if (wave >= n) return;
    int beg = rowptr[wave], end = rowptr[wave + 1];
    float sself = score_self[wave];
    float al0 = 0.f, al1 = 0.f, al2 = 0.f, al3 = 0.f;   // low-col accumulators
    float ah0 = 0.f, ah1 = 0.f, ah2 = 0.f, ah3 = 0.f;   // high-col accumulators
    float wsum = 0.f;
    int j = beg;
    for (; j + 8 <= end; j += 8) {
        int nb[8];
#pragma unroll
        for (int u = 0; u < 8; ++u) nb[u] = nbrs[j + u];
        uint32_t hv[8];
        float sn[8];
#pragma unroll
        for (int u = 0; u < 8; ++u) {
            hv[u] = *(const uint32_t*)(hb + (size_t)nb[u] * D + 2 * lane);
            sn[u] = score_nb[nb[u]];
        }
        float w[8];
#pragma unroll
        for (int u = 0; u < 8; ++u) {
            float e = sn[u] + sself;
            e = (e > 0.f) ? e : 0.2f * e;
            w[u] = __expf(e);
            wsum += w[u];
        }
#pragma unroll
        for (int u = 0; u < 8; ++u) {
            float lo = __uint_as_float(hv[u] << 16);
            float hi = __uint_as_float(hv[u] & 0xFFFF0000u);
            switch (u & 3) {
                case 0: al0 += w[u] * lo; ah0 += w[u] * hi; break;
                case 1: al1 += w[u] * lo; ah1 += w[u] * hi; break;
                case 2: al2 += w[u] * lo; ah2 += w[u] * hi; break;
                case 3: al3 += w[u] * lo; ah3 += w[u] * hi; break;
            }
        }
    }
    for (; j < end; ++j) {
        int nb = nbrs[j];
        uint32_t hv = *(const uint32_t*)(hb + (size_t)nb * D + 2 * lane);
        float e = score_nb[nb] + sself;
        e = (e > 0.f) ? e : 0.2f * e;
        float w = __expf(e);
        wsum += w;
        al0 += w * __uint_as_float(hv << 16);
        ah0 += w * __uint_as_float(hv & 0xFFFF0000u);
    }
    float accL = (al0 + al1) + (al2 + al3);
    float accH = (ah0 + ah1) + (ah2 + ah3);
    float inv = 1.0f / (wsum + 1e-16f);
    size_t o = (size_t)wave * D + 2 * lane;
    float2 rv = *(const float2*)(resid + o);
    float2 ov;
    ov.x = accL * inv + bias[2 * lane]     + rv.x;
    ov.y = accH * inv + bias[2 * lane + 1] + rv.y;
    *(float2*)(out + o) = ov;
}

// ---------------- host ----------------
extern "C" void kernel_launch(void* const* d_in, const int* in_sizes, int n_in,
                              void* d_out, int out_size, void* d_ws, size_t ws_size,
                              hipStream_t stream) {
    const float* Xw    = (const float*)d_in[0];
    const float* Xs    = (const float*)d_in[1];
    const int*   edge  = (const int*)d_in[2];
    const float* W_s2w = (const float*)d_in[3];
    const float* as1   = (const float*)d_in[4];
    const float* ad1   = (const float*)d_in[5];
    const float* b1    = (const float*)d_in[6];
    const float* W_w2s = (const float*)d_in[7];
    const float* as2   = (const float*)d_in[8];
    const float* ad2   = (const float*)d_in[9];
    const float* b2    = (const float*)d_in[10];
    const float* W_lin = (const float*)d_in[11];
    const float* b_lin = (const float*)d_in[12];
    float* out = (float*)d_out;

    const int N  = in_sizes[0] / D;       // 20000
    const int NE = in_sizes[2] / 2;       // 640000
    const int NB = (N + BKT_W - 1) / BKT_W;
    const int* e_src = edge;
    const int* e_dst = edge + NE;

    char* p = (char*)d_ws;
    auto take = [&](size_t bytes) -> void* {
        p = (char*)(((uintptr_t)p + 255) & ~(uintptr_t)255);
        void* r = (void*)p;
        p += bytes;
        return r;
    };
    __hip_bfloat16* hb1 = (__hip_bfloat16*)take((size_t)N * D * 2);
    __hip_bfloat16* hb2 = (__hip_bfloat16*)take((size_t)N * D * 2);
    float* ss1  = (float*)take((size_t)N * 4);
    float* sd1  = (float*)take((size_t)N * 4);
    float* ss2  = (float*)take((size_t)N * 4);
    float* sd2  = (float*)take((size_t)N * 4);
    int*   bcnt = (int*)take((size_t)2 * NB * 4);
    int*   bcnt_d = bcnt;
    int*   bcnt_s = bcnt + NB;
    int*   bbase_d = (int*)take((size_t)(NB + 1) * 4);
    int*   bbase_s = (int*)take((size_t)(NB + 1) * 4);
    int*   bcur_d  = (int*)take((size_t)NB * 4);
    int*   bcur_s  = (int*)take((size_t)NB * 4);
    int*   rp_d = (int*)take((size_t)(N + 1) * 4);
    int*   rp_s = (int*)take((size_t)(N + 1) * 4);
    uint32_t* rec_d = (uint32_t*)take((size_t)NE * 4);
    uint32_t* rec_s = (uint32_t*)take((size_t)NE * 4);
    int*   nbr_d = (int*)take((size_t)NE * 4);
    int*   nbr_s = (int*)take((size_t)NE * 4);

    float* t1 = out;
    float* t2 = out + (size_t)N * D;

    hipMemsetAsync(bcnt, 0, (size_t)2 * NB * 4, stream);

    int gemmGrid = (N + 15) / 16;
    // h (bf16 full rows) + fused scores: h1 = Xs @ W_s2w ; h2 = Xw @ W_w2s
    gemm128_k<1><<<gemmGrid, 256, 0, stream>>>(Xs, W_s2w, nullptr, nullptr, hb1, as1, ad1, ss1, sd1, N);
    gemm128_k<1><<<gemmGrid, 256, 0, stream>>>(Xw, W_w2s, nullptr, nullptr, hb2, as2, ad2, ss2, sd2, N);

    // CSR build
    hist_k<<<512, 256, 0, stream>>>(e_src, e_dst, bcnt_d, bcnt_s, NE, NB);
    bscan_k<<<1, 256, 0, stream>>>(bcnt_d, bcnt_s, bbase_d, bbase_s, bcur_d, bcur_s,
                                   rp_d, rp_s, NB, N, NE);
    int partGrid = (NE + 256 * EPT - 1) / (256 * EPT);
    part_k<<<partGrid, 256, 0, stream>>>(e_src, e_dst, bcur_d, bcur_s, rec_d, rec_s, NE);
    dim3 fillGrid(NB, 2);
    csrfill_k<<<fillGrid, 256, 0, stream>>>(rec_d, rec_s, bbase_d, bbase_s,
                                            rp_d, rp_s, nbr_d, nbr_s, N);

    // gathers: fused alpha (exp per edge) + normalize + bias + residual
    int nodeWaveGrid = (N + 3) / 4;
    gat_gather_k<<<nodeWaveGrid, 256, 0, stream>>>(rp_d, nbr_d, ss1, sd1, hb1, b1, Xw, t1, N);
    gat_gather_k<<<nodeWaveGrid, 256, 0, stream>>>(rp_s, nbr_s, ss2, sd2, hb2, b2, Xs, t2, N);

    // epilogue (both directions in one launch): t = t @ W_lin + b_lin
    dim3 epGrid(gemmGrid, 2);
    gemm_ep_k<<<epGrid, 256, 0, stream>>>(out, W_lin, b_lin, N);
}

// Round 5
// 183.614 us; speedup vs baseline: 2.2518x; 1.0526x over previous
//
#include <hip/hip_runtime.h>
#include <hip/hip_bf16.h>
#include <stdint.h>

#define D 128
#define BKT_W 128            // nodes per bucket
#define NB_MAX 256           // supports N <= 32768

// ---------------- fused h-GEMM (both directions, grid.y selects): ----------------
// HB[y] = IN[y] @ W[y] (bf16 rows), ss[y]/sd[y] = per-row scores
__global__ __launch_bounds__(256) void gemm_h_k(const float* __restrict__ IN0,
                                                const float* __restrict__ IN1,
                                                const float* __restrict__ W0,
                                                const float* __restrict__ W1,
                                                __hip_bfloat16* __restrict__ HB0,
                                                __hip_bfloat16* __restrict__ HB1,
                                                const float* __restrict__ as0,
                                                const float* __restrict__ as1,
                                                const float* __restrict__ ad0,
                                                const float* __restrict__ ad1,
                                                float* __restrict__ ss0,
                                                float* __restrict__ ss1,
                                                float* __restrict__ sd0,
                                                float* __restrict__ sd1,
                                                int nrows) {
    const float* IN = blockIdx.y ? IN1 : IN0;
    const float* W  = blockIdx.y ? W1  : W0;
    __hip_bfloat16* HB = blockIdx.y ? HB1 : HB0;
    const float* a_src = blockIdx.y ? as1 : as0;
    const float* a_dst = blockIdx.y ? ad1 : ad0;
    float* ssO = blockIdx.y ? ss1 : ss0;
    float* sdO = blockIdx.y ? sd1 : sd0;

    __shared__ float xs[16][132];
    __shared__ float ps[2][2][8][2];   // [rowgrp][colhalf][r][src/dst]
    int row0 = blockIdx.x * 16;
    int tid  = threadIdx.x;
    const float4* in4 = (const float4*)(IN + (size_t)row0 * D);
#pragma unroll
    for (int it = 0; it < 2; ++it) {
        int idx = tid + it * 256;
        int r = idx >> 5;
        int k = (idx & 31) * 4;
        float4 v = make_float4(0.f, 0.f, 0.f, 0.f);
        if (row0 + r < nrows) v = in4[idx];
        xs[r][k] = v.x; xs[r][k + 1] = v.y; xs[r][k + 2] = v.z; xs[r][k + 3] = v.w;
    }
    __syncthreads();
    int j = tid & 127;
    int g = (tid >> 7) * 8;
    float acc[8] = {0, 0, 0, 0, 0, 0, 0, 0};
    for (int k0 = 0; k0 < D; k0 += 4) {
        float w0 = W[(k0 + 0) * D + j];
        float w1 = W[(k0 + 1) * D + j];
        float w2 = W[(k0 + 2) * D + j];
        float w3 = W[(k0 + 3) * D + j];
#pragma unroll
        for (int r = 0; r < 8; ++r) {
            const float4 xv = *(const float4*)&xs[g + r][k0];
            acc[r] += xv.x * w0;
            acc[r] += xv.y * w1;
            acc[r] += xv.z * w2;
            acc[r] += xv.w * w3;
        }
    }
#pragma unroll
    for (int r = 0; r < 8; ++r) {
        int row = row0 + g + r;
        if (row < nrows) HB[(size_t)row * D + j] = __float2bfloat16(acc[r]);
    }
    // fused scores: per row, reduce acc*a over the 128 cols (2 waves)
    float asj = a_src[j], adj = a_dst[j];
    float vs[8], vd[8];
#pragma unroll
    for (int r = 0; r < 8; ++r) { vs[r] = acc[r] * asj; vd[r] = acc[r] * adj; }
#pragma unroll
    for (int off = 1; off < 64; off <<= 1) {
#pragma unroll
        for (int r = 0; r < 8; ++r) {
            vs[r] += __shfl_xor(vs[r], off);
            vd[r] += __shfl_xor(vd[r], off);
        }
    }
    if ((tid & 63) == 0) {
        int rg = tid >> 7, ch = (tid >> 6) & 1;
#pragma unroll
        for (int r = 0; r < 8; ++r) { ps[rg][ch][r][0] = vs[r]; ps[rg][ch][r][1] = vd[r]; }
    }
    __syncthreads();
    if (tid < 16) {
        int rg = tid >> 3, r = tid & 7;
        int row = row0 + rg * 8 + r;
        if (row < nrows) {
            ssO[row] = ps[rg][0][r][0] + ps[rg][1][r][0];
            sdO[row] = ps[rg][0][r][1] + ps[rg][1][r][1];
        }
    }
}

// ---------------- combined in-place epilogue GEMM: buf[dir] = buf[dir] @ W + b ----------------
__global__ __launch_bounds__(256) void gemm_ep_k(float* __restrict__ buf,
                                                 const float* __restrict__ W,
                                                 const float* __restrict__ bias,
                                                 int nrows) {
    float* t = buf + (size_t)blockIdx.y * nrows * D;
    __shared__ float xs[16][132];
    int row0 = blockIdx.x * 16;
    int tid  = threadIdx.x;
    const float4* in4 = (const float4*)(t + (size_t)row0 * D);
#pragma unroll
    for (int it = 0; it < 2; ++it) {
        int idx = tid + it * 256;
        int r = idx >> 5;
        int k = (idx & 31) * 4;
        float4 v = make_float4(0.f, 0.f, 0.f, 0.f);
        if (row0 + r < nrows) v = in4[idx];
        xs[r][k] = v.x; xs[r][k + 1] = v.y; xs[r][k + 2] = v.z; xs[r][k + 3] = v.w;
    }
    __syncthreads();
    int j = tid & 127;
    int g = (tid >> 7) * 8;
    float acc[8] = {0, 0, 0, 0, 0, 0, 0, 0};
    for (int k0 = 0; k0 < D; k0 += 4) {
        float w0 = W[(k0 + 0) * D + j];
        float w1 = W[(k0 + 1) * D + j];
        float w2 = W[(k0 + 2) * D + j];
        float w3 = W[(k0 + 3) * D + j];
#pragma unroll
        for (int r = 0; r < 8; ++r) {
            const float4 xv = *(const float4*)&xs[g + r][k0];
            acc[r] += xv.x * w0;
            acc[r] += xv.y * w1;
            acc[r] += xv.z * w2;
            acc[r] += xv.w * w3;
        }
    }
    float bv = bias[j];
#pragma unroll
    for (int r = 0; r < 8; ++r) {
        int row = row0 + g + r;
        if (row < nrows) t[(size_t)row * D + j] = acc[r] + bv;
    }
}

// ---------------- CSR build: bucket histogram ----------------
__global__ __launch_bounds__(256) void hist_k(const int* __restrict__ src,
                                              const int* __restrict__ dst,
                                              int* __restrict__ bcnt_d, int* __restrict__ bcnt_s,
                                              int ne, int nb) {
    __shared__ int cnt[2][NB_MAX];
    int tid = threadIdx.x;
    for (int i = tid; i < 2 * NB_MAX; i += 256) ((int*)cnt)[i] = 0;
    __syncthreads();
    for (int i = blockIdx.x * 256 + tid; i < ne; i += gridDim.x * 256) {
        atomicAdd(&cnt[0][dst[i] >> 7], 1);
        atomicAdd(&cnt[1][src[i] >> 7], 1);
    }
    __syncthreads();
    for (int i = tid; i < nb; i += 256) {
        if (cnt[0][i]) atomicAdd(&bcnt_d[i], cnt[0][i]);
        if (cnt[1][i]) atomicAdd(&bcnt_s[i], cnt[1][i]);
    }
}

// ---------------- CSR build: bucket exclusive scan (1 block) ----------------
__global__ __launch_bounds__(256) void bscan_k(const int* __restrict__ bcnt_d,
                                               const int* __restrict__ bcnt_s,
                                               int* bbase_d, int* bbase_s,
                                               int* bcur_d, int* bcur_s,
                                               int* rp_d, int* rp_s,
                                               int nb, int n, int ne) {
    __shared__ int buf[256];
    int tid = threadIdx.x;
#pragma unroll
    for (int a = 0; a < 2; ++a) {
        const int* c = a ? bcnt_s : bcnt_d;
        int* bb = a ? bbase_s : bbase_d;
        int* bc = a ? bcur_s : bcur_d;
        int v = (tid < nb) ? c[tid] : 0;
        buf[tid] = v;
        __syncthreads();
        for (int off = 1; off < 256; off <<= 1) {
            int t = (tid >= off) ? buf[tid - off] : 0;
            __syncthreads();
            buf[tid] += t;
            __syncthreads();
        }
        int excl = buf[tid] - v;
        if (tid < nb) { bb[tid] = excl; bc[tid] = excl; }
        if (tid == nb - 1) bb[nb] = buf[tid];
        __syncthreads();
    }
    if (tid == 0) { rp_d[n] = ne; rp_s[n] = ne; }
}

// ---------------- CSR build: LDS-aggregated partition into bucket regions ----------------
#define EPT 8
__global__ __launch_bounds__(256) void part_k(const int* __restrict__ src,
                                              const int* __restrict__ dst,
                                              int* __restrict__ bcur_d, int* __restrict__ bcur_s,
                                              uint32_t* __restrict__ rec_d, uint32_t* __restrict__ rec_s,
                                              int ne) {
    __shared__ int cnt[2][NB_MAX];
    __shared__ int base[2][NB_MAX];
    int tid = threadIdx.x;
    int blockStart = blockIdx.x * 256 * EPT;
    for (int i = tid; i < 2 * NB_MAX; i += 256) ((int*)cnt)[i] = 0;
    __syncthreads();
    int s[EPT], d[EPT], sl_d[EPT], sl_s[EPT];
#pragma unroll
    for (int e = 0; e < EPT; ++e) {
        int i = blockStart + e * 256 + tid;
        s[e] = -1;
        if (i < ne) {
            s[e] = src[i]; d[e] = dst[i];
            sl_d[e] = atomicAdd(&cnt[0][d[e] >> 7], 1);
            sl_s[e] = atomicAdd(&cnt[1][s[e] >> 7], 1);
        }
    }
    __syncthreads();
    for (int i = tid; i < NB_MAX; i += 256) {
        if (cnt[0][i]) base[0][i] = atomicAdd(&bcur_d[i], cnt[0][i]);
        if (cnt[1][i]) base[1][i] = atomicAdd(&bcur_s[i], cnt[1][i]);
    }
    __syncthreads();
#pragma unroll
    for (int e = 0; e < EPT; ++e) {
        if (s[e] >= 0) {
            rec_d[base[0][d[e] >> 7] + sl_d[e]] = (uint32_t)s[e] | ((uint32_t)(d[e] & 127) << 17);
            rec_s[base[1][s[e] >> 7] + sl_s[e]] = (uint32_t)d[e] | ((uint32_t)(s[e] & 127) << 17);
        }
    }
}

// ---------------- CSR build: per-bucket local fill (grid = (nb, 2)) ----------------
__global__ __launch_bounds__(256) void csrfill_k(const uint32_t* __restrict__ rec_d,
                                                 const uint32_t* __restrict__ rec_s,
                                                 const int* __restrict__ bbase_d,
                                                 const int* __restrict__ bbase_s,
                                                 int* __restrict__ rp_d, int* __restrict__ rp_s,
                                                 int* __restrict__ nbr_d, int* __restrict__ nbr_s,
                                                 int n) {
    const uint32_t* rec = blockIdx.y ? rec_s : rec_d;
    const int* bbase    = blockIdx.y ? bbase_s : bbase_d;
    int* rp             = blockIdx.y ? rp_s : rp_d;
    int* nbr            = blockIdx.y ? nbr_s : nbr_d;
    int b = blockIdx.x;
    int tid = threadIdx.x;
    int beg = bbase[b], end = bbase[b + 1];
    __shared__ int deg[BKT_W];
    __shared__ int sbuf[BKT_W];
    __shared__ int cur[BKT_W];
    if (tid < BKT_W) deg[tid] = 0;
    __syncthreads();
    for (int j = beg + tid; j < end; j += 256) atomicAdd(&deg[rec[j] >> 17], 1);
    __syncthreads();
    if (tid < BKT_W) sbuf[tid] = deg[tid];
    __syncthreads();
    for (int off = 1; off < BKT_W; off <<= 1) {
        int t = (tid < BKT_W && tid >= off) ? sbuf[tid - off] : 0;
        __syncthreads();
        if (tid < BKT_W) sbuf[tid] += t;
        __syncthreads();
    }
    if (tid < BKT_W) {
        int abs0 = beg + sbuf[tid] - deg[tid];
        cur[tid] = abs0;
        int node = b * BKT_W + tid;
        if (node < n) rp[node] = abs0;
    }
    __syncthreads();
    for (int j = beg + tid; j < end; j += 256) {
        uint32_t r = rec[j];
        nbr[atomicAdd(&cur[r >> 17], 1)] = (int)(r & 0x1FFFFu);
    }
}

// ---------------- GAT gather: wave/node; 4 edges x 16-lane groups, uint4 row loads ----------------
__global__ __launch_bounds__(256) void gat_gather_k(const int* __restrict__ rowptr,
                                                    const int* __restrict__ nbrs,
                                                    const float* __restrict__ score_nb,
                                                    const float* __restrict__ score_self,
                                                    const __hip_bfloat16* __restrict__ hb,
                                                    const float* __restrict__ bias,
                                                    const float* __restrict__ resid,
                                                    float* __restrict__ out, int n) {
    int wave = (int)((blockIdx.x * 256 + threadIdx.x) >> 6);
    int lane = threadIdx.x & 63;
    if (wave >= n) return;
    int beg = rowptr[wave], end = rowptr[wave + 1];
    float sself = score_self[wave];
    int slot = lane >> 4;        // which edge of the group of 4
    int c    = lane & 15;        // col chunk: cols 8c..8c+7
    float acc[8] = {0, 0, 0, 0, 0, 0, 0, 0};
    float wsum = 0.f;
    for (int j = beg; j < end; j += 8) {
        int i0 = j + slot;
        int i1 = j + 4 + slot;
        bool v0 = i0 < end, v1 = i1 < end;
        int nb0 = v0 ? nbrs[i0] : 0;
        int nb1 = v1 ? nbrs[i1] : 0;
        uint4 h0 = *(const uint4*)(hb + (size_t)nb0 * D + c * 8);
        uint4 h1 = *(const uint4*)(hb + (size_t)nb1 * D + c * 8);
        float s0 = v0 ? score_nb[nb0] : 0.f;
        float s1 = v1 ? score_nb[nb1] : 0.f;
        float e0 = s0 + sself; e0 = (e0 > 0.f) ? e0 : 0.2f * e0;
        float e1 = s1 + sself; e1 = (e1 > 0.f) ? e1 : 0.2f * e1;
        float w0 = v0 ? __expf(e0) : 0.f;
        float w1 = v1 ? __expf(e1) : 0.f;
        wsum += w0 + w1;
        const uint32_t* p0 = (const uint32_t*)&h0;
        const uint32_t* p1 = (const uint32_t*)&h1;
#pragma unroll
        for (int q = 0; q < 4; ++q) {
            uint32_t a = p0[q];
            acc[2 * q]     += w0 * __uint_as_float(a << 16);
            acc[2 * q + 1] += w0 * __uint_as_float(a & 0xFFFF0000u);
            uint32_t b = p1[q];
            acc[2 * q]     += w1 * __uint_as_float(b << 16);
            acc[2 * q + 1] += w1 * __uint_as_float(b & 0xFFFF0000u);
        }
    }
    // merge the 4 edge-slots (xor 16, 32)
#pragma unroll
    for (int off = 16; off <= 32; off <<= 1) {
        wsum += __shfl_xor(wsum, off);
#pragma unroll
        for (int r = 0; r < 8; ++r) acc[r] += __shfl_xor(acc[r], off);
    }
    if (lane < 16) {
        float inv = 1.0f / (wsum + 1e-16f);
        size_t o = (size_t)wave * D + c * 8;
        float4 r0 = *(const float4*)(resid + o);
        float4 r1 = *(const float4*)(resid + o + 4);
        float4 o0, o1;
        o0.x = acc[0] * inv + bias[c * 8 + 0] + r0.x;
        o0.y = acc[1] * inv + bias[c * 8 + 1] + r0.y;
        o0.z = acc[2] * inv + bias[c * 8 + 2] + r0.z;
        o0.w = acc[3] * inv + bias[c * 8 + 3] + r0.w;
        o1.x = acc[4] * inv + bias[c * 8 + 4] + r1.x;
        o1.y = acc[5] * inv + bias[c * 8 + 5] + r1.y;
        o1.z = acc[6] * inv + bias[c * 8 + 6] + r1.z;
        o1.w = acc[7] * inv + bias[c * 8 + 7] + r1.w;
        *(float4*)(out + o)     = o0;
        *(float4*)(out + o + 4) = o1;
    }
}

// ---------------- host ----------------
extern "C" void kernel_launch(void* const* d_in, const int* in_sizes, int n_in,
                              void* d_out, int out_size, void* d_ws, size_t ws_size,
                              hipStream_t stream) {
    const float* Xw    = (const float*)d_in[0];
    const float* Xs    = (const float*)d_in[1];
    const int*   edge  = (const int*)d_in[2];
    const float* W_s2w = (const float*)d_in[3];
    const float* as1   = (const float*)d_in[4];
    const float* ad1   = (const float*)d_in[5];
    const float* b1    = (const float*)d_in[6];
    const float* W_w2s = (const float*)d_in[7];
    const float* as2   = (const float*)d_in[8];
    const float* ad2   = (const float*)d_in[9];
    const float* b2    = (const float*)d_in[10];
    const float* W_lin = (const float*)d_in[11];
    const float* b_lin = (const float*)d_in[12];
    float* out = (float*)d_out;

    const int N  = in_sizes[0] / D;       // 20000
    const int NE = in_sizes[2] / 2;       // 640000
    const int NB = (N + BKT_W - 1) / BKT_W;
    const int* e_src = edge;
    const int* e_dst = edge + NE;

    char* p = (char*)d_ws;
    auto take = [&](size_t bytes) -> void* {
        p = (char*)(((uintptr_t)p + 255) & ~(uintptr_t)255);
        void* r = (void*)p;
        p += bytes;
        return r;
    };
    __hip_bfloat16* hb1 = (__hip_bfloat16*)take((size_t)N * D * 2);
    __hip_bfloat16* hb2 = (__hip_bfloat16*)take((size_t)N * D * 2);
    float* ss1  = (float*)take((size_t)N * 4);
    float* sd1  = (float*)take((size_t)N * 4);
    float* ss2  = (float*)take((size_t)N * 4);
    float* sd2  = (float*)take((size_t)N * 4);
    int*   bcnt = (int*)take((size_t)2 * NB * 4);
    int*   bcnt_d = bcnt;
    int*   bcnt_s = bcnt + NB;
    int*   bbase_d = (int*)take((size_t)(NB + 1) * 4);
    int*   bbase_s = (int*)take((size_t)(NB + 1) * 4);
    int*   bcur_d  = (int*)take((size_t)NB * 4);
    int*   bcur_s  = (int*)take((size_t)NB * 4);
    int*   rp_d = (int*)take((size_t)(N + 1) * 4);
    int*   rp_s = (int*)take((size_t)(N + 1) * 4);
    uint32_t* rec_d = (uint32_t*)take((size_t)NE * 4);
    uint32_t* rec_s = (uint32_t*)take((size_t)NE * 4);
    int*   nbr_d = (int*)take((size_t)NE * 4);
    int*   nbr_s = (int*)take((size_t)NE * 4);

    float* t1 = out;
    float* t2 = out + (size_t)N * D;

    hipMemsetAsync(bcnt, 0, (size_t)2 * NB * 4, stream);

    int gemmGrid = (N + 15) / 16;
    // h (bf16 full rows) + fused scores, both directions in one launch
    dim3 hGrid(gemmGrid, 2);
    gemm_h_k<<<hGrid, 256, 0, stream>>>(Xs, Xw, W_s2w, W_w2s, hb1, hb2,
                                        as1, as2, ad1, ad2, ss1, ss2, sd1, sd2, N);

    // CSR build
    hist_k<<<512, 256, 0, stream>>>(e_src, e_dst, bcnt_d, bcnt_s, NE, NB);
    bscan_k<<<1, 256, 0, stream>>>(bcnt_d, bcnt_s, bbase_d, bbase_s, bcur_d, bcur_s,
                                   rp_d, rp_s, NB, N, NE);
    int partGrid = (NE + 256 * EPT - 1) / (256 * EPT);
    part_k<<<partGrid, 256, 0, stream>>>(e_src, e_dst, bcur_d, bcur_s, rec_d, rec_s, NE);
    dim3 fillGrid(NB, 2);
    csrfill_k<<<fillGrid, 256, 0, stream>>>(rec_d, rec_s, bbase_d, bbase_s,
                                            rp_d, rp_s, nbr_d, nbr_s, N);

    // gathers: fused alpha (exp per edge) + normalize + bias + residual
    int nodeWaveGrid = (N + 3) / 4;
    gat_gather_k<<<nodeWaveGrid, 256, 0, stream>>>(rp_d, nbr_d, ss1, sd1, hb1, b1, Xw, t1, N);
    gat_gather_k<<<nodeWaveGrid, 256, 0, stream>>>(rp_s, nbr_s, ss2, sd2, hb2, b2, Xs, t2, N);

    // epilogue (both directions in one launch): t = t @ W_lin + b_lin
    dim3 epGrid(gemmGrid, 2);
    gemm_ep_k<<<epGrid, 256, 0, stream>>>(out, W_lin, b_lin, N);
}

// Round 6
// 148.905 us; speedup vs baseline: 2.7767x; 1.2331x over previous
//
#include <hip/hip_runtime.h>
#include <hip/hip_bf16.h>
#include <stdint.h>

#define D 128
#define BKT_W 128            // nodes per bucket
#define NB_MAX 256           // supports N <= 32768
#define RPB 128              // rows per block in MFMA GEMMs

typedef __attribute__((ext_vector_type(8))) short bf16x8;
typedef __attribute__((ext_vector_type(4))) float f32x4;

static __device__ __forceinline__ short f2bf(float x) {
    __hip_bfloat16 h = __float2bfloat16(x);
    return *reinterpret_cast<short*>(&h);
}

// ---------------- W pre-pack into MFMA B-fragment order (3 matrices) ----------------
// frag (kc, ct), lane l, elem e  <-  W[k][col], k = kc*32 + 4*(l>>4) + (e&3) + 16*(e>>2),
// col = ct*16 + (l&15).  Pk flat: ((kc*8+ct)*64 + l)*8 + e
__global__ __launch_bounds__(256) void pack_w_k(const float* __restrict__ W0,
                                                const float* __restrict__ W1,
                                                const float* __restrict__ W2,
                                                short* __restrict__ P0,
                                                short* __restrict__ P1,
                                                short* __restrict__ P2) {
    int t = blockIdx.x * 256 + threadIdx.x;      // 3 * 2048 threads
    int m = t >> 11;
    int r = t & 2047;                            // (kc*8+ct)*64 + lane
    const float* W = (m == 0) ? W0 : (m == 1) ? W1 : W2;
    short*       P = (m == 0) ? P0 : (m == 1) ? P1 : P2;
    int lane = r & 63;
    int fr   = r >> 6;                           // kc*8 + ct
    int kc = fr >> 3, ct = fr & 7;
    int col = ct * 16 + (lane & 15);
    int kb  = kc * 32 + 4 * (lane >> 4);
    short v[8];
#pragma unroll
    for (int e = 0; e < 8; ++e) {
        int k = kb + (e & 3) + 16 * (e >> 2);
        v[e] = f2bf(W[k * D + col]);
    }
    short* dst = P + (size_t)r * 8;
#pragma unroll
    for (int e = 0; e < 8; ++e) dst[e] = v[e];
}

// ---------------- MFMA h-GEMM (both dirs): HB = bf16(IN @ W), fused scores ----------------
__global__ __launch_bounds__(256) void mfma_h_k(const float* __restrict__ IN0,
                                                const float* __restrict__ IN1,
                                                const short* __restrict__ P0,
                                                const short* __restrict__ P1,
                                                short* __restrict__ HB0,
                                                short* __restrict__ HB1,
                                                const float* __restrict__ as0,
                                                const float* __restrict__ as1,
                                                const float* __restrict__ ad0,
                                                const float* __restrict__ ad1,
                                                float* __restrict__ ss0,
                                                float* __restrict__ ss1,
                                                float* __restrict__ sd0,
                                                float* __restrict__ sd1,
                                                int nrows) {
    const float* IN = blockIdx.y ? IN1 : IN0;
    const short* PK = blockIdx.y ? P1  : P0;
    short*       HB = blockIdx.y ? HB1 : HB0;
    const float* a_src = blockIdx.y ? as1 : as0;
    const float* a_dst = blockIdx.y ? ad1 : ad0;
    float* ss = blockIdx.y ? ss1 : ss0;
    float* sd = blockIdx.y ? sd1 : sd0;

    __shared__ short As[RPB * 136];
    int row0 = blockIdx.x * RPB;
    int tid  = threadIdx.x;
    const float4* in4 = (const float4*)IN;
#pragma unroll
    for (int i = 0; i < 16; ++i) {
        int idx = tid + i * 256;
        int row = idx >> 5;               // 32 float4 per row
        int q   = idx & 31;
        float4 v = make_float4(0.f, 0.f, 0.f, 0.f);
        int grow = row0 + row;
        if (grow < nrows) v = in4[(size_t)grow * 32 + q];
        int kc = q >> 3, hi = (q >> 2) & 1, g2 = q & 3;
        short4 s4;
        s4.x = f2bf(v.x); s4.y = f2bf(v.y); s4.z = f2bf(v.z); s4.w = f2bf(v.w);
        *(short4*)&As[row * 136 + kc * 32 + g2 * 8 + hi * 4] = s4;
    }
    __syncthreads();

    int lane = tid & 63;
    int wv   = tid >> 6;
    const bf16x8* Wf = (const bf16x8*)PK;
    f32x4 acc[2][8] = {};
#pragma unroll
    for (int kc = 0; kc < 4; ++kc) {
        bf16x8 a0 = *(const bf16x8*)&As[(wv * 32 +      (lane & 15)) * 136 + kc * 32 + (lane >> 4) * 8];
        bf16x8 a1 = *(const bf16x8*)&As[(wv * 32 + 16 + (lane & 15)) * 136 + kc * 32 + (lane >> 4) * 8];
#pragma unroll
        for (int ct = 0; ct < 8; ++ct) {
            bf16x8 b = Wf[(kc * 8 + ct) * 64 + lane];
            acc[0][ct] = __builtin_amdgcn_mfma_f32_16x16x32_bf16(a0, b, acc[0][ct], 0, 0, 0);
            acc[1][ct] = __builtin_amdgcn_mfma_f32_16x16x32_bf16(a1, b, acc[1][ct], 0, 0, 0);
        }
    }

    // epilogue: D layout col = lane&15, row = (lane>>4)*4 + reg
    int cb = lane & 15, rg = lane >> 4;
    float asv[8], adv[8];
#pragma unroll
    for (int ct = 0; ct < 8; ++ct) { asv[ct] = a_src[ct * 16 + cb]; adv[ct] = a_dst[ct * 16 + cb]; }
#pragma unroll
    for (int rt = 0; rt < 2; ++rt) {
        float ssum[4] = {0, 0, 0, 0}, dsum[4] = {0, 0, 0, 0};
#pragma unroll
        for (int ct = 0; ct < 8; ++ct) {
#pragma unroll
            for (int r = 0; r < 4; ++r) {
                float x = acc[rt][ct][r];
                int grow = row0 + wv * 32 + rt * 16 + rg * 4 + r;
                if (grow < nrows) HB[(size_t)grow * D + ct * 16 + cb] = f2bf(x);
                ssum[r] += x * asv[ct];
                dsum[r] += x * adv[ct];
            }
        }
#pragma unroll
        for (int off = 1; off < 16; off <<= 1) {
#pragma unroll
            for (int r = 0; r < 4; ++r) {
                ssum[r] += __shfl_xor(ssum[r], off);
                dsum[r] += __shfl_xor(dsum[r], off);
            }
        }
        if (cb == 0) {
#pragma unroll
            for (int r = 0; r < 4; ++r) {
                int grow = row0 + wv * 32 + rt * 16 + rg * 4 + r;
                if (grow < nrows) { ss[grow] = ssum[r]; sd[grow] = dsum[r]; }
            }
        }
    }
}

// ---------------- MFMA epilogue GEMM, in-place, both dirs: t = t @ W_lin + b ----------------
__global__ __launch_bounds__(256) void mfma_ep_k(float* __restrict__ buf,
                                                 const short* __restrict__ PK,
                                                 const float* __restrict__ bias,
                                                 int nrows) {
    float* T = buf + (size_t)blockIdx.y * nrows * D;
    __shared__ short As[RPB * 136];
    int row0 = blockIdx.x * RPB;
    int tid  = threadIdx.x;
    const float4* in4 = (const float4*)T;
#pragma unroll
    for (int i = 0; i < 16; ++i) {
        int idx = tid + i * 256;
        int row = idx >> 5;
        int q   = idx & 31;
        float4 v = make_float4(0.f, 0.f, 0.f, 0.f);
        int grow = row0 + row;
        if (grow < nrows) v = in4[(size_t)grow * 32 + q];
        int kc = q >> 3, hi = (q >> 2) & 1, g2 = q & 3;
        short4 s4;
        s4.x = f2bf(v.x); s4.y = f2bf(v.y); s4.z = f2bf(v.z); s4.w = f2bf(v.w);
        *(short4*)&As[row * 136 + kc * 32 + g2 * 8 + hi * 4] = s4;
    }
    __syncthreads();

    int lane = tid & 63;
    int wv   = tid >> 6;
    const bf16x8* Wf = (const bf16x8*)PK;
    f32x4 acc[2][8] = {};
#pragma unroll
    for (int kc = 0; kc < 4; ++kc) {
        bf16x8 a0 = *(const bf16x8*)&As[(wv * 32 +      (lane & 15)) * 136 + kc * 32 + (lane >> 4) * 8];
        bf16x8 a1 = *(const bf16x8*)&As[(wv * 32 + 16 + (lane & 15)) * 136 + kc * 32 + (lane >> 4) * 8];
#pragma unroll
        for (int ct = 0; ct < 8; ++ct) {
            bf16x8 b = Wf[(kc * 8 + ct) * 64 + lane];
            acc[0][ct] = __builtin_amdgcn_mfma_f32_16x16x32_bf16(a0, b, acc[0][ct], 0, 0, 0);
            acc[1][ct] = __builtin_amdgcn_mfma_f32_16x16x32_bf16(a1, b, acc[1][ct], 0, 0, 0);
        }
    }

    int cb = lane & 15, rg = lane >> 4;
    float bv[8];
#pragma unroll
    for (int ct = 0; ct < 8; ++ct) bv[ct] = bias[ct * 16 + cb];
#pragma unroll
    for (int rt = 0; rt < 2; ++rt) {
#pragma unroll
        for (int ct = 0; ct < 8; ++ct) {
#pragma unroll
            for (int r = 0; r < 4; ++r) {
                int grow = row0 + wv * 32 + rt * 16 + rg * 4 + r;
                if (grow < nrows) T[(size_t)grow * D + ct * 16 + cb] = acc[rt][ct][r] + bv[ct];
            }
        }
    }
}

// ---------------- CSR build: bucket histogram ----------------
__global__ __launch_bounds__(256) void hist_k(const int* __restrict__ src,
                                              const int* __restrict__ dst,
                                              int* __restrict__ bcnt_d, int* __restrict__ bcnt_s,
                                              int ne, int nb) {
    __shared__ int cnt[2][NB_MAX];
    int tid = threadIdx.x;
    for (int i = tid; i < 2 * NB_MAX; i += 256) ((int*)cnt)[i] = 0;
    __syncthreads();
    for (int i = blockIdx.x * 256 + tid; i < ne; i += gridDim.x * 256) {
        atomicAdd(&cnt[0][dst[i] >> 7], 1);
        atomicAdd(&cnt[1][src[i] >> 7], 1);
    }
    __syncthreads();
    for (int i = tid; i < nb; i += 256) {
        if (cnt[0][i]) atomicAdd(&bcnt_d[i], cnt[0][i]);
        if (cnt[1][i]) atomicAdd(&bcnt_s[i], cnt[1][i]);
    }
}

// ---------------- CSR build: bucket exclusive scan (1 block) ----------------
__global__ __launch_bounds__(256) void bscan_k(const int* __restrict__ bcnt_d,
                                               const int* __restrict__ bcnt_s,
                                               int* bbase_d, int* bbase_s,
                                               int* bcur_d, int* bcur_s,
                                               int* rp_d, int* rp_s,
                                               int nb, int n, int ne) {
    __shared__ int buf[256];
    int tid = threadIdx.x;
#pragma unroll
    for (int a = 0; a < 2; ++a) {
        const int* c = a ? bcnt_s : bcnt_d;
        int* bb = a ? bbase_s : bbase_d;
        int* bc = a ? bcur_s : bcur_d;
        int v = (tid < nb) ? c[tid] : 0;
        buf[tid] = v;
        __syncthreads();
        for (int off = 1; off < 256; off <<= 1) {
            int t = (tid >= off) ? buf[tid - off] : 0;
            __syncthreads();
            buf[tid] += t;
            __syncthreads();
        }
        int excl = buf[tid] - v;
        if (tid < nb) { bb[tid] = excl; bc[tid] = excl; }
        if (tid == nb - 1) bb[nb] = buf[tid];
        __syncthreads();
    }
    if (tid == 0) { rp_d[n] = ne; rp_s[n] = ne; }
}

// ---------------- CSR build: LDS-aggregated partition into bucket regions ----------------
#define EPT 8
__global__ __launch_bounds__(256) void part_k(const int* __restrict__ src,
                                              const int* __restrict__ dst,
                                              int* __restrict__ bcur_d, int* __restrict__ bcur_s,
                                              uint32_t* __restrict__ rec_d, uint32_t* __restrict__ rec_s,
                                              int ne) {
    __shared__ int cnt[2][NB_MAX];
    __shared__ int base[2][NB_MAX];
    int tid = threadIdx.x;
    int blockStart = blockIdx.x * 256 * EPT;
    for (int i = tid; i < 2 * NB_MAX; i += 256) ((int*)cnt)[i] = 0;
    __syncthreads();
    int s[EPT], d[EPT], sl_d[EPT], sl_s[EPT];
#pragma unroll
    for (int e = 0; e < EPT; ++e) {
        int i = blockStart + e * 256 + tid;
        s[e] = -1;
        if (i < ne) {
            s[e] = src[i]; d[e] = dst[i];
            sl_d[e] = atomicAdd(&cnt[0][d[e] >> 7], 1);
            sl_s[e] = atomicAdd(&cnt[1][s[e] >> 7], 1);
        }
    }
    __syncthreads();
    for (int i = tid; i < NB_MAX; i += 256) {
        if (cnt[0][i]) base[0][i] = atomicAdd(&bcur_d[i], cnt[0][i]);
        if (cnt[1][i]) base[1][i] = atomicAdd(&bcur_s[i], cnt[1][i]);
    }
    __syncthreads();
#pragma unroll
    for (int e = 0; e < EPT; ++e) {
        if (s[e] >= 0) {
            rec_d[base[0][d[e] >> 7] + sl_d[e]] = (uint32_t)s[e] | ((uint32_t)(d[e] & 127) << 17);
            rec_s[base[1][s[e] >> 7] + sl_s[e]] = (uint32_t)d[e] | ((uint32_t)(s[e] & 127) << 17);
        }
    }
}

// ---------------- CSR build: per-bucket local fill (grid = (nb, 2)) ----------------
__global__ __launch_bounds__(256) void csrfill_k(const uint32_t* __restrict__ rec_d,
                                                 const uint32_t* __restrict__ rec_s,
                                                 const int* __restrict__ bbase_d,
                                                 const int* __restrict__ bbase_s,
                                                 int* __restrict__ rp_d, int* __restrict__ rp_s,
                                                 int* __restrict__ nbr_d, int* __restrict__ nbr_s,
                                                 int n) {
    const uint32_t* rec = blockIdx.y ? rec_s : rec_d;
    const int* bbase    = blockIdx.y ? bbase_s : bbase_d;
    int* rp             = blockIdx.y ? rp_s : rp_d;
    int* nbr            = blockIdx.y ? nbr_s : nbr_d;
    int b = blockIdx.x;
    int tid = threadIdx.x;
    int beg = bbase[b], end = bbase[b + 1];
    __shared__ int deg[BKT_W];
    __shared__ int sbuf[BKT_W];
    __shared__ int cur[BKT_W];
    if (tid < BKT_W) deg[tid] = 0;
    __syncthreads();
    for (int j = beg + tid; j < end; j += 256) atomicAdd(&deg[rec[j] >> 17], 1);
    __syncthreads();
    if (tid < BKT_W) sbuf[tid] = deg[tid];
    __syncthreads();
    for (int off = 1; off < BKT_W; off <<= 1) {
        int t = (tid < BKT_W && tid >= off) ? sbuf[tid - off] : 0;
        __syncthreads();
        if (tid < BKT_W) sbuf[tid] += t;
        __syncthreads();
    }
    if (tid < BKT_W) {
        int abs0 = beg + sbuf[tid] - deg[tid];
        cur[tid] = abs0;
        int node = b * BKT_W + tid;
        if (node < n) rp[node] = abs0;
    }
    __syncthreads();
    for (int j = beg + tid; j < end; j += 256) {
        uint32_t r = rec[j];
        nbr[atomicAdd(&cur[r >> 17], 1)] = (int)(r & 0x1FFFFu);
    }
}

// ---------------- GAT gather: wave/node; 4 edges x 16-lane groups, uint4 row loads ----------------
__global__ __launch_bounds__(256) void gat_gather_k(const int* __restrict__ rowptr,
                                                    const int* __restrict__ nbrs,
                                                    const float* __restrict__ score_nb,
                                                    const float* __restrict__ score_self,
                                                    const short* __restrict__ hb,
                                                    const float* __restrict__ bias,
                                                    const float* __restrict__ resid,
                                                    float* __restrict__ out, int n) {
    int wave = (int)((blockIdx.x * 256 + threadIdx.x) >> 6);
    int lane = threadIdx.x & 63;
    if (wave >= n) return;
    int beg = rowptr[wave], end = rowptr[wave + 1];
    float sself = score_self[wave];
    int slot = lane >> 4;        // which edge of the group of 4
    int c    = lane & 15;        // col chunk: cols 8c..8c+7
    float acc[8] = {0, 0, 0, 0, 0, 0, 0, 0};
    float wsum = 0.f;
    for (int j = beg; j < end; j += 8) {
        int i0 = j + slot;
        int i1 = j + 4 + slot;
        bool v0 = i0 < end, v1 = i1 < end;
        int nb0 = v0 ? nbrs[i0] : 0;
        int nb1 = v1 ? nbrs[i1] : 0;
        uint4 h0 = *(const uint4*)(hb + (size_t)nb0 * D + c * 8);
        uint4 h1 = *(const uint4*)(hb + (size_t)nb1 * D + c * 8);
        float s0 = v0 ? score_nb[nb0] : 0.f;
        float s1 = v1 ? score_nb[nb1] : 0.f;
        float e0 = s0 + sself; e0 = (e0 > 0.f) ? e0 : 0.2f * e0;
        float e1 = s1 + sself; e1 = (e1 > 0.f) ? e1 : 0.2f * e1;
        float w0 = v0 ? __expf(e0) : 0.f;
        float w1 = v1 ? __expf(e1) : 0.f;
        wsum += w0 + w1;
        const uint32_t* p0 = (const uint32_t*)&h0;
        const uint32_t* p1 = (const uint32_t*)&h1;
#pragma unroll
        for (int q = 0; q < 4; ++q) {
            uint32_t a = p0[q];
            acc[2 * q]     += w0 * __uint_as_float(a << 16);
            acc[2 * q + 1] += w0 * __uint_as_float(a & 0xFFFF0000u);
            uint32_t b = p1[q];
            acc[2 * q]     += w1 * __uint_as_float(b << 16);
            acc[2 * q + 1] += w1 * __uint_as_float(b & 0xFFFF0000u);
        }
    }
#pragma unroll
    for (int off = 16; off <= 32; off <<= 1) {
        wsum += __shfl_xor(wsum, off);
#pragma unroll
        for (int r = 0; r < 8; ++r) acc[r] += __shfl_xor(acc[r], off);
    }
    if (lane < 16) {
        float inv = 1.0f / (wsum + 1e-16f);
        size_t o = (size_t)wave * D + c * 8;
        float4 r0 = *(const float4*)(resid + o);
        float4 r1 = *(const float4*)(resid + o + 4);
        float4 o0, o1;
        o0.x = acc[0] * inv + bias[c * 8 + 0] + r0.x;
        o0.y = acc[1] * inv + bias[c * 8 + 1] + r0.y;
        o0.z = acc[2] * inv + bias[c * 8 + 2] + r0.z;
        o0.w = acc[3] * inv + bias[c * 8 + 3] + r0.w;
        o1.x = acc[4] * inv + bias[c * 8 + 4] + r1.x;
        o1.y = acc[5] * inv + bias[c * 8 + 5] + r1.y;
        o1.z = acc[6] * inv + bias[c * 8 + 6] + r1.z;
        o1.w = acc[7] * inv + bias[c * 8 + 7] + r1.w;
        *(float4*)(out + o)     = o0;
        *(float4*)(out + o + 4) = o1;
    }
}

// ---------------- host ----------------
extern "C" void kernel_launch(void* const* d_in, const int* in_sizes, int n_in,
                              void* d_out, int out_size, void* d_ws, size_t ws_size,
                              hipStream_t stream) {
    const float* Xw    = (const float*)d_in[0];
    const float* Xs    = (const float*)d_in[1];
    const int*   edge  = (const int*)d_in[2];
    const float* W_s2w = (const float*)d_in[3];
    const float* as1   = (const float*)d_in[4];
    const float* ad1   = (const float*)d_in[5];
    const float* b1    = (const float*)d_in[6];
    const float* W_w2s = (const float*)d_in[7];
    const float* as2   = (const float*)d_in[8];
    const float* ad2   = (const float*)d_in[9];
    const float* b2    = (const float*)d_in[10];
    const float* W_lin = (const float*)d_in[11];
    const float* b_lin = (const float*)d_in[12];
    float* out = (float*)d_out;

    const int N  = in_sizes[0] / D;       // 20000
    const int NE = in_sizes[2] / 2;       // 640000
    const int NB = (N + BKT_W - 1) / BKT_W;
    const int* e_src = edge;
    const int* e_dst = edge + NE;

    char* p = (char*)d_ws;
    auto take = [&](size_t bytes) -> void* {
        p = (char*)(((uintptr_t)p + 255) & ~(uintptr_t)255);
        void* r = (void*)p;
        p += bytes;
        return r;
    };
    short* hb1  = (short*)take((size_t)N * D * 2);
    short* hb2  = (short*)take((size_t)N * D * 2);
    short* wpk1 = (short*)take((size_t)D * D * 2);
    short* wpk2 = (short*)take((size_t)D * D * 2);
    short* wpkL = (short*)take((size_t)D * D * 2);
    float* ss1  = (float*)take((size_t)N * 4);
    float* sd1  = (float*)take((size_t)N * 4);
    float* ss2  = (float*)take((size_t)N * 4);
    float* sd2  = (float*)take((size_t)N * 4);
    int*   bcnt = (int*)take((size_t)2 * NB * 4);
    int*   bcnt_d = bcnt;
    int*   bcnt_s = bcnt + NB;
    int*   bbase_d = (int*)take((size_t)(NB + 1) * 4);
    int*   bbase_s = (int*)take((size_t)(NB + 1) * 4);
    int*   bcur_d  = (int*)take((size_t)NB * 4);
    int*   bcur_s  = (int*)take((size_t)NB * 4);
    int*   rp_d = (int*)take((size_t)(N + 1) * 4);
    int*   rp_s = (int*)take((size_t)(N + 1) * 4);
    uint32_t* rec_d = (uint32_t*)take((size_t)NE * 4);
    uint32_t* rec_s = (uint32_t*)take((size_t)NE * 4);
    int*   nbr_d = (int*)take((size_t)NE * 4);
    int*   nbr_s = (int*)take((size_t)NE * 4);

    float* t1 = out;
    float* t2 = out + (size_t)N * D;

    hipMemsetAsync(bcnt, 0, (size_t)2 * NB * 4, stream);

    // W pre-pack (fragment order, bf16)
    pack_w_k<<<24, 256, 0, stream>>>(W_s2w, W_w2s, W_lin, wpk1, wpk2, wpkL);

    // h (bf16 rows) + fused scores, both directions in one MFMA launch
    int mg = (N + RPB - 1) / RPB;
    dim3 hGrid(mg, 2);
    mfma_h_k<<<hGrid, 256, 0, stream>>>(Xs, Xw, wpk1, wpk2, hb1, hb2,
                                        as1, as2, ad1, ad2, ss1, ss2, sd1, sd2, N);

    // CSR build
    hist_k<<<512, 256, 0, stream>>>(e_src, e_dst, bcnt_d, bcnt_s, NE, NB);
    bscan_k<<<1, 256, 0, stream>>>(bcnt_d, bcnt_s, bbase_d, bbase_s, bcur_d, bcur_s,
                                   rp_d, rp_s, NB, N, NE);
    int partGrid = (NE + 256 * EPT - 1) / (256 * EPT);
    part_k<<<partGrid, 256, 0, stream>>>(e_src, e_dst, bcur_d, bcur_s, rec_d, rec_s, NE);
    dim3 fillGrid(NB, 2);
    csrfill_k<<<fillGrid, 256, 0, stream>>>(rec_d, rec_s, bbase_d, bbase_s,
                                            rp_d, rp_s, nbr_d, nbr_s, N);

    // gathers: fused alpha (exp per edge) + normalize + bias + residual
    int nodeWaveGrid = (N + 3) / 4;
    gat_gather_k<<<nodeWaveGrid, 256, 0, stream>>>(rp_d, nbr_d, ss1, sd1, hb1, b1, Xw, t1, N);
    gat_gather_k<<<nodeWaveGrid, 256, 0, stream>>>(rp_s, nbr_s, ss2, sd2, hb2, b2, Xs, t2, N);

    // epilogue (both directions in one MFMA launch, in-place): t = t @ W_lin + b_lin
    dim3 epGrid(mg, 2);
    mfma_ep_k<<<epGrid, 256, 0, stream>>>(out, wpkL, b_lin, N);
}

// Round 7
// 130.592 us; speedup vs baseline: 3.1660x; 1.1402x over previous
//
#include <hip/hip_runtime.h>
#include <hip/hip_bf16.h>
#include <stdint.h>

#define D 128
#define BKT_W 128            // nodes per bucket
#define NB_MAX 256           // supports N <= 32768
#define RPB 128              // rows per block in MFMA GEMMs

typedef __attribute__((ext_vector_type(8))) short bf16x8;
typedef __attribute__((ext_vector_type(4))) float f32x4;

static __device__ __forceinline__ short f2bf(float x) {
    __hip_bfloat16 h = __float2bfloat16(x);
    return *reinterpret_cast<short*>(&h);
}

// ---------------- W pre-pack into MFMA B-fragment order (3 matrices) ----------------
__global__ __launch_bounds__(256) void pack_w_k(const float* __restrict__ W0,
                                                const float* __restrict__ W1,
                                                const float* __restrict__ W2,
                                                short* __restrict__ P0,
                                                short* __restrict__ P1,
                                                short* __restrict__ P2) {
    int t = blockIdx.x * 256 + threadIdx.x;      // 3 * 2048 threads
    int m = t >> 11;
    int r = t & 2047;                            // (kc*8+ct)*64 + lane
    const float* W = (m == 0) ? W0 : (m == 1) ? W1 : W2;
    short*       P = (m == 0) ? P0 : (m == 1) ? P1 : P2;
    int lane = r & 63;
    int fr   = r >> 6;                           // kc*8 + ct
    int kc = fr >> 3, ct = fr & 7;
    int col = ct * 16 + (lane & 15);
    int kb  = kc * 32 + 4 * (lane >> 4);
    short v[8];
#pragma unroll
    for (int e = 0; e < 8; ++e) {
        int k = kb + (e & 3) + 16 * (e >> 2);
        v[e] = f2bf(W[k * D + col]);
    }
    short* dst = P + (size_t)r * 8;
#pragma unroll
    for (int e = 0; e < 8; ++e) dst[e] = v[e];
}

// ---------------- MFMA h-GEMM (both dirs): HB = bf16(IN @ W), fused scores ----------------
__global__ __launch_bounds__(256) void mfma_h_k(const float* __restrict__ IN0,
                                                const float* __restrict__ IN1,
                                                const short* __restrict__ P0,
                                                const short* __restrict__ P1,
                                                short* __restrict__ HB0,
                                                short* __restrict__ HB1,
                                                const float* __restrict__ as0,
                                                const float* __restrict__ as1,
                                                const float* __restrict__ ad0,
                                                const float* __restrict__ ad1,
                                                float* __restrict__ ss0,
                                                float* __restrict__ ss1,
                                                float* __restrict__ sd0,
                                                float* __restrict__ sd1,
                                                int nrows) {
    const float* IN = blockIdx.y ? IN1 : IN0;
    const short* PK = blockIdx.y ? P1  : P0;
    short*       HB = blockIdx.y ? HB1 : HB0;
    const float* a_src = blockIdx.y ? as1 : as0;
    const float* a_dst = blockIdx.y ? ad1 : ad0;
    float* ss = blockIdx.y ? ss1 : ss0;
    float* sd = blockIdx.y ? sd1 : sd0;

    __shared__ short As[RPB * 136];
    int row0 = blockIdx.x * RPB;
    int tid  = threadIdx.x;
    const float4* in4 = (const float4*)IN;
#pragma unroll
    for (int i = 0; i < 16; ++i) {
        int idx = tid + i * 256;
        int row = idx >> 5;               // 32 float4 per row
        int q   = idx & 31;
        float4 v = make_float4(0.f, 0.f, 0.f, 0.f);
        int grow = row0 + row;
        if (grow < nrows) v = in4[(size_t)grow * 32 + q];
        int kc = q >> 3, hi = (q >> 2) & 1, g2 = q & 3;
        short4 s4;
        s4.x = f2bf(v.x); s4.y = f2bf(v.y); s4.z = f2bf(v.z); s4.w = f2bf(v.w);
        *(short4*)&As[row * 136 + kc * 32 + g2 * 8 + hi * 4] = s4;
    }
    __syncthreads();

    int lane = tid & 63;
    int wv   = tid >> 6;
    const bf16x8* Wf = (const bf16x8*)PK;
    f32x4 acc[2][8] = {};
#pragma unroll
    for (int kc = 0; kc < 4; ++kc) {
        bf16x8 a0 = *(const bf16x8*)&As[(wv * 32 +      (lane & 15)) * 136 + kc * 32 + (lane >> 4) * 8];
        bf16x8 a1 = *(const bf16x8*)&As[(wv * 32 + 16 + (lane & 15)) * 136 + kc * 32 + (lane >> 4) * 8];
#pragma unroll
        for (int ct = 0; ct < 8; ++ct) {
            bf16x8 b = Wf[(kc * 8 + ct) * 64 + lane];
            acc[0][ct] = __builtin_amdgcn_mfma_f32_16x16x32_bf16(a0, b, acc[0][ct], 0, 0, 0);
            acc[1][ct] = __builtin_amdgcn_mfma_f32_16x16x32_bf16(a1, b, acc[1][ct], 0, 0, 0);
        }
    }

    // epilogue: D layout col = lane&15, row = (lane>>4)*4 + reg
    int cb = lane & 15, rg = lane >> 4;
    float asv[8], adv[8];
#pragma unroll
    for (int ct = 0; ct < 8; ++ct) { asv[ct] = a_src[ct * 16 + cb]; adv[ct] = a_dst[ct * 16 + cb]; }
#pragma unroll
    for (int rt = 0; rt < 2; ++rt) {
        float ssum[4] = {0, 0, 0, 0}, dsum[4] = {0, 0, 0, 0};
#pragma unroll
        for (int ct = 0; ct < 8; ++ct) {
#pragma unroll
            for (int r = 0; r < 4; ++r) {
                float x = acc[rt][ct][r];
                int grow = row0 + wv * 32 + rt * 16 + rg * 4 + r;
                if (grow < nrows) HB[(size_t)grow * D + ct * 16 + cb] = f2bf(x);
                ssum[r] += x * asv[ct];
                dsum[r] += x * adv[ct];
            }
        }
#pragma unroll
        for (int off = 1; off < 16; off <<= 1) {
#pragma unroll
            for (int r = 0; r < 4; ++r) {
                ssum[r] += __shfl_xor(ssum[r], off);
                dsum[r] += __shfl_xor(dsum[r], off);
            }
        }
        if (cb == 0) {
#pragma unroll
            for (int r = 0; r < 4; ++r) {
                int grow = row0 + wv * 32 + rt * 16 + rg * 4 + r;
                if (grow < nrows) { ss[grow] = ssum[r]; sd[grow] = dsum[r]; }
            }
        }
    }
}

// ---------------- MFMA epilogue GEMM, in-place, both dirs: t = t @ W_lin + b ----------------
__global__ __launch_bounds__(256) void mfma_ep_k(float* __restrict__ buf,
                                                 const short* __restrict__ PK,
                                                 const float* __restrict__ bias,
                                                 int nrows) {
    float* T = buf + (size_t)blockIdx.y * nrows * D;
    __shared__ short As[RPB * 136];
    int row0 = blockIdx.x * RPB;
    int tid  = threadIdx.x;
    const float4* in4 = (const float4*)T;
#pragma unroll
    for (int i = 0; i < 16; ++i) {
        int idx = tid + i * 256;
        int row = idx >> 5;
        int q   = idx & 31;
        float4 v = make_float4(0.f, 0.f, 0.f, 0.f);
        int grow = row0 + row;
        if (grow < nrows) v = in4[(size_t)grow * 32 + q];
        int kc = q >> 3, hi = (q >> 2) & 1, g2 = q & 3;
        short4 s4;
        s4.x = f2bf(v.x); s4.y = f2bf(v.y); s4.z = f2bf(v.z); s4.w = f2bf(v.w);
        *(short4*)&As[row * 136 + kc * 32 + g2 * 8 + hi * 4] = s4;
    }
    __syncthreads();

    int lane = tid & 63;
    int wv   = tid >> 6;
    const bf16x8* Wf = (const bf16x8*)PK;
    f32x4 acc[2][8] = {};
#pragma unroll
    for (int kc = 0; kc < 4; ++kc) {
        bf16x8 a0 = *(const bf16x8*)&As[(wv * 32 +      (lane & 15)) * 136 + kc * 32 + (lane >> 4) * 8];
        bf16x8 a1 = *(const bf16x8*)&As[(wv * 32 + 16 + (lane & 15)) * 136 + kc * 32 + (lane >> 4) * 8];
#pragma unroll
        for (int ct = 0; ct < 8; ++ct) {
            bf16x8 b = Wf[(kc * 8 + ct) * 64 + lane];
            acc[0][ct] = __builtin_amdgcn_mfma_f32_16x16x32_bf16(a0, b, acc[0][ct], 0, 0, 0);
            acc[1][ct] = __builtin_amdgcn_mfma_f32_16x16x32_bf16(a1, b, acc[1][ct], 0, 0, 0);
        }
    }

    int cb = lane & 15, rg = lane >> 4;
    float bv[8];
#pragma unroll
    for (int ct = 0; ct < 8; ++ct) bv[ct] = bias[ct * 16 + cb];
#pragma unroll
    for (int rt = 0; rt < 2; ++rt) {
#pragma unroll
        for (int ct = 0; ct < 8; ++ct) {
#pragma unroll
            for (int r = 0; r < 4; ++r) {
                int grow = row0 + wv * 32 + rt * 16 + rg * 4 + r;
                if (grow < nrows) T[(size_t)grow * D + ct * 16 + cb] = acc[rt][ct][r] + bv[ct];
            }
        }
    }
}

// ---------------- CSR build: bucket histogram ----------------
__global__ __launch_bounds__(256) void hist_k(const int* __restrict__ src,
                                              const int* __restrict__ dst,
                                              int* __restrict__ bcnt_d, int* __restrict__ bcnt_s,
                                              int ne, int nb) {
    __shared__ int cnt[2][NB_MAX];
    int tid = threadIdx.x;
    for (int i = tid; i < 2 * NB_MAX; i += 256) ((int*)cnt)[i] = 0;
    __syncthreads();
    for (int i = blockIdx.x * 256 + tid; i < ne; i += gridDim.x * 256) {
        atomicAdd(&cnt[0][dst[i] >> 7], 1);
        atomicAdd(&cnt[1][src[i] >> 7], 1);
    }
    __syncthreads();
    for (int i = tid; i < nb; i += 256) {
        if (cnt[0][i]) atomicAdd(&bcnt_d[i], cnt[0][i]);
        if (cnt[1][i]) atomicAdd(&bcnt_s[i], cnt[1][i]);
    }
}

// ---------------- CSR build: bucket exclusive scan (1 block) ----------------
__global__ __launch_bounds__(256) void bscan_k(const int* __restrict__ bcnt_d,
                                               const int* __restrict__ bcnt_s,
                                               int* bbase_d, int* bbase_s,
                                               int* bcur_d, int* bcur_s,
                                               int* rp_d, int* rp_s,
                                               int nb, int n, int ne) {
    __shared__ int buf[256];
    int tid = threadIdx.x;
#pragma unroll
    for (int a = 0; a < 2; ++a) {
        const int* c = a ? bcnt_s : bcnt_d;
        int* bb = a ? bbase_s : bbase_d;
        int* bc = a ? bcur_s : bcur_d;
        int v = (tid < nb) ? c[tid] : 0;
        buf[tid] = v;
        __syncthreads();
        for (int off = 1; off < 256; off <<= 1) {
            int t = (tid >= off) ? buf[tid - off] : 0;
            __syncthreads();
            buf[tid] += t;
            __syncthreads();
        }
        int excl = buf[tid] - v;
        if (tid < nb) { bb[tid] = excl; bc[tid] = excl; }
        if (tid == nb - 1) bb[nb] = buf[tid];
        __syncthreads();
    }
    if (tid == 0) { rp_d[n] = ne; rp_s[n] = ne; }
}

// ---------------- CSR build: LDS-aggregated partition into bucket regions ----------------
#define EPT 8
__global__ __launch_bounds__(256) void part_k(const int* __restrict__ src,
                                              const int* __restrict__ dst,
                                              int* __restrict__ bcur_d, int* __restrict__ bcur_s,
                                              uint32_t* __restrict__ rec_d, uint32_t* __restrict__ rec_s,
                                              int ne) {
    __shared__ int cnt[2][NB_MAX];
    __shared__ int base[2][NB_MAX];
    int tid = threadIdx.x;
    int blockStart = blockIdx.x * 256 * EPT;
    for (int i = tid; i < 2 * NB_MAX; i += 256) ((int*)cnt)[i] = 0;
    __syncthreads();
    int s[EPT], d[EPT], sl_d[EPT], sl_s[EPT];
#pragma unroll
    for (int e = 0; e < EPT; ++e) {
        int i = blockStart + e * 256 + tid;
        s[e] = -1;
        if (i < ne) {
            s[e] = src[i]; d[e] = dst[i];
            sl_d[e] = atomicAdd(&cnt[0][d[e] >> 7], 1);
            sl_s[e] = atomicAdd(&cnt[1][s[e] >> 7], 1);
        }
    }
    __syncthreads();
    for (int i = tid; i < NB_MAX; i += 256) {
        if (cnt[0][i]) base[0][i] = atomicAdd(&bcur_d[i], cnt[0][i]);
        if (cnt[1][i]) base[1][i] = atomicAdd(&bcur_s[i], cnt[1][i]);
    }
    __syncthreads();
#pragma unroll
    for (int e = 0; e < EPT; ++e) {
        if (s[e] >= 0) {
            rec_d[base[0][d[e] >> 7] + sl_d[e]] = (uint32_t)s[e] | ((uint32_t)(d[e] & 127) << 17);
            rec_s[base[1][s[e] >> 7] + sl_s[e]] = (uint32_t)d[e] | ((uint32_t)(s[e] & 127) << 17);
        }
    }
}

// ---------------- CSR build + edge weights: per-bucket fill (grid = (nb, 2)) ----------------
// Writes erec[pos] = (bf16(w) << 16) | nbr, where w = exp(leakyrelu(ss[nbr] + sd[self]))
__global__ __launch_bounds__(256) void csrfill_k(const uint32_t* __restrict__ rec_d,
                                                 const uint32_t* __restrict__ rec_s,
                                                 const int* __restrict__ bbase_d,
                                                 const int* __restrict__ bbase_s,
                                                 const float* __restrict__ ss1,
                                                 const float* __restrict__ sd1,
                                                 const float* __restrict__ ss2,
                                                 const float* __restrict__ sd2,
                                                 int* __restrict__ rp_d, int* __restrict__ rp_s,
                                                 uint32_t* __restrict__ erec_d,
                                                 uint32_t* __restrict__ erec_s,
                                                 int n) {
    const uint32_t* rec = blockIdx.y ? rec_s : rec_d;
    const int* bbase    = blockIdx.y ? bbase_s : bbase_d;
    const float* ss     = blockIdx.y ? ss2 : ss1;     // neighbor-side score
    const float* sdv    = blockIdx.y ? sd2 : sd1;     // self-side score
    int* rp             = blockIdx.y ? rp_s : rp_d;
    uint32_t* erec      = blockIdx.y ? erec_s : erec_d;
    int b = blockIdx.x;
    int tid = threadIdx.x;
    int beg = bbase[b], end = bbase[b + 1];
    __shared__ int deg[BKT_W];
    __shared__ int sbuf[BKT_W];
    __shared__ int cur[BKT_W];
    __shared__ float sdl[BKT_W];
    if (tid < BKT_W) {
        deg[tid] = 0;
        int node = b * BKT_W + tid;
        sdl[tid] = (node < n) ? sdv[node] : 0.f;
    }
    __syncthreads();
    for (int j = beg + tid; j < end; j += 256) atomicAdd(&deg[rec[j] >> 17], 1);
    __syncthreads();
    if (tid < BKT_W) sbuf[tid] = deg[tid];
    __syncthreads();
    for (int off = 1; off < BKT_W; off <<= 1) {
        int t = (tid < BKT_W && tid >= off) ? sbuf[tid - off] : 0;
        __syncthreads();
        if (tid < BKT_W) sbuf[tid] += t;
        __syncthreads();
    }
    if (tid < BKT_W) {
        int abs0 = beg + sbuf[tid] - deg[tid];
        cur[tid] = abs0;
        int node = b * BKT_W + tid;
        if (node < n) rp[node] = abs0;
    }
    __syncthreads();
    for (int j = beg + tid; j < end; j += 256) {
        uint32_t r = rec[j];
        int g  = r >> 17;
        int nb = (int)(r & 0x1FFFFu);
        float e = ss[nb] + sdl[g];
        e = (e > 0.f) ? e : 0.2f * e;
        float w = __expf(e);
        uint32_t wb = ((uint32_t)(unsigned short)f2bf(w)) << 16;
        erec[atomicAdd(&cur[g], 1)] = wb | (uint32_t)nb;
    }
}

// ---------------- GAT gather (both dirs): 4 edges x 16-lane groups, 16-deep unroll ----------------
__global__ __launch_bounds__(256) void gat_gather_k(const int* __restrict__ rp_d,
                                                    const int* __restrict__ rp_s,
                                                    const uint32_t* __restrict__ erec_d,
                                                    const uint32_t* __restrict__ erec_s,
                                                    const short* __restrict__ hb1,
                                                    const short* __restrict__ hb2,
                                                    const float* __restrict__ b1,
                                                    const float* __restrict__ b2,
                                                    const float* __restrict__ Xw,
                                                    const float* __restrict__ Xs,
                                                    float* __restrict__ out, int n) {
    int dir = blockIdx.y;
    const int*      rowptr = dir ? rp_s   : rp_d;
    const uint32_t* erec   = dir ? erec_s : erec_d;
    const short*    hb     = dir ? hb2    : hb1;
    const float*    bias   = dir ? b2     : b1;
    const float*    resid  = dir ? Xs     : Xw;
    float*          outp   = out + (size_t)dir * n * D;

    int wave = (int)((blockIdx.x * 256 + threadIdx.x) >> 6);
    int lane = threadIdx.x & 63;
    if (wave >= n) return;
    int beg = rowptr[wave], end = rowptr[wave + 1];
    int slot = lane >> 4;        // which edge of the group of 4
    int c    = lane & 15;        // col chunk: cols 8c..8c+7
    float acc[8] = {0, 0, 0, 0, 0, 0, 0, 0};
    float wsum = 0.f;
    for (int j = beg; j < end; j += 16) {
        uint32_t r[4];
#pragma unroll
        for (int u = 0; u < 4; ++u) {
            int i = j + 4 * u + slot;
            r[u] = (i < end) ? erec[i] : 0u;
        }
        uint4 h[4];
#pragma unroll
        for (int u = 0; u < 4; ++u)
            h[u] = *(const uint4*)(hb + (size_t)(r[u] & 0xFFFFu) * D + c * 8);
#pragma unroll
        for (int u = 0; u < 4; ++u) {
            float w = __uint_as_float(r[u] & 0xFFFF0000u);
            wsum += w;
            const uint32_t* pq = (const uint32_t*)&h[u];
#pragma unroll
            for (int q = 0; q < 4; ++q) {
                uint32_t a = pq[q];
                acc[2 * q]     += w * __uint_as_float(a << 16);
                acc[2 * q + 1] += w * __uint_as_float(a & 0xFFFF0000u);
            }
        }
    }
#pragma unroll
    for (int off = 16; off <= 32; off <<= 1) {
        wsum += __shfl_xor(wsum, off);
#pragma unroll
        for (int q = 0; q < 8; ++q) acc[q] += __shfl_xor(acc[q], off);
    }
    if (lane < 16) {
        float inv = 1.0f / (wsum + 1e-16f);
        size_t o = (size_t)wave * D + c * 8;
        float4 r0 = *(const float4*)(resid + o);
        float4 r1 = *(const float4*)(resid + o + 4);
        float4 o0, o1;
        o0.x = acc[0] * inv + bias[c * 8 + 0] + r0.x;
        o0.y = acc[1] * inv + bias[c * 8 + 1] + r0.y;
        o0.z = acc[2] * inv + bias[c * 8 + 2] + r0.z;
        o0.w = acc[3] * inv + bias[c * 8 + 3] + r0.w;
        o1.x = acc[4] * inv + bias[c * 8 + 4] + r1.x;
        o1.y = acc[5] * inv + bias[c * 8 + 5] + r1.y;
        o1.z = acc[6] * inv + bias[c * 8 + 6] + r1.z;
        o1.w = acc[7] * inv + bias[c * 8 + 7] + r1.w;
        *(float4*)(outp + o)     = o0;
        *(float4*)(outp + o + 4) = o1;
    }
}

// ---------------- host ----------------
extern "C" void kernel_launch(void* const* d_in, const int* in_sizes, int n_in,
                              void* d_out, int out_size, void* d_ws, size_t ws_size,
                              hipStream_t stream) {
    const float* Xw    = (const float*)d_in[0];
    const float* Xs    = (const float*)d_in[1];
    const int*   edge  = (const int*)d_in[2];
    const float* W_s2w = (const float*)d_in[3];
    const float* as1   = (const float*)d_in[4];
    const float* ad1   = (const float*)d_in[5];
    const float* b1    = (const float*)d_in[6];
    const float* W_w2s = (const float*)d_in[7];
    const float* as2   = (const float*)d_in[8];
    const float* ad2   = (const float*)d_in[9];
    const float* b2    = (const float*)d_in[10];
    const float* W_lin = (const float*)d_in[11];
    const float* b_lin = (const float*)d_in[12];
    float* out = (float*)d_out;

    const int N  = in_sizes[0] / D;       // 20000
    const int NE = in_sizes[2] / 2;       // 640000
    const int NB = (N + BKT_W - 1) / BKT_W;
    const int* e_src = edge;
    const int* e_dst = edge + NE;

    char* p = (char*)d_ws;
    auto take = [&](size_t bytes) -> void* {
        p = (char*)(((uintptr_t)p + 255) & ~(uintptr_t)255);
        void* r = (void*)p;
        p += bytes;
        return r;
    };
    short* hb1  = (short*)take((size_t)N * D * 2);
    short* hb2  = (short*)take((size_t)N * D * 2);
    short* wpk1 = (short*)take((size_t)D * D * 2);
    short* wpk2 = (short*)take((size_t)D * D * 2);
    short* wpkL = (short*)take((size_t)D * D * 2);
    float* ss1  = (float*)take((size_t)N * 4);
    float* sd1  = (float*)take((size_t)N * 4);
    float* ss2  = (float*)take((size_t)N * 4);
    float* sd2  = (float*)take((size_t)N * 4);
    int*   bcnt = (int*)take((size_t)2 * NB * 4);
    int*   bcnt_d = bcnt;
    int*   bcnt_s = bcnt + NB;
    int*   bbase_d = (int*)take((size_t)(NB + 1) * 4);
    int*   bbase_s = (int*)take((size_t)(NB + 1) * 4);
    int*   bcur_d  = (int*)take((size_t)NB * 4);
    int*   bcur_s  = (int*)take((size_t)NB * 4);
    int*   rp_d = (int*)take((size_t)(N + 1) * 4);
    int*   rp_s = (int*)take((size_t)(N + 1) * 4);
    uint32_t* rec_d = (uint32_t*)take((size_t)NE * 4);
    uint32_t* rec_s = (uint32_t*)take((size_t)NE * 4);
    uint32_t* erec_d = (uint32_t*)take((size_t)NE * 4);
    uint32_t* erec_s = (uint32_t*)take((size_t)NE * 4);

    hipMemsetAsync(bcnt, 0, (size_t)2 * NB * 4, stream);

    // W pre-pack (fragment order, bf16)
    pack_w_k<<<24, 256, 0, stream>>>(W_s2w, W_w2s, W_lin, wpk1, wpk2, wpkL);

    // h (bf16 rows) + fused scores, both directions in one MFMA launch
    int mg = (N + RPB - 1) / RPB;
    dim3 hGrid(mg, 2);
    mfma_h_k<<<hGrid, 256, 0, stream>>>(Xs, Xw, wpk1, wpk2, hb1, hb2,
                                        as1, as2, ad1, ad2, ss1, ss2, sd1, sd2, N);

    // CSR build
    hist_k<<<512, 256, 0, stream>>>(e_src, e_dst, bcnt_d, bcnt_s, NE, NB);
    bscan_k<<<1, 256, 0, stream>>>(bcnt_d, bcnt_s, bbase_d, bbase_s, bcur_d, bcur_s,
                                   rp_d, rp_s, NB, N, NE);
    int partGrid = (NE + 256 * EPT - 1) / (256 * EPT);
    part_k<<<partGrid, 256, 0, stream>>>(e_src, e_dst, bcur_d, bcur_s, rec_d, rec_s, NE);
    dim3 fillGrid(NB, 2);
    csrfill_k<<<fillGrid, 256, 0, stream>>>(rec_d, rec_s, bbase_d, bbase_s,
                                            ss1, sd1, ss2, sd2,
                                            rp_d, rp_s, erec_d, erec_s, N);

    // gather, both directions in one launch: alpha from erec, fused norm+bias+resid
    int nodeWaveGrid = (N + 3) / 4;
    dim3 gGrid(nodeWaveGrid, 2);
    gat_gather_k<<<gGrid, 256, 0, stream>>>(rp_d, rp_s, erec_d, erec_s, hb1, hb2,
                                            b1, b2, Xw, Xs, out, N);

    // epilogue (both directions in one MFMA launch, in-place): t = t @ W_lin + b_lin
    dim3 epGrid(mg, 2);
    mfma_ep_k<<<epGrid, 256, 0, stream>>>(out, wpkL, b_lin, N);
}

// Round 8
// 97.516 us; speedup vs baseline: 4.2399x; 1.3392x over previous
//
#include <hip/hip_runtime.h>
#include <hip/hip_bf16.h>
#include <stdint.h>

#define D 128
#define BKT_W 128            // nodes per bucket
#define NB_MAX 256           // supports N <= 32768
#define RPB 128              // rows per block in MFMA GEMMs
#define CAPMAX 8192          // csrfill LDS staging bound
#define EPT 8
#define FILL_T 512

typedef __attribute__((ext_vector_type(8))) short bf16x8;
typedef __attribute__((ext_vector_type(4))) float f32x4;

static __device__ __forceinline__ short f2bf(float x) {
    __hip_bfloat16 h = __float2bfloat16(x);
    return *reinterpret_cast<short*>(&h);
}

// ---------------- W pre-pack into MFMA B-fragment order (+ zero bucket cursors) ----------------
__global__ __launch_bounds__(256) void pack_w_k(const float* __restrict__ W0,
                                                const float* __restrict__ W1,
                                                const float* __restrict__ W2,
                                                short* __restrict__ P0,
                                                short* __restrict__ P1,
                                                short* __restrict__ P2,
                                                int* __restrict__ bcur, int nb2) {
    if (blockIdx.x == 0) {
        for (int i = threadIdx.x; i < nb2; i += 256) bcur[i] = 0;
    }
    int t = blockIdx.x * 256 + threadIdx.x;      // 3 * 2048 threads
    int m = t >> 11;
    int r = t & 2047;                            // (kc*8+ct)*64 + lane
    const float* W = (m == 0) ? W0 : (m == 1) ? W1 : W2;
    short*       P = (m == 0) ? P0 : (m == 1) ? P1 : P2;
    int lane = r & 63;
    int fr   = r >> 6;                           // kc*8 + ct
    int kc = fr >> 3, ct = fr & 7;
    int col = ct * 16 + (lane & 15);
    int kb  = kc * 32 + 4 * (lane >> 4);
    short v[8];
#pragma unroll
    for (int e = 0; e < 8; ++e) {
        int k = kb + (e & 3) + 16 * (e >> 2);
        v[e] = f2bf(W[k * D + col]);
    }
    short* dst = P + (size_t)r * 8;
#pragma unroll
    for (int e = 0; e < 8; ++e) dst[e] = v[e];
}

// ---------------- FAT kernel: MFMA h-GEMM (2*mg blocks) || edge partition (rest) ----------------
__global__ __launch_bounds__(256) void fat_h_part_k(
    const float* __restrict__ IN0, const float* __restrict__ IN1,
    const short* __restrict__ P0,  const short* __restrict__ P1,
    short* __restrict__ HB0, short* __restrict__ HB1,
    const float* __restrict__ as0, const float* __restrict__ as1,
    const float* __restrict__ ad0, const float* __restrict__ ad1,
    float* __restrict__ ss0, float* __restrict__ ss1,
    float* __restrict__ sd0, float* __restrict__ sd1,
    int nrows, int mg,
    const int* __restrict__ esrc, const int* __restrict__ edst,
    int* __restrict__ bcur_d, int* __restrict__ bcur_s,
    uint32_t* __restrict__ rec_d, uint32_t* __restrict__ rec_s,
    int ne, int cap) {
    __shared__ __align__(16) char smem[RPB * 136 * 2 + 256];
    int bid = blockIdx.x;
    int tid = threadIdx.x;

    if (bid < 2 * mg) {
        // ---------- MFMA h-GEMM branch ----------
        int yy = (bid >= mg) ? 1 : 0;
        int xb = bid - yy * mg;
        const float* IN = yy ? IN1 : IN0;
        const short* PK = yy ? P1  : P0;
        short*       HB = yy ? HB1 : HB0;
        const float* a_src = yy ? as1 : as0;
        const float* a_dst = yy ? ad1 : ad0;
        float* ss = yy ? ss1 : ss0;
        float* sd = yy ? sd1 : sd0;
        short* As = (short*)smem;
        float* ps = (float*)(smem + RPB * 136 * 2);   // [2][2][8][2]

        int row0 = xb * RPB;
        const float4* in4 = (const float4*)IN;
#pragma unroll
        for (int i = 0; i < 16; ++i) {
            int idx = tid + i * 256;
            int row = idx >> 5;               // 32 float4 per row
            int q   = idx & 31;
            float4 v = make_float4(0.f, 0.f, 0.f, 0.f);
            int grow = row0 + row;
            if (grow < nrows) v = in4[(size_t)grow * 32 + q];
            int kc = q >> 3, hi = (q >> 2) & 1, g2 = q & 3;
            short4 s4;
            s4.x = f2bf(v.x); s4.y = f2bf(v.y); s4.z = f2bf(v.z); s4.w = f2bf(v.w);
            *(short4*)&As[row * 136 + kc * 32 + g2 * 8 + hi * 4] = s4;
        }
        __syncthreads();

        int lane = tid & 63;
        int wv   = tid >> 6;
        const bf16x8* Wf = (const bf16x8*)PK;
        f32x4 acc[2][8] = {};
#pragma unroll
        for (int kc = 0; kc < 4; ++kc) {
            bf16x8 a0 = *(const bf16x8*)&As[(wv * 32 +      (lane & 15)) * 136 + kc * 32 + (lane >> 4) * 8];
            bf16x8 a1 = *(const bf16x8*)&As[(wv * 32 + 16 + (lane & 15)) * 136 + kc * 32 + (lane >> 4) * 8];
#pragma unroll
            for (int ct = 0; ct < 8; ++ct) {
                bf16x8 b = Wf[(kc * 8 + ct) * 64 + lane];
                acc[0][ct] = __builtin_amdgcn_mfma_f32_16x16x32_bf16(a0, b, acc[0][ct], 0, 0, 0);
                acc[1][ct] = __builtin_amdgcn_mfma_f32_16x16x32_bf16(a1, b, acc[1][ct], 0, 0, 0);
            }
        }

        int cb = lane & 15, rg = lane >> 4;
        float asv[8], adv[8];
#pragma unroll
        for (int ct = 0; ct < 8; ++ct) { asv[ct] = a_src[ct * 16 + cb]; adv[ct] = a_dst[ct * 16 + cb]; }
#pragma unroll
        for (int rt = 0; rt < 2; ++rt) {
            float ssum[4] = {0, 0, 0, 0}, dsum[4] = {0, 0, 0, 0};
#pragma unroll
            for (int ct = 0; ct < 8; ++ct) {
#pragma unroll
                for (int r = 0; r < 4; ++r) {
                    float x = acc[rt][ct][r];
                    int grow = row0 + wv * 32 + rt * 16 + rg * 4 + r;
                    if (grow < nrows) HB[(size_t)grow * D + ct * 16 + cb] = f2bf(x);
                    ssum[r] += x * asv[ct];
                    dsum[r] += x * adv[ct];
                }
            }
#pragma unroll
            for (int off = 1; off < 16; off <<= 1) {
#pragma unroll
                for (int r = 0; r < 4; ++r) {
                    ssum[r] += __shfl_xor(ssum[r], off);
                    dsum[r] += __shfl_xor(dsum[r], off);
                }
            }
            if (cb == 0) {
#pragma unroll
                for (int r = 0; r < 4; ++r) {
                    int grow = row0 + wv * 32 + rt * 16 + rg * 4 + r;
                    if (grow < nrows) {
                        ps[((rg * 2 + 0) * 8 + r) * 2 + 0] = 0.f; // placate compiler aliasing? (no-op)
                        ss[grow] = ssum[r]; sd[grow] = dsum[r];
                    }
                }
            }
        }
    } else {
        // ---------- edge partition branch ----------
        int pid = bid - 2 * mg;
        int* cnt  = (int*)smem;                       // [2][NB_MAX]
        int* base = (int*)(smem + 2 * NB_MAX * 4);    // [2][NB_MAX]
        int blockStart = pid * 256 * EPT;
        for (int i = tid; i < 2 * NB_MAX; i += 256) cnt[i] = 0;
        __syncthreads();
        int s[EPT], d[EPT], sl_d[EPT], sl_s[EPT];
#pragma unroll
        for (int e = 0; e < EPT; ++e) {
            int i = blockStart + e * 256 + tid;
            s[e] = -1;
            if (i < ne) {
                s[e] = esrc[i]; d[e] = edst[i];
                sl_d[e] = atomicAdd(&cnt[0 * NB_MAX + (d[e] >> 7)], 1);
                sl_s[e] = atomicAdd(&cnt[1 * NB_MAX + (s[e] >> 7)], 1);
            }
        }
        __syncthreads();
        for (int i = tid; i < NB_MAX; i += 256) {
            if (cnt[0 * NB_MAX + i]) base[0 * NB_MAX + i] = atomicAdd(&bcur_d[i], cnt[0 * NB_MAX + i]);
            if (cnt[1 * NB_MAX + i]) base[1 * NB_MAX + i] = atomicAdd(&bcur_s[i], cnt[1 * NB_MAX + i]);
        }
        __syncthreads();
#pragma unroll
        for (int e = 0; e < EPT; ++e) {
            if (s[e] >= 0) {
                int bd = d[e] >> 7, bs = s[e] >> 7;
                int od = base[0 * NB_MAX + bd] + sl_d[e];
                int os = base[1 * NB_MAX + bs] + sl_s[e];
                if (od < cap) rec_d[(size_t)bd * cap + od] = (uint32_t)s[e] | ((uint32_t)(d[e] & 127) << 17);
                if (os < cap) rec_s[(size_t)bs * cap + os] = (uint32_t)d[e] | ((uint32_t)(s[e] & 127) << 17);
            }
        }
    }
}

// ---------------- CSR finalize: per-bucket order + weights, in-place; writes node ranges ----------------
__global__ __launch_bounds__(FILL_T) void csrfill_k(uint32_t* __restrict__ rec_d,
                                                    uint32_t* __restrict__ rec_s,
                                                    const int* __restrict__ bcur_d,
                                                    const int* __restrict__ bcur_s,
                                                    const float* __restrict__ ss1,
                                                    const float* __restrict__ sd1,
                                                    const float* __restrict__ ss2,
                                                    const float* __restrict__ sd2,
                                                    int2* __restrict__ nr_d,
                                                    int2* __restrict__ nr_s,
                                                    int n, int cap) {
    __shared__ uint32_t lrec[CAPMAX];
    __shared__ int deg[BKT_W], sbuf[BKT_W], cur[BKT_W];
    __shared__ float sdl[BKT_W];
    int dirv = blockIdx.y;
    uint32_t* rec   = dirv ? rec_s  : rec_d;
    const int* bc   = dirv ? bcur_s : bcur_d;
    const float* ss = dirv ? ss2 : ss1;       // neighbor-side score
    const float* sv = dirv ? sd2 : sd1;       // self-side score
    int2* nr        = dirv ? nr_s : nr_d;
    int b = blockIdx.x, tid = threadIdx.x;
    int base = b * cap;
    int cnt = bc[b]; if (cnt > cap) cnt = cap;
    if (tid < BKT_W) {
        deg[tid] = 0;
        int node = b * BKT_W + tid;
        sdl[tid] = (node < n) ? sv[node] : 0.f;
    }
    for (int j = tid; j < cnt; j += FILL_T) lrec[j] = rec[base + j];
    __syncthreads();
    for (int j = tid; j < cnt; j += FILL_T) atomicAdd(&deg[lrec[j] >> 17], 1);
    __syncthreads();
    if (tid < BKT_W) sbuf[tid] = deg[tid];
    __syncthreads();
    for (int off = 1; off < BKT_W; off <<= 1) {
        int t = (tid < BKT_W && tid >= off) ? sbuf[tid - off] : 0;
        __syncthreads();
        if (tid < BKT_W) sbuf[tid] += t;
        __syncthreads();
    }
    if (tid < BKT_W) {
        int abs0 = base + sbuf[tid] - deg[tid];
        cur[tid] = abs0;
        int node = b * BKT_W + tid;
        if (node < n) nr[node] = make_int2(abs0, abs0 + deg[tid]);
    }
    __syncthreads();
    for (int j = tid; j < cnt; j += FILL_T) {
        uint32_t r = lrec[j];
        int g  = r >> 17;
        int nb = (int)(r & 0x1FFFFu);
        float e = ss[nb] + sdl[g];
        e = (e > 0.f) ? e : 0.2f * e;
        float w = __expf(e);
        rec[atomicAdd(&cur[g], 1)] = (((uint32_t)(unsigned short)f2bf(w)) << 16) | (uint32_t)nb;
    }
}

// ---------------- GAT gather: 1D grid, dir-0 blocks first; 4 edges x 16-lane groups ----------------
__global__ __launch_bounds__(256) void gat_gather_k(const int2* __restrict__ nr_d,
                                                    const int2* __restrict__ nr_s,
                                                    const uint32_t* __restrict__ erec_d,
                                                    const uint32_t* __restrict__ erec_s,
                                                    const short* __restrict__ hb1,
                                                    const short* __restrict__ hb2,
                                                    const float* __restrict__ b1,
                                                    const float* __restrict__ b2,
                                                    const float* __restrict__ Xw,
                                                    const float* __restrict__ Xs,
                                                    float* __restrict__ out, int n, int gB) {
    int bid = blockIdx.x;
    int dirv = (bid >= gB) ? 1 : 0;
    int xb = bid - dirv * gB;
    const int2*     nr   = dirv ? nr_s   : nr_d;
    const uint32_t* erec = dirv ? erec_s : erec_d;
    const short*    hb   = dirv ? hb2    : hb1;
    const float*    bias = dirv ? b2     : b1;
    const float*    resid= dirv ? Xs     : Xw;
    float*          outp = out + (size_t)dirv * n * D;

    int wave = (xb * 256 + (int)threadIdx.x) >> 6;
    int lane = threadIdx.x & 63;
    if (wave >= n) return;
    int2 be = nr[wave];
    int beg = be.x, end = be.y;
    int slot = lane >> 4;        // which edge of the group of 4
    int c    = lane & 15;        // col chunk: cols 8c..8c+7
    float acc[8] = {0, 0, 0, 0, 0, 0, 0, 0};
    float wsum = 0.f;
    for (int j = beg; j < end; j += 16) {
        uint32_t r[4];
#pragma unroll
        for (int u = 0; u < 4; ++u) {
            int i = j + 4 * u + slot;
            r[u] = (i < end) ? erec[i] : 0u;
        }
        uint4 h[4];
#pragma unroll
        for (int u = 0; u < 4; ++u)
            h[u] = *(const uint4*)(hb + (size_t)(r[u] & 0xFFFFu) * D + c * 8);
#pragma unroll
        for (int u = 0; u < 4; ++u) {
            float w = __uint_as_float(r[u] & 0xFFFF0000u);
            wsum += w;
            const uint32_t* pq = (const uint32_t*)&h[u];
#pragma unroll
            for (int q = 0; q < 4; ++q) {
                uint32_t a = pq[q];
                acc[2 * q]     += w * __uint_as_float(a << 16);
                acc[2 * q + 1] += w * __uint_as_float(a & 0xFFFF0000u);
            }
        }
    }
#pragma unroll
    for (int off = 16; off <= 32; off <<= 1) {
        wsum += __shfl_xor(wsum, off);
#pragma unroll
        for (int q = 0; q < 8; ++q) acc[q] += __shfl_xor(acc[q], off);
    }
    if (lane < 16) {
        float inv = 1.0f / (wsum + 1e-16f);
        size_t o = (size_t)wave * D + c * 8;
        float4 r0 = *(const float4*)(resid + o);
        float4 r1 = *(const float4*)(resid + o + 4);
        float4 o0, o1;
        o0.x = acc[0] * inv + bias[c * 8 + 0] + r0.x;
        o0.y = acc[1] * inv + bias[c * 8 + 1] + r0.y;
        o0.z = acc[2] * inv + bias[c * 8 + 2] + r0.z;
        o0.w = acc[3] * inv + bias[c * 8 + 3] + r0.w;
        o1.x = acc[4] * inv + bias[c * 8 + 4] + r1.x;
        o1.y = acc[5] * inv + bias[c * 8 + 5] + r1.y;
        o1.z = acc[6] * inv + bias[c * 8 + 6] + r1.z;
        o1.w = acc[7] * inv + bias[c * 8 + 7] + r1.w;
        *(float4*)(outp + o)     = o0;
        *(float4*)(outp + o + 4) = o1;
    }
}

// ---------------- MFMA epilogue GEMM, in-place, both dirs: t = t @ W_lin + b ----------------
__global__ __launch_bounds__(256) void mfma_ep_k(float* __restrict__ buf,
                                                 const short* __restrict__ PK,
                                                 const float* __restrict__ bias,
                                                 int nrows) {
    float* T = buf + (size_t)blockIdx.y * nrows * D;
    __shared__ short As[RPB * 136];
    int row0 = blockIdx.x * RPB;
    int tid  = threadIdx.x;
    const float4* in4 = (const float4*)T;
#pragma unroll
    for (int i = 0; i < 16; ++i) {
        int idx = tid + i * 256;
        int row = idx >> 5;
        int q   = idx & 31;
        float4 v = make_float4(0.f, 0.f, 0.f, 0.f);
        int grow = row0 + row;
        if (grow < nrows) v = in4[(size_t)grow * 32 + q];
        int kc = q >> 3, hi = (q >> 2) & 1, g2 = q & 3;
        short4 s4;
        s4.x = f2bf(v.x); s4.y = f2bf(v.y); s4.z = f2bf(v.z); s4.w = f2bf(v.w);
        *(short4*)&As[row * 136 + kc * 32 + g2 * 8 + hi * 4] = s4;
    }
    __syncthreads();

    int lane = tid & 63;
    int wv   = tid >> 6;
    const bf16x8* Wf = (const bf16x8*)PK;
    f32x4 acc[2][8] = {};
#pragma unroll
    for (int kc = 0; kc < 4; ++kc) {
        bf16x8 a0 = *(const bf16x8*)&As[(wv * 32 +      (lane & 15)) * 136 + kc * 32 + (lane >> 4) * 8];
        bf16x8 a1 = *(const bf16x8*)&As[(wv * 32 + 16 + (lane & 15)) * 136 + kc * 32 + (lane >> 4) * 8];
#pragma unroll
        for (int ct = 0; ct < 8; ++ct) {
            bf16x8 b = Wf[(kc * 8 + ct) * 64 + lane];
            acc[0][ct] = __builtin_amdgcn_mfma_f32_16x16x32_bf16(a0, b, acc[0][ct], 0, 0, 0);
            acc[1][ct] = __builtin_amdgcn_mfma_f32_16x16x32_bf16(a1, b, acc[1][ct], 0, 0, 0);
        }
    }

    int cb = lane & 15, rg = lane >> 4;
    float bv[8];
#pragma unroll
    for (int ct = 0; ct < 8; ++ct) bv[ct] = bias[ct * 16 + cb];
#pragma unroll
    for (int rt = 0; rt < 2; ++rt) {
#pragma unroll
        for (int ct = 0; ct < 8; ++ct) {
#pragma unroll
            for (int r = 0; r < 4; ++r) {
                int grow = row0 + wv * 32 + rt * 16 + rg * 4 + r;
                if (grow < nrows) T[(size_t)grow * D + ct * 16 + cb] = acc[rt][ct][r] + bv[ct];
            }
        }
    }
}

// ---------------- host ----------------
extern "C" void kernel_launch(void* const* d_in, const int* in_sizes, int n_in,
                              void* d_out, int out_size, void* d_ws, size_t ws_size,
                              hipStream_t stream) {
    const float* Xw    = (const float*)d_in[0];
    const float* Xs    = (const float*)d_in[1];
    const int*   edge  = (const int*)d_in[2];
    const float* W_s2w = (const float*)d_in[3];
    const float* as1   = (const float*)d_in[4];
    const float* ad1   = (const float*)d_in[5];
    const float* b1    = (const float*)d_in[6];
    const float* W_w2s = (const float*)d_in[7];
    const float* as2   = (const float*)d_in[8];
    const float* ad2   = (const float*)d_in[9];
    const float* b2    = (const float*)d_in[10];
    const float* W_lin = (const float*)d_in[11];
    const float* b_lin = (const float*)d_in[12];
    float* out = (float*)d_out;

    const int N  = in_sizes[0] / D;       // 20000
    const int NE = in_sizes[2] / 2;       // 640000
    const int NB = (N + BKT_W - 1) / BKT_W;
    int CAP = ((NE / NB) * 3 / 2 + 255) & ~255;
    if (CAP > CAPMAX) CAP = CAPMAX;
    const int* e_src = edge;
    const int* e_dst = edge + NE;

    char* p = (char*)d_ws;
    auto take = [&](size_t bytes) -> void* {
        p = (char*)(((uintptr_t)p + 255) & ~(uintptr_t)255);
        void* r = (void*)p;
        p += bytes;
        return r;
    };
    short* hb1  = (short*)take((size_t)N * D * 2);
    short* hb2  = (short*)take((size_t)N * D * 2);
    short* wpk1 = (short*)take((size_t)D * D * 2);
    short* wpk2 = (short*)take((size_t)D * D * 2);
    short* wpkL = (short*)take((size_t)D * D * 2);
    float* ss1  = (float*)take((size_t)N * 4);
    float* sd1  = (float*)take((size_t)N * 4);
    float* ss2  = (float*)take((size_t)N * 4);
    float* sd2  = (float*)take((size_t)N * 4);
    int*   bcur = (int*)take((size_t)2 * NB * 4);     // bcur_d | bcur_s
    int*   bcur_d = bcur;
    int*   bcur_s = bcur + NB;
    int2*  nr_d = (int2*)take((size_t)N * 8);
    int2*  nr_s = (int2*)take((size_t)N * 8);
    uint32_t* rec_d = (uint32_t*)take((size_t)NB * CAP * 4);
    uint32_t* rec_s = (uint32_t*)take((size_t)NB * CAP * 4);

    // 1) pack W (also zeroes bcur)
    pack_w_k<<<24, 256, 0, stream>>>(W_s2w, W_w2s, W_lin, wpk1, wpk2, wpkL, bcur, 2 * NB);

    // 2) fat: MFMA h-GEMM (both dirs) || edge partition
    int mg = (N + RPB - 1) / RPB;
    int partGrid = (NE + 256 * EPT - 1) / (256 * EPT);
    fat_h_part_k<<<2 * mg + partGrid, 256, 0, stream>>>(
        Xs, Xw, wpk1, wpk2, hb1, hb2,
        as1, as2, ad1, ad2, ss1, ss2, sd1, sd2, N, mg,
        e_src, e_dst, bcur_d, bcur_s, rec_d, rec_s, NE, CAP);

    // 3) per-bucket order + weights (in-place rec -> erec), node ranges
    dim3 fillGrid(NB, 2);
    csrfill_k<<<fillGrid, FILL_T, 0, stream>>>(rec_d, rec_s, bcur_d, bcur_s,
                                               ss1, sd1, ss2, sd2, nr_d, nr_s, N, CAP);

    // 4) gather, dir0 blocks dispatched first
    int gB = (N + 3) / 4;
    gat_gather_k<<<2 * gB, 256, 0, stream>>>(nr_d, nr_s, rec_d, rec_s, hb1, hb2,
                                             b1, b2, Xw, Xs, out, N, gB);

    // 5) epilogue (both dirs, in-place): t = t @ W_lin + b_lin
    dim3 epGrid(mg, 2);
    mfma_ep_k<<<epGrid, 256, 0, stream>>>(out, wpkL, b_lin, N);
}

// Round 9
// 86.693 us; speedup vs baseline: 4.7692x; 1.1248x over previous
//
#include <hip/hip_runtime.h>
#include <hip/hip_bf16.h>
#include <stdint.h>

#define D 128
#define BKT_W 64             // nodes per bucket
#define BKT_SH 6
#define NB_MAX 512           // supports N <= 32768
#define RPB 128              // rows per block in MFMA GEMMs
#define CAPMAX 4096          // csrfill LDS staging bound (uint32 each)
#define EPT 8
#define FILL_T 512

typedef __attribute__((ext_vector_type(8))) short bf16x8;
typedef __attribute__((ext_vector_type(4))) float f32x4;

static __device__ __forceinline__ short f2bf(float x) {
    __hip_bfloat16 h = __float2bfloat16(x);
    return *reinterpret_cast<short*>(&h);
}

// ---------------- W pre-pack into MFMA B-fragment order (+ zero bucket cursors) ----------------
__global__ __launch_bounds__(256) void pack_w_k(const float* __restrict__ W0,
                                                const float* __restrict__ W1,
                                                const float* __restrict__ W2,
                                                short* __restrict__ P0,
                                                short* __restrict__ P1,
                                                short* __restrict__ P2,
                                                int* __restrict__ bcur, int nb2) {
    if (blockIdx.x == 0) {
        for (int i = threadIdx.x; i < nb2; i += 256) bcur[i] = 0;
    }
    int t = blockIdx.x * 256 + threadIdx.x;      // 3 * 2048 threads
    int m = t >> 11;
    int r = t & 2047;                            // (kc*8+ct)*64 + lane
    const float* W = (m == 0) ? W0 : (m == 1) ? W1 : W2;
    short*       P = (m == 0) ? P0 : (m == 1) ? P1 : P2;
    int lane = r & 63;
    int fr   = r >> 6;                           // kc*8 + ct
    int kc = fr >> 3, ct = fr & 7;
    int col = ct * 16 + (lane & 15);
    int kb  = kc * 32 + 4 * (lane >> 4);
    short v[8];
#pragma unroll
    for (int e = 0; e < 8; ++e) {
        int k = kb + (e & 3) + 16 * (e >> 2);
        v[e] = f2bf(W[k * D + col]);
    }
    short* dst = P + (size_t)r * 8;
#pragma unroll
    for (int e = 0; e < 8; ++e) dst[e] = v[e];
}

// ---------------- FAT kernel: MFMA h-GEMM (2*mg blocks) || edge partition (rest) ----------------
__global__ __launch_bounds__(256) void fat_h_part_k(
    const float* __restrict__ IN0, const float* __restrict__ IN1,
    const short* __restrict__ P0,  const short* __restrict__ P1,
    short* __restrict__ HB0, short* __restrict__ HB1,
    const float* __restrict__ as0, const float* __restrict__ as1,
    const float* __restrict__ ad0, const float* __restrict__ ad1,
    float* __restrict__ ss0, float* __restrict__ ss1,
    float* __restrict__ sd0, float* __restrict__ sd1,
    int nrows, int mg,
    const int* __restrict__ esrc, const int* __restrict__ edst,
    int* __restrict__ bcur_d, int* __restrict__ bcur_s,
    uint32_t* __restrict__ rec_d, uint32_t* __restrict__ rec_s,
    int ne, int cap) {
    __shared__ __align__(16) char smem[RPB * 136 * 2];
    int bid = blockIdx.x;
    int tid = threadIdx.x;

    if (bid < 2 * mg) {
        // ---------- MFMA h-GEMM branch ----------
        int yy = (bid >= mg) ? 1 : 0;
        int xb = bid - yy * mg;
        const float* IN = yy ? IN1 : IN0;
        const short* PK = yy ? P1  : P0;
        short*       HB = yy ? HB1 : HB0;
        const float* a_src = yy ? as1 : as0;
        const float* a_dst = yy ? ad1 : ad0;
        float* ss = yy ? ss1 : ss0;
        float* sd = yy ? sd1 : sd0;
        short* As = (short*)smem;

        int row0 = xb * RPB;
        const float4* in4 = (const float4*)IN;
#pragma unroll
        for (int i = 0; i < 16; ++i) {
            int idx = tid + i * 256;
            int row = idx >> 5;               // 32 float4 per row
            int q   = idx & 31;
            float4 v = make_float4(0.f, 0.f, 0.f, 0.f);
            int grow = row0 + row;
            if (grow < nrows) v = in4[(size_t)grow * 32 + q];
            int kc = q >> 3, hi = (q >> 2) & 1, g2 = q & 3;
            short4 s4;
            s4.x = f2bf(v.x); s4.y = f2bf(v.y); s4.z = f2bf(v.z); s4.w = f2bf(v.w);
            *(short4*)&As[row * 136 + kc * 32 + g2 * 8 + hi * 4] = s4;
        }
        __syncthreads();

        int lane = tid & 63;
        int wv   = tid >> 6;
        const bf16x8* Wf = (const bf16x8*)PK;
        f32x4 acc[2][8] = {};
#pragma unroll
        for (int kc = 0; kc < 4; ++kc) {
            bf16x8 a0 = *(const bf16x8*)&As[(wv * 32 +      (lane & 15)) * 136 + kc * 32 + (lane >> 4) * 8];
            bf16x8 a1 = *(const bf16x8*)&As[(wv * 32 + 16 + (lane & 15)) * 136 + kc * 32 + (lane >> 4) * 8];
#pragma unroll
            for (int ct = 0; ct < 8; ++ct) {
                bf16x8 b = Wf[(kc * 8 + ct) * 64 + lane];
                acc[0][ct] = __builtin_amdgcn_mfma_f32_16x16x32_bf16(a0, b, acc[0][ct], 0, 0, 0);
                acc[1][ct] = __builtin_amdgcn_mfma_f32_16x16x32_bf16(a1, b, acc[1][ct], 0, 0, 0);
            }
        }

        int cb = lane & 15, rg = lane >> 4;
        float asv[8], adv[8];
#pragma unroll
        for (int ct = 0; ct < 8; ++ct) { asv[ct] = a_src[ct * 16 + cb]; adv[ct] = a_dst[ct * 16 + cb]; }
#pragma unroll
        for (int rt = 0; rt < 2; ++rt) {
            float ssum[4] = {0, 0, 0, 0}, dsum[4] = {0, 0, 0, 0};
#pragma unroll
            for (int ct = 0; ct < 8; ++ct) {
#pragma unroll
                for (int r = 0; r < 4; ++r) {
                    float x = acc[rt][ct][r];
                    int grow = row0 + wv * 32 + rt * 16 + rg * 4 + r;
                    if (grow < nrows) HB[(size_t)grow * D + ct * 16 + cb] = f2bf(x);
                    ssum[r] += x * asv[ct];
                    dsum[r] += x * adv[ct];
                }
            }
#pragma unroll
            for (int off = 1; off < 16; off <<= 1) {
#pragma unroll
                for (int r = 0; r < 4; ++r) {
                    ssum[r] += __shfl_xor(ssum[r], off);
                    dsum[r] += __shfl_xor(dsum[r], off);
                }
            }
            if (cb == 0) {
#pragma unroll
                for (int r = 0; r < 4; ++r) {
                    int grow = row0 + wv * 32 + rt * 16 + rg * 4 + r;
                    if (grow < nrows) { ss[grow] = ssum[r]; sd[grow] = dsum[r]; }
                }
            }
        }
    } else {
        // ---------- edge partition branch ----------
        int pid = bid - 2 * mg;
        int* cnt  = (int*)smem;                       // [2][NB_MAX]
        int* base = (int*)(smem + 2 * NB_MAX * 4);    // [2][NB_MAX]
        int blockStart = pid * 256 * EPT;
        for (int i = tid; i < 2 * NB_MAX; i += 256) cnt[i] = 0;
        __syncthreads();
        int s[EPT], d[EPT], sl_d[EPT], sl_s[EPT];
#pragma unroll
        for (int e = 0; e < EPT; ++e) {
            int i = blockStart + e * 256 + tid;
            s[e] = -1;
            if (i < ne) {
                s[e] = esrc[i]; d[e] = edst[i];
                sl_d[e] = atomicAdd(&cnt[0 * NB_MAX + (d[e] >> BKT_SH)], 1);
                sl_s[e] = atomicAdd(&cnt[1 * NB_MAX + (s[e] >> BKT_SH)], 1);
            }
        }
        __syncthreads();
        for (int i = tid; i < NB_MAX; i += 256) {
            if (cnt[0 * NB_MAX + i]) base[0 * NB_MAX + i] = atomicAdd(&bcur_d[i], cnt[0 * NB_MAX + i]);
            if (cnt[1 * NB_MAX + i]) base[1 * NB_MAX + i] = atomicAdd(&bcur_s[i], cnt[1 * NB_MAX + i]);
        }
        __syncthreads();
#pragma unroll
        for (int e = 0; e < EPT; ++e) {
            if (s[e] >= 0) {
                int bd = d[e] >> BKT_SH, bs = s[e] >> BKT_SH;
                int od = base[0 * NB_MAX + bd] + sl_d[e];
                int os = base[1 * NB_MAX + bs] + sl_s[e];
                if (od < cap) rec_d[(size_t)bd * cap + od] = (uint32_t)s[e] | ((uint32_t)(d[e] & (BKT_W - 1)) << 17);
                if (os < cap) rec_s[(size_t)bs * cap + os] = (uint32_t)d[e] | ((uint32_t)(s[e] & (BKT_W - 1)) << 17);
            }
        }
    }
}

// ---------------- CSR finalize: per-bucket order + weights, in-place; writes node ranges ----------------
__global__ __launch_bounds__(FILL_T) void csrfill_k(uint32_t* __restrict__ rec_d,
                                                    uint32_t* __restrict__ rec_s,
                                                    const int* __restrict__ bcur_d,
                                                    const int* __restrict__ bcur_s,
                                                    const float* __restrict__ ss1,
                                                    const float* __restrict__ sd1,
                                                    const float* __restrict__ ss2,
                                                    const float* __restrict__ sd2,
                                                    int2* __restrict__ nr_d,
                                                    int2* __restrict__ nr_s,
                                                    int n, int cap) {
    __shared__ uint32_t lrec[CAPMAX];
    __shared__ int deg[BKT_W], sbuf[BKT_W], cur[BKT_W];
    __shared__ float sdl[BKT_W];
    int dirv = blockIdx.y;
    uint32_t* rec   = dirv ? rec_s  : rec_d;
    const int* bc   = dirv ? bcur_s : bcur_d;
    const float* ss = dirv ? ss2 : ss1;       // neighbor-side score
    const float* sv = dirv ? sd2 : sd1;       // self-side score
    int2* nr        = dirv ? nr_s : nr_d;
    int b = blockIdx.x, tid = threadIdx.x;
    int base = b * cap;
    int cnt = bc[b]; if (cnt > cap) cnt = cap;
    if (tid < BKT_W) {
        deg[tid] = 0;
        int node = b * BKT_W + tid;
        sdl[tid] = (node < n) ? sv[node] : 0.f;
    }
    for (int j = tid; j < cnt; j += FILL_T) lrec[j] = rec[base + j];
    __syncthreads();
    for (int j = tid; j < cnt; j += FILL_T) atomicAdd(&deg[lrec[j] >> 17], 1);
    __syncthreads();
    if (tid < BKT_W) sbuf[tid] = deg[tid];
    __syncthreads();
    for (int off = 1; off < BKT_W; off <<= 1) {
        int t = (tid < BKT_W && tid >= off) ? sbuf[tid - off] : 0;
        __syncthreads();
        if (tid < BKT_W) sbuf[tid] += t;
        __syncthreads();
    }
    if (tid < BKT_W) {
        int abs0 = base + sbuf[tid] - deg[tid];
        cur[tid] = abs0;
        int node = b * BKT_W + tid;
        if (node < n) nr[node] = make_int2(abs0, abs0 + deg[tid]);
    }
    __syncthreads();
    for (int j = tid; j < cnt; j += FILL_T) {
        uint32_t r = lrec[j];
        int g  = r >> 17;
        int nb = (int)(r & 0x1FFFFu);
        float e = ss[nb] + sdl[g];
        e = (e > 0.f) ? e : 0.2f * e;
        float w = __expf(e);
        rec[atomicAdd(&cur[g], 1)] = (((uint32_t)(unsigned short)f2bf(w)) << 16) | (uint32_t)nb;
    }
}

// ---------------- FUSED gather + epilogue GEMM ----------------
// 512 thr = 8 waves; each wave gathers 2 nodes (16 rows/block) -> bf16 frag rows in LDS
// -> 16x128 @ 128x128 MFMA with W_lin -> out. 1D grid, dir-0 blocks first.
__global__ __launch_bounds__(512) void gat_ep_k(const int2* __restrict__ nr_d,
                                                const int2* __restrict__ nr_s,
                                                const uint32_t* __restrict__ erec_d,
                                                const uint32_t* __restrict__ erec_s,
                                                const short* __restrict__ hb1,
                                                const short* __restrict__ hb2,
                                                const float* __restrict__ b1,
                                                const float* __restrict__ b2,
                                                const float* __restrict__ Xw,
                                                const float* __restrict__ Xs,
                                                const short* __restrict__ wpkL,
                                                const float* __restrict__ b_lin,
                                                float* __restrict__ out, int n, int gB) {
    int bid = blockIdx.x;
    int dirv = (bid >= gB) ? 1 : 0;
    int xb = bid - dirv * gB;
    const int2*     nr   = dirv ? nr_s   : nr_d;
    const uint32_t* erec = dirv ? erec_s : erec_d;
    const short*    hb   = dirv ? hb2    : hb1;
    const float*    bias = dirv ? b2     : b1;
    const float*    resid= dirv ? Xs     : Xw;
    float*          outp = out + (size_t)dirv * n * D;

    __shared__ short T[16 * 136];
    int tid  = threadIdx.x;
    int wv   = tid >> 6;          // 0..7
    int lane = tid & 63;
    int slot = lane >> 4;         // edge slot 0..3
    int c    = lane & 15;         // col chunk: cols 8c..8c+7
    int nbase = xb * 16;

#pragma unroll
    for (int h = 0; h < 2; ++h) {
        int node = nbase + wv * 2 + h;
        int lrow = wv * 2 + h;
        float acc[8] = {0, 0, 0, 0, 0, 0, 0, 0};
        float wsum = 0.f;
        bool valid = (node < n);
        if (valid) {
            int2 be = nr[node];
            int beg = be.x, end = be.y;
            int deg = end - beg;
            // one coalesced wave-load covers the first 64 edges
            uint32_t rpre = 0;
            if (lane < deg) rpre = erec[beg + lane];
            int nfull = (deg < 64) ? deg : 64;
            for (int jj = 0; jj < nfull; jj += 16) {
                uint32_t r[4];
#pragma unroll
                for (int u = 0; u < 4; ++u)
                    r[u] = (uint32_t)__shfl((int)rpre, jj + 4 * u + slot);
                uint4 hrow[4];
#pragma unroll
                for (int u = 0; u < 4; ++u)
                    hrow[u] = *(const uint4*)(hb + (size_t)(r[u] & 0xFFFFu) * D + c * 8);
#pragma unroll
                for (int u = 0; u < 4; ++u) {
                    float w = __uint_as_float(r[u] & 0xFFFF0000u);
                    wsum += w;
                    const uint32_t* pq = (const uint32_t*)&hrow[u];
#pragma unroll
                    for (int q = 0; q < 4; ++q) {
                        uint32_t a = pq[q];
                        acc[2 * q]     += w * __uint_as_float(a << 16);
                        acc[2 * q + 1] += w * __uint_as_float(a & 0xFFFF0000u);
                    }
                }
            }
            // rare tail: deg > 64
            for (int j = beg + 64; j < end; j += 16) {
                uint32_t r[4];
#pragma unroll
                for (int u = 0; u < 4; ++u) {
                    int i = j + 4 * u + slot;
                    r[u] = (i < end) ? erec[i] : 0u;
                }
#pragma unroll
                for (int u = 0; u < 4; ++u) {
                    uint4 hrow = *(const uint4*)(hb + (size_t)(r[u] & 0xFFFFu) * D + c * 8);
                    float w = __uint_as_float(r[u] & 0xFFFF0000u);
                    wsum += w;
                    const uint32_t* pq = (const uint32_t*)&hrow;
#pragma unroll
                    for (int q = 0; q < 4; ++q) {
                        uint32_t a = pq[q];
                        acc[2 * q]     += w * __uint_as_float(a << 16);
                        acc[2 * q + 1] += w * __uint_as_float(a & 0xFFFF0000u);
                    }
                }
            }
        }
        // merge the 4 edge-slot groups
#pragma unroll
        for (int off = 16; off <= 32; off <<= 1) {
            wsum += __shfl_xor(wsum, off);
#pragma unroll
            for (int q = 0; q < 8; ++q) acc[q] += __shfl_xor(acc[q], off);
        }
        // lanes 0..15 finalize row (norm + bias + resid) and store bf16 frag-layout row
        if (lane < 16) {
            float v[8];
            if (valid) {
                float inv = 1.0f / (wsum + 1e-16f);
                size_t o = (size_t)node * D + lane * 8;
                float4 r0 = *(const float4*)(resid + o);
                float4 r1 = *(const float4*)(resid + o + 4);
                float4 bb0 = *(const float4*)(bias + lane * 8);
                float4 bb1 = *(const float4*)(bias + lane * 8 + 4);
                v[0] = acc[0] * inv + bb0.x + r0.x;
                v[1] = acc[1] * inv + bb0.y + r0.y;
                v[2] = acc[2] * inv + bb0.z + r0.z;
                v[3] = acc[3] * inv + bb0.w + r0.w;
                v[4] = acc[4] * inv + bb1.x + r1.x;
                v[5] = acc[5] * inv + bb1.y + r1.y;
                v[6] = acc[6] * inv + bb1.z + r1.z;
                v[7] = acc[7] * inv + bb1.w + r1.w;
            } else {
#pragma unroll
                for (int m = 0; m < 8; ++m) v[m] = 0.f;
            }
#pragma unroll
            for (int half = 0; half < 2; ++half) {
                int k0 = lane * 8 + half * 4;
                int kc = k0 >> 5, hi = (k0 >> 4) & 1, g2 = (k0 >> 2) & 3;
                short4 s4;
                s4.x = f2bf(v[half * 4 + 0]);
                s4.y = f2bf(v[half * 4 + 1]);
                s4.z = f2bf(v[half * 4 + 2]);
                s4.w = f2bf(v[half * 4 + 3]);
                *(short4*)&T[lrow * 136 + kc * 32 + g2 * 8 + hi * 4] = s4;
            }
        }
    }
    __syncthreads();

    // MFMA epilogue: wave wv owns col-tile ct = wv
    const bf16x8* Wf = (const bf16x8*)wpkL;
    f32x4 acc2 = {};
#pragma unroll
    for (int kc = 0; kc < 4; ++kc) {
        bf16x8 a = *(const bf16x8*)&T[(lane & 15) * 136 + kc * 32 + (lane >> 4) * 8];
        bf16x8 b = Wf[(kc * 8 + wv) * 64 + lane];
        acc2 = __builtin_amdgcn_mfma_f32_16x16x32_bf16(a, b, acc2, 0, 0, 0);
    }
    int cb = lane & 15, rg = lane >> 4;
    float bv = b_lin[wv * 16 + cb];
#pragma unroll
    for (int r = 0; r < 4; ++r) {
        int grow = nbase + rg * 4 + r;
        if (grow < n) outp[(size_t)grow * D + wv * 16 + cb] = acc2[r] + bv;
    }
}

// ---------------- host ----------------
extern "C" void kernel_launch(void* const* d_in, const int* in_sizes, int n_in,
                              void* d_out, int out_size, void* d_ws, size_t ws_size,
                              hipStream_t stream) {
    const float* Xw    = (const float*)d_in[0];
    const float* Xs    = (const float*)d_in[1];
    const int*   edge  = (const int*)d_in[2];
    const float* W_s2w = (const float*)d_in[3];
    const float* as1   = (const float*)d_in[4];
    const float* ad1   = (const float*)d_in[5];
    const float* b1    = (const float*)d_in[6];
    const float* W_w2s = (const float*)d_in[7];
    const float* as2   = (const float*)d_in[8];
    const float* ad2   = (const float*)d_in[9];
    const float* b2    = (const float*)d_in[10];
    const float* W_lin = (const float*)d_in[11];
    const float* b_lin = (const float*)d_in[12];
    float* out = (float*)d_out;

    const int N  = in_sizes[0] / D;       // 20000
    const int NE = in_sizes[2] / 2;       // 640000
    const int NB = (N + BKT_W - 1) / BKT_W;
    int CAP = ((NE / NB) * 3 / 2 + 255) & ~255;
    if (CAP > CAPMAX) CAP = CAPMAX;
    const int* e_src = edge;
    const int* e_dst = edge + NE;

    char* p = (char*)d_ws;
    auto take = [&](size_t bytes) -> void* {
        p = (char*)(((uintptr_t)p + 255) & ~(uintptr_t)255);
        void* r = (void*)p;
        p += bytes;
        return r;
    };
    short* hb1  = (short*)take((size_t)N * D * 2);
    short* hb2  = (short*)take((size_t)N * D * 2);
    short* wpk1 = (short*)take((size_t)D * D * 2);
    short* wpk2 = (short*)take((size_t)D * D * 2);
    short* wpkL = (short*)take((size_t)D * D * 2);
    float* ss1  = (float*)take((size_t)N * 4);
    float* sd1  = (float*)take((size_t)N * 4);
    float* ss2  = (float*)take((size_t)N * 4);
    float* sd2  = (float*)take((size_t)N * 4);
    int*   bcur = (int*)take((size_t)2 * NB * 4);     // bcur_d | bcur_s
    int*   bcur_d = bcur;
    int*   bcur_s = bcur + NB;
    int2*  nr_d = (int2*)take((size_t)N * 8);
    int2*  nr_s = (int2*)take((size_t)N * 8);
    uint32_t* rec_d = (uint32_t*)take((size_t)NB * CAP * 4);
    uint32_t* rec_s = (uint32_t*)take((size_t)NB * CAP * 4);

    // 1) pack W (also zeroes bcur)
    pack_w_k<<<24, 256, 0, stream>>>(W_s2w, W_w2s, W_lin, wpk1, wpk2, wpkL, bcur, 2 * NB);

    // 2) fat: MFMA h-GEMM (both dirs) || edge partition
    int mg = (N + RPB - 1) / RPB;
    int partGrid = (NE + 256 * EPT - 1) / (256 * EPT);
    fat_h_part_k<<<2 * mg + partGrid, 256, 0, stream>>>(
        Xs, Xw, wpk1, wpk2, hb1, hb2,
        as1, as2, ad1, ad2, ss1, ss2, sd1, sd2, N, mg,
        e_src, e_dst, bcur_d, bcur_s, rec_d, rec_s, NE, CAP);

    // 3) per-bucket order + weights (in-place rec -> erec), node ranges
    dim3 fillGrid(NB, 2);
    csrfill_k<<<fillGrid, FILL_T, 0, stream>>>(rec_d, rec_s, bcur_d, bcur_s,
                                               ss1, sd1, ss2, sd2, nr_d, nr_s, N, CAP);

    // 4) fused gather + epilogue GEMM (dir0 blocks first)
    int gB = (N + 15) / 16;
    gat_ep_k<<<2 * gB, 512, 0, stream>>>(nr_d, nr_s, rec_d, rec_s, hb1, hb2,
                                         b1, b2, Xw, Xs, wpkL, b_lin, out, N, gB);
}

// Round 10
// 84.821 us; speedup vs baseline: 4.8745x; 1.0221x over previous
//
#include <hip/hip_runtime.h>
#include <hip/hip_bf16.h>
#include <stdint.h>

#define D 128
#define BKT_W 64             // nodes per bucket
#define BKT_SH 6
#define NB_MAX 512           // supports N <= 32768
#define RPB 128              // rows per block in MFMA h-GEMM
#define CAPMAX 4096          // per-bucket record capacity (uint32 each)
#define EPT 8

typedef __attribute__((ext_vector_type(8))) short bf16x8;
typedef __attribute__((ext_vector_type(4))) float f32x4;

static __device__ __forceinline__ short f2bf(float x) {
    __hip_bfloat16 h = __float2bfloat16(x);
    return *reinterpret_cast<short*>(&h);
}

// ---------------- W pre-pack into MFMA B-fragment order (+ zero bucket cursors) ----------------
__global__ __launch_bounds__(256) void pack_w_k(const float* __restrict__ W0,
                                                const float* __restrict__ W1,
                                                const float* __restrict__ W2,
                                                short* __restrict__ P0,
                                                short* __restrict__ P1,
                                                short* __restrict__ P2,
                                                int* __restrict__ bcur, int nb2) {
    if (blockIdx.x == 0) {
        for (int i = threadIdx.x; i < nb2; i += 256) bcur[i] = 0;
    }
    int t = blockIdx.x * 256 + threadIdx.x;      // 3 * 2048 threads
    int m = t >> 11;
    int r = t & 2047;                            // (kc*8+ct)*64 + lane
    const float* W = (m == 0) ? W0 : (m == 1) ? W1 : W2;
    short*       P = (m == 0) ? P0 : (m == 1) ? P1 : P2;
    int lane = r & 63;
    int fr   = r >> 6;                           // kc*8 + ct
    int kc = fr >> 3, ct = fr & 7;
    int col = ct * 16 + (lane & 15);
    int kb  = kc * 32 + 4 * (lane >> 4);
    short v[8];
#pragma unroll
    for (int e = 0; e < 8; ++e) {
        int k = kb + (e & 3) + 16 * (e >> 2);
        v[e] = f2bf(W[k * D + col]);
    }
    short* dst = P + (size_t)r * 8;
#pragma unroll
    for (int e = 0; e < 8; ++e) dst[e] = v[e];
}

// ---------------- FAT kernel: MFMA h-GEMM (2*mg blocks) || edge partition (rest) ----------------
__global__ __launch_bounds__(256) void fat_h_part_k(
    const float* __restrict__ IN0, const float* __restrict__ IN1,
    const short* __restrict__ P0,  const short* __restrict__ P1,
    short* __restrict__ HB0, short* __restrict__ HB1,
    const float* __restrict__ as0, const float* __restrict__ as1,
    const float* __restrict__ ad0, const float* __restrict__ ad1,
    float* __restrict__ ss0, float* __restrict__ ss1,
    float* __restrict__ sd0, float* __restrict__ sd1,
    int nrows, int mg,
    const int* __restrict__ esrc, const int* __restrict__ edst,
    int* __restrict__ bcur_d, int* __restrict__ bcur_s,
    uint32_t* __restrict__ rec_d, uint32_t* __restrict__ rec_s,
    int ne, int cap) {
    __shared__ __align__(16) char smem[RPB * 136 * 2];
    int bid = blockIdx.x;
    int tid = threadIdx.x;

    if (bid < 2 * mg) {
        // ---------- MFMA h-GEMM branch ----------
        int yy = (bid >= mg) ? 1 : 0;
        int xb = bid - yy * mg;
        const float* IN = yy ? IN1 : IN0;
        const short* PK = yy ? P1  : P0;
        short*       HB = yy ? HB1 : HB0;
        const float* a_src = yy ? as1 : as0;
        const float* a_dst = yy ? ad1 : ad0;
        float* ss = yy ? ss1 : ss0;
        float* sd = yy ? sd1 : sd0;
        short* As = (short*)smem;

        int row0 = xb * RPB;
        const float4* in4 = (const float4*)IN;
#pragma unroll
        for (int i = 0; i < 16; ++i) {
            int idx = tid + i * 256;
            int row = idx >> 5;               // 32 float4 per row
            int q   = idx & 31;
            float4 v = make_float4(0.f, 0.f, 0.f, 0.f);
            int grow = row0 + row;
            if (grow < nrows) v = in4[(size_t)grow * 32 + q];
            int kc = q >> 3, hi = (q >> 2) & 1, g2 = q & 3;
            short4 s4;
            s4.x = f2bf(v.x); s4.y = f2bf(v.y); s4.z = f2bf(v.z); s4.w = f2bf(v.w);
            *(short4*)&As[row * 136 + kc * 32 + g2 * 8 + hi * 4] = s4;
        }
        __syncthreads();

        int lane = tid & 63;
        int wv   = tid >> 6;
        const bf16x8* Wf = (const bf16x8*)PK;
        f32x4 acc[2][8] = {};
#pragma unroll
        for (int kc = 0; kc < 4; ++kc) {
            bf16x8 a0 = *(const bf16x8*)&As[(wv * 32 +      (lane & 15)) * 136 + kc * 32 + (lane >> 4) * 8];
            bf16x8 a1 = *(const bf16x8*)&As[(wv * 32 + 16 + (lane & 15)) * 136 + kc * 32 + (lane >> 4) * 8];
#pragma unroll
            for (int ct = 0; ct < 8; ++ct) {
                bf16x8 b = Wf[(kc * 8 + ct) * 64 + lane];
                acc[0][ct] = __builtin_amdgcn_mfma_f32_16x16x32_bf16(a0, b, acc[0][ct], 0, 0, 0);
                acc[1][ct] = __builtin_amdgcn_mfma_f32_16x16x32_bf16(a1, b, acc[1][ct], 0, 0, 0);
            }
        }

        int cb = lane & 15, rg = lane >> 4;
        float asv[8], adv[8];
#pragma unroll
        for (int ct = 0; ct < 8; ++ct) { asv[ct] = a_src[ct * 16 + cb]; adv[ct] = a_dst[ct * 16 + cb]; }
#pragma unroll
        for (int rt = 0; rt < 2; ++rt) {
            float ssum[4] = {0, 0, 0, 0}, dsum[4] = {0, 0, 0, 0};
#pragma unroll
            for (int ct = 0; ct < 8; ++ct) {
#pragma unroll
                for (int r = 0; r < 4; ++r) {
                    float x = acc[rt][ct][r];
                    int grow = row0 + wv * 32 + rt * 16 + rg * 4 + r;
                    if (grow < nrows) HB[(size_t)grow * D + ct * 16 + cb] = f2bf(x);
                    ssum[r] += x * asv[ct];
                    dsum[r] += x * adv[ct];
                }
            }
#pragma unroll
            for (int off = 1; off < 16; off <<= 1) {
#pragma unroll
                for (int r = 0; r < 4; ++r) {
                    ssum[r] += __shfl_xor(ssum[r], off);
                    dsum[r] += __shfl_xor(dsum[r], off);
                }
            }
            if (cb == 0) {
#pragma unroll
                for (int r = 0; r < 4; ++r) {
                    int grow = row0 + wv * 32 + rt * 16 + rg * 4 + r;
                    if (grow < nrows) { ss[grow] = ssum[r]; sd[grow] = dsum[r]; }
                }
            }
        }
    } else {
        // ---------- edge partition branch ----------
        int pid = bid - 2 * mg;
        int* cnt  = (int*)smem;                       // [2][NB_MAX]
        int* base = (int*)(smem + 2 * NB_MAX * 4);    // [2][NB_MAX]
        int blockStart = pid * 256 * EPT;
        for (int i = tid; i < 2 * NB_MAX; i += 256) cnt[i] = 0;
        __syncthreads();
        int s[EPT], d[EPT], sl_d[EPT], sl_s[EPT];
#pragma unroll
        for (int e = 0; e < EPT; ++e) {
            int i = blockStart + e * 256 + tid;
            s[e] = -1;
            if (i < ne) {
                s[e] = esrc[i]; d[e] = edst[i];
                sl_d[e] = atomicAdd(&cnt[0 * NB_MAX + (d[e] >> BKT_SH)], 1);
                sl_s[e] = atomicAdd(&cnt[1 * NB_MAX + (s[e] >> BKT_SH)], 1);
            }
        }
        __syncthreads();
        for (int i = tid; i < NB_MAX; i += 256) {
            if (cnt[0 * NB_MAX + i]) base[0 * NB_MAX + i] = atomicAdd(&bcur_d[i], cnt[0 * NB_MAX + i]);
            if (cnt[1 * NB_MAX + i]) base[1 * NB_MAX + i] = atomicAdd(&bcur_s[i], cnt[1 * NB_MAX + i]);
        }
        __syncthreads();
#pragma unroll
        for (int e = 0; e < EPT; ++e) {
            if (s[e] >= 0) {
                int bd = d[e] >> BKT_SH, bs = s[e] >> BKT_SH;
                int od = base[0 * NB_MAX + bd] + sl_d[e];
                int os = base[1 * NB_MAX + bs] + sl_s[e];
                if (od < cap) rec_d[(size_t)bd * cap + od] = (uint32_t)s[e] | ((uint32_t)(d[e] & (BKT_W - 1)) << 17);
                if (os < cap) rec_s[(size_t)bs * cap + os] = (uint32_t)d[e] | ((uint32_t)(s[e] & (BKT_W - 1)) << 17);
            }
        }
    }
}

// ---------------- FUSED bucket sort + weights + gather + epilogue GEMM ----------------
// One block per (bucket, dir), 512 thr = 8 waves. Phase A: LDS sort + weight calc.
// Phase B: each wave gathers 8 nodes (records from LDS). Phase C: 64x128 @ 128x128 MFMA.
__global__ __launch_bounds__(512) void bucket_gat_ep_k(
    const uint32_t* __restrict__ rec_d, const uint32_t* __restrict__ rec_s,
    const int* __restrict__ bcur_d, const int* __restrict__ bcur_s,
    const float* __restrict__ ss1, const float* __restrict__ sd1,
    const float* __restrict__ ss2, const float* __restrict__ sd2,
    const short* __restrict__ hb1, const short* __restrict__ hb2,
    const float* __restrict__ b1,  const float* __restrict__ b2,
    const float* __restrict__ Xw,  const float* __restrict__ Xs,
    const short* __restrict__ wpkL, const float* __restrict__ b_lin,
    float* __restrict__ out, int n, int nb, int cap) {

    __shared__ __align__(16) char smem0[BKT_W * 136 * 2];   // lrec (16KB) then T (17.4KB)
    __shared__ uint32_t srec[CAPMAX];                        // sorted weighted records
    __shared__ int deg[BKT_W], scn[BKT_W], cur[BKT_W];
    __shared__ float sdl[BKT_W];

    int bid = blockIdx.x;
    int dirv = (bid >= nb) ? 1 : 0;
    int b = bid - dirv * nb;
    const uint32_t* rec  = dirv ? rec_s  : rec_d;
    const int*      bc   = dirv ? bcur_s : bcur_d;
    const float*    ss   = dirv ? ss2 : ss1;      // neighbor-side score
    const float*    sv   = dirv ? sd2 : sd1;      // self-side score
    const short*    hb   = dirv ? hb2 : hb1;
    const float*    bias = dirv ? b2  : b1;
    const float*    resid= dirv ? Xs  : Xw;
    float*          outp = out + (size_t)dirv * n * D;

    uint32_t* lrec = (uint32_t*)smem0;
    short*    T    = (short*)smem0;

    int tid = threadIdx.x;
    int cnt = bc[b]; if (cnt > cap) cnt = cap;
    int base = b * cap;

    // ---- Phase A: stage, count, scan, weighted scatter (into srec) ----
    if (tid < BKT_W) {
        deg[tid] = 0;
        int node = b * BKT_W + tid;
        sdl[tid] = (node < n) ? sv[node] : 0.f;
    }
    for (int j = tid; j < cnt; j += 512) lrec[j] = rec[base + j];
    __syncthreads();
    for (int j = tid; j < cnt; j += 512) atomicAdd(&deg[lrec[j] >> 17], 1);
    __syncthreads();
    if (tid < BKT_W) scn[tid] = deg[tid];
    __syncthreads();
    for (int off = 1; off < BKT_W; off <<= 1) {
        int t = (tid < BKT_W && tid >= off) ? scn[tid - off] : 0;
        __syncthreads();
        if (tid < BKT_W) scn[tid] += t;
        __syncthreads();
    }
    if (tid < BKT_W) cur[tid] = scn[tid] - deg[tid];
    __syncthreads();
    for (int j = tid; j < cnt; j += 512) {
        uint32_t r = lrec[j];
        int g  = r >> 17;
        int nbb = (int)(r & 0x1FFFFu);
        float e = ss[nbb] + sdl[g];
        e = (e > 0.f) ? e : 0.2f * e;
        float w = __expf(e);
        srec[atomicAdd(&cur[g], 1)] = (((uint32_t)(unsigned short)f2bf(w)) << 16) | (uint32_t)nbb;
    }
    __syncthreads();   // lrec dead from here; T may be written

    // ---- Phase B: each wave gathers 8 nodes; records from LDS srec ----
    int wv   = tid >> 6;
    int lane = tid & 63;
    int slot = lane >> 4;        // edge slot 0..3
    int c    = lane & 15;        // col chunk: cols 8c..8c+7
#pragma unroll
    for (int h = 0; h < 8; ++h) {
        int g = wv * 8 + h;
        int node = b * BKT_W + g;
        bool valid = (node < n);
        float acc[8] = {0, 0, 0, 0, 0, 0, 0, 0};
        float wsum = 0.f;
        int beg = scn[g] - deg[g];
        int dg  = valid ? deg[g] : 0;
        // first 64 edges via one LDS read + shfl distribution
        uint32_t rpre = (lane < dg) ? srec[beg + lane] : 0u;
        int nfull = (dg < 64) ? dg : 64;
        for (int jj = 0; jj < nfull; jj += 16) {
            uint32_t r[4];
#pragma unroll
            for (int u = 0; u < 4; ++u)
                r[u] = (uint32_t)__shfl((int)rpre, jj + 4 * u + slot);
            uint4 hrow[4];
#pragma unroll
            for (int u = 0; u < 4; ++u)
                hrow[u] = *(const uint4*)(hb + (size_t)(r[u] & 0xFFFFu) * D + c * 8);
#pragma unroll
            for (int u = 0; u < 4; ++u) {
                float w = __uint_as_float(r[u] & 0xFFFF0000u);
                wsum += w;
                const uint32_t* pq = (const uint32_t*)&hrow[u];
#pragma unroll
                for (int q = 0; q < 4; ++q) {
                    uint32_t a = pq[q];
                    acc[2 * q]     += w * __uint_as_float(a << 16);
                    acc[2 * q + 1] += w * __uint_as_float(a & 0xFFFF0000u);
                }
            }
        }
        // rare tail: dg > 64 (records still in LDS)
        for (int j = 64; j < dg; j += 16) {
            int i = j + 4 * slot;  // 4 slots x 4 unroll pattern below
            uint32_t r[4];
#pragma unroll
            for (int u = 0; u < 4; ++u) {
                int idx = j + 4 * u + slot;
                r[u] = (idx < dg) ? srec[beg + idx] : 0u;
            }
#pragma unroll
            for (int u = 0; u < 4; ++u) {
                uint4 hrow = *(const uint4*)(hb + (size_t)(r[u] & 0xFFFFu) * D + c * 8);
                float w = __uint_as_float(r[u] & 0xFFFF0000u);
                wsum += w;
                const uint32_t* pq = (const uint32_t*)&hrow;
#pragma unroll
                for (int q = 0; q < 4; ++q) {
                    uint32_t a = pq[q];
                    acc[2 * q]     += w * __uint_as_float(a << 16);
                    acc[2 * q + 1] += w * __uint_as_float(a & 0xFFFF0000u);
                }
            }
            (void)i;
        }
        // merge 4 edge-slot groups
#pragma unroll
        for (int off = 16; off <= 32; off <<= 1) {
            wsum += __shfl_xor(wsum, off);
#pragma unroll
            for (int q = 0; q < 8; ++q) acc[q] += __shfl_xor(acc[q], off);
        }
        // lanes 0..15 finalize row and store bf16 frag-layout into T
        if (lane < 16) {
            float v[8];
            if (valid) {
                float inv = 1.0f / (wsum + 1e-16f);
                size_t o = (size_t)node * D + lane * 8;
                float4 r0 = *(const float4*)(resid + o);
                float4 r1 = *(const float4*)(resid + o + 4);
                float4 bb0 = *(const float4*)(bias + lane * 8);
                float4 bb1 = *(const float4*)(bias + lane * 8 + 4);
                v[0] = acc[0] * inv + bb0.x + r0.x;
                v[1] = acc[1] * inv + bb0.y + r0.y;
                v[2] = acc[2] * inv + bb0.z + r0.z;
                v[3] = acc[3] * inv + bb0.w + r0.w;
                v[4] = acc[4] * inv + bb1.x + r1.x;
                v[5] = acc[5] * inv + bb1.y + r1.y;
                v[6] = acc[6] * inv + bb1.z + r1.z;
                v[7] = acc[7] * inv + bb1.w + r1.w;
            } else {
#pragma unroll
                for (int m = 0; m < 8; ++m) v[m] = 0.f;
            }
#pragma unroll
            for (int half = 0; half < 2; ++half) {
                int k0 = lane * 8 + half * 4;
                int kc = k0 >> 5, hi = (k0 >> 4) & 1, g2 = (k0 >> 2) & 3;
                short4 s4;
                s4.x = f2bf(v[half * 4 + 0]);
                s4.y = f2bf(v[half * 4 + 1]);
                s4.z = f2bf(v[half * 4 + 2]);
                s4.w = f2bf(v[half * 4 + 3]);
                *(short4*)&T[g * 136 + kc * 32 + g2 * 8 + hi * 4] = s4;
            }
        }
    }
    __syncthreads();

    // ---- Phase C: 64x128 @ 128x128 MFMA epilogue; 32 tile-tasks over 8 waves ----
    const bf16x8* Wf = (const bf16x8*)wpkL;
#pragma unroll
    for (int q = 0; q < 4; ++q) {
        int task = wv * 4 + q;         // 0..31
        int rt = task >> 3, ct = task & 7;
        f32x4 acc2 = {};
#pragma unroll
        for (int kc = 0; kc < 4; ++kc) {
            bf16x8 a = *(const bf16x8*)&T[(rt * 16 + (lane & 15)) * 136 + kc * 32 + (lane >> 4) * 8];
            bf16x8 bfr = Wf[(kc * 8 + ct) * 64 + lane];
            acc2 = __builtin_amdgcn_mfma_f32_16x16x32_bf16(a, bfr, acc2, 0, 0, 0);
        }
        int cb = lane & 15, rg = lane >> 4;
        float bv = b_lin[ct * 16 + cb];
#pragma unroll
        for (int r = 0; r < 4; ++r) {
            int grow = b * BKT_W + rt * 16 + rg * 4 + r;
            if (grow < n) outp[(size_t)grow * D + ct * 16 + cb] = acc2[r] + bv;
        }
    }
}

// ---------------- host ----------------
extern "C" void kernel_launch(void* const* d_in, const int* in_sizes, int n_in,
                              void* d_out, int out_size, void* d_ws, size_t ws_size,
                              hipStream_t stream) {
    const float* Xw    = (const float*)d_in[0];
    const float* Xs    = (const float*)d_in[1];
    const int*   edge  = (const int*)d_in[2];
    const float* W_s2w = (const float*)d_in[3];
    const float* as1   = (const float*)d_in[4];
    const float* ad1   = (const float*)d_in[5];
    const float* b1    = (const float*)d_in[6];
    const float* W_w2s = (const float*)d_in[7];
    const float* as2   = (const float*)d_in[8];
    const float* ad2   = (const float*)d_in[9];
    const float* b2    = (const float*)d_in[10];
    const float* W_lin = (const float*)d_in[11];
    const float* b_lin = (const float*)d_in[12];
    float* out = (float*)d_out;

    const int N  = in_sizes[0] / D;       // 20000
    const int NE = in_sizes[2] / 2;       // 640000
    const int NB = (N + BKT_W - 1) / BKT_W;
    int CAP = ((NE / NB) * 3 / 2 + 255) & ~255;
    if (CAP > CAPMAX) CAP = CAPMAX;
    const int* e_src = edge;
    const int* e_dst = edge + NE;

    char* p = (char*)d_ws;
    auto take = [&](size_t bytes) -> void* {
        p = (char*)(((uintptr_t)p + 255) & ~(uintptr_t)255);
        void* r = (void*)p;
        p += bytes;
        return r;
    };
    short* hb1  = (short*)take((size_t)N * D * 2);
    short* hb2  = (short*)take((size_t)N * D * 2);
    short* wpk1 = (short*)take((size_t)D * D * 2);
    short* wpk2 = (short*)take((size_t)D * D * 2);
    short* wpkL = (short*)take((size_t)D * D * 2);
    float* ss1  = (float*)take((size_t)N * 4);
    float* sd1  = (float*)take((size_t)N * 4);
    float* ss2  = (float*)take((size_t)N * 4);
    float* sd2  = (float*)take((size_t)N * 4);
    int*   bcur = (int*)take((size_t)2 * NB * 4);     // bcur_d | bcur_s
    int*   bcur_d = bcur;
    int*   bcur_s = bcur + NB;
    uint32_t* rec_d = (uint32_t*)take((size_t)NB * CAP * 4);
    uint32_t* rec_s = (uint32_t*)take((size_t)NB * CAP * 4);

    // 1) pack W (also zeroes bcur)
    pack_w_k<<<24, 256, 0, stream>>>(W_s2w, W_w2s, W_lin, wpk1, wpk2, wpkL, bcur, 2 * NB);

    // 2) fat: MFMA h-GEMM (both dirs) || edge partition
    int mg = (N + RPB - 1) / RPB;
    int partGrid = (NE + 256 * EPT - 1) / (256 * EPT);
    fat_h_part_k<<<2 * mg + partGrid, 256, 0, stream>>>(
        Xs, Xw, wpk1, wpk2, hb1, hb2,
        as1, as2, ad1, ad2, ss1, ss2, sd1, sd2, N, mg,
        e_src, e_dst, bcur_d, bcur_s, rec_d, rec_s, NE, CAP);

    // 3) fused: per-bucket sort + weights + gather + epilogue GEMM (dir0 first)
    bucket_gat_ep_k<<<2 * NB, 512, 0, stream>>>(
        rec_d, rec_s, bcur_d, bcur_s, ss1, sd1, ss2, sd2,
        hb1, hb2, b1, b2, Xw, Xs, wpkL, b_lin, out, N, NB, CAP);
}